// Round 1
// baseline (985.056 us; speedup 1.0000x reference)
//
#include <hip/hip_runtime.h>
#include <math.h>

#define NB 4
#define NL 576
#define NC 256
#define NTOK (NB*NL)      // 2304
#define NDIN 512
#define NXD 112
#define NDTR 16
#define NDST 48
#define NFREQ 289
#define NWIN 1024         // w_in output width

// ---- workspace layout (floats) ----
#define OFF_H     0u
#define OFF_XR    589824u
#define OFF_XC    2949120u
#define OFF_XDBL  4128768u
#define OFF_DELTA 4386816u
#define OFF_YF    5566464u
#define OFF_X2    6746112u
#define OFF_H2    7335936u
#define OFF_F     7925760u
#define OFF_RF    9105408u
#define OFF_IF    9697280u
#define OFF_XRE   10289152u
#define OFF_XIM   10881024u
#define OFF_FF    11472896u
#define OFF_CT    12652544u
#define OFF_ST    12653120u

__device__ __forceinline__ float wave_sum(float v) {
#pragma unroll
  for (int o = 32; o > 0; o >>= 1) v += __shfl_xor(v, o);
  return v;
}

__global__ void trig_kernel(float* ct, float* st) {
  int i = threadIdx.x;
  if (i < NL) {
    double a = (6.283185307179586476925286766559 * (double)i) / (double)NL;
    ct[i] = (float)cos(a);
    st[i] = (float)sin(a);
  }
}

// one wave per token row; C=256 -> 4 elems/lane. dbl=1: two chained LNs.
__global__ void ln_kernel(const float* __restrict__ in, float* __restrict__ out,
                          const float* __restrict__ g1, const float* __restrict__ b1,
                          const float* __restrict__ g2, const float* __restrict__ b2,
                          int dbl) {
  int row = blockIdx.x, lane = threadIdx.x;
  const float* p = in + (size_t)row * NC;
  float v[4];
#pragma unroll
  for (int j = 0; j < 4; ++j) v[j] = p[lane + j * 64];
  float s = wave_sum(v[0] + v[1] + v[2] + v[3]);
  float m = s * (1.f / NC);
  float q = 0.f;
#pragma unroll
  for (int j = 0; j < 4; ++j) { float d = v[j] - m; q += d * d; }
  q = wave_sum(q);
  float rs = 1.f / sqrtf(q * (1.f / NC) + 1e-3f);
#pragma unroll
  for (int j = 0; j < 4; ++j) {
    int c = lane + j * 64;
    v[j] = (v[j] - m) * rs * g1[c] + b1[c];
  }
  if (dbl) {
    s = wave_sum(v[0] + v[1] + v[2] + v[3]);
    m = s * (1.f / NC);
    q = 0.f;
#pragma unroll
    for (int j = 0; j < 4; ++j) { float d = v[j] - m; q += d * d; }
    q = wave_sum(q);
    rs = 1.f / sqrtf(q * (1.f / NC) + 1e-3f);
#pragma unroll
    for (int j = 0; j < 4; ++j) {
      int c = lane + j * 64;
      v[j] = (v[j] - m) * rs * g2[c] + b2[c];
    }
  }
  float* o = out + (size_t)row * NC;
#pragma unroll
  for (int j = 0; j < 4; ++j) o[lane + j * 64] = v[j];
}

// generic tiled f32 GEMM: C[M,N] = A[M,K(lda)] @ B[K,N(ldb)], fused epilogues.
// mode 0: store; 1: softplus(v+bias); 2: v+add; 3: relu(v*scl+bias); 4: v*scl+bias+add
__global__ __launch_bounds__(256) void gemm_f32(
    const float* __restrict__ A, int lda, const float* __restrict__ B, int ldb,
    float* __restrict__ C, int ldc, int M, int N, int K, int mode,
    const float* __restrict__ scl, const float* __restrict__ bias,
    const float* __restrict__ add, int ldadd) {
  __shared__ float As[16][65];   // [k][m]
  __shared__ float Bs[16][68];   // [k][n]
  int tid = threadIdx.x;
  int tx = tid & 15, ty = tid >> 4;
  int m0 = blockIdx.y * 64, n0 = blockIdx.x * 64;
  int am = tid >> 2, ak = (tid & 3) * 4;
  int bk = tid >> 4, bn = (tid & 15) * 4;
  float acc[4][4] = {};
  for (int k0 = 0; k0 < K; k0 += 16) {
    float4 av = make_float4(0.f, 0.f, 0.f, 0.f);
    if (m0 + am < M)
      av = *reinterpret_cast<const float4*>(A + (size_t)(m0 + am) * lda + k0 + ak);
    As[ak + 0][am] = av.x; As[ak + 1][am] = av.y;
    As[ak + 2][am] = av.z; As[ak + 3][am] = av.w;
    float4 bv = make_float4(0.f, 0.f, 0.f, 0.f);
    if (n0 + bn < N)
      bv = *reinterpret_cast<const float4*>(B + (size_t)(k0 + bk) * ldb + n0 + bn);
    *reinterpret_cast<float4*>(&Bs[bk][bn]) = bv;
    __syncthreads();
#pragma unroll
    for (int kk = 0; kk < 16; ++kk) {
      float a[4], b[4];
#pragma unroll
      for (int i = 0; i < 4; ++i) a[i] = As[kk][ty * 4 + i];
#pragma unroll
      for (int j = 0; j < 4; ++j) b[j] = Bs[kk][tx * 4 + j];
#pragma unroll
      for (int i = 0; i < 4; ++i)
#pragma unroll
        for (int j = 0; j < 4; ++j) acc[i][j] += a[i] * b[j];
    }
    __syncthreads();
  }
#pragma unroll
  for (int i = 0; i < 4; ++i) {
    int gm = m0 + ty * 4 + i;
    if (gm >= M) continue;
#pragma unroll
    for (int j = 0; j < 4; ++j) {
      int gn = n0 + tx * 4 + j;
      if (gn >= N) continue;
      float v = acc[i][j];
      if (mode == 1) { v += bias[gn]; v = fmaxf(v, 0.f) + log1pf(expf(-fabsf(v))); }
      else if (mode == 2) { v += add[(size_t)gm * ldadd + gn]; }
      else if (mode == 3) { v = fmaxf(v * scl[gn] + bias[gn], 0.f); }
      else if (mode == 4) { v = v * scl[gn] + bias[gn] + add[(size_t)gm * ldadd + gn]; }
      C[(size_t)gm * ldc + gn] = v;
    }
  }
}

// causal depthwise conv (width 4) over xm = xr[:, :512], then silu.
__global__ void conv_silu_kernel(const float* __restrict__ xr,
                                 const float* __restrict__ cw,
                                 const float* __restrict__ cb,
                                 float* __restrict__ xc) {
  int id = blockIdx.x * blockDim.x + threadIdx.x;
  if (id >= NTOK * NDIN) return;
  int d = id & 511, row = id >> 9;
  int b = row / NL, l = row % NL;
  float acc = cb[d];
#pragma unroll
  for (int k = 0; k < 4; ++k) {
    int l2 = l - 3 + k;
    if (l2 >= 0) acc += xr[((size_t)(b * NL + l2)) * NWIN + d] * cw[k * NDIN + d];
  }
  xc[(size_t)row * NDIN + d] = acc / (1.f + expf(-acc));
}

// selective scan, reference-faithful (suffix-sum + eps-divide). 1 wave per (b,d).
__global__ void scan_kernel(const float* __restrict__ delta,
                            const float* __restrict__ xc,
                            const float* __restrict__ xdbl,
                            const float* __restrict__ A_log,
                            const float* __restrict__ Dp,
                            const float* __restrict__ xr,  // res at cols 512..1023
                            float* __restrict__ yf) {
  int blk = blockIdx.x;
  int b = blk >> 9, d = blk & 511;
  int lane = threadIdx.x;
  __shared__ float Tsuf[NL];
  __shared__ float Dcol[NL];
  for (int l = lane; l < NL; l += 64)
    Dcol[l] = delta[((size_t)(b * NL + l)) * NDIN + d];
  __syncthreads();
  if (lane == 0) {
    float t = 0.f;
    for (int l = NL - 1; l >= 0; --l) { Tsuf[l] = t; t += Dcol[l]; }
  }
  __syncthreads();
  bool act = lane < NDST;
  float An = act ? -expf(A_log[d * NDST + lane]) : 0.f;
  float Dd = Dp[d];
  float csum = 0.f;
  for (int l = 0; l < NL; ++l) {
    size_t row = (size_t)(b * NL + l);
    float dl = Dcol[l];
    float ul = xc[row * NDIN + d];
    float contrib = 0.f;
    if (act) {
      float e = expf(An * Tsuf[l]);
      float bm = xdbl[row * NXD + NDTR + lane];
      float cm = xdbl[row * NXD + NDTR + NDST + lane];
      csum += dl * ul * bm * e;
      contrib = (csum / (e + 1e-12f)) * cm;
    }
    contrib = wave_sum(contrib);
    if (lane == 0) {
      float y = contrib + ul * Dd;
      float r = xr[row * NWIN + NDIN + d];
      yf[row * NDIN + d] = y * (r / (1.f + expf(-r)));
    }
  }
}

// forward DFT along L (rfft): RF/IF[b,k,c], trig from table via (k*l)%576.
__global__ void dft_fwd_kernel(const float* __restrict__ f,
                               const float* __restrict__ ct,
                               const float* __restrict__ st,
                               float* __restrict__ RF, float* __restrict__ IF) {
  int k = blockIdx.x, b = blockIdx.y, tid = threadIdx.x;
  __shared__ float lc[NL], ls[NL];
  for (int l = tid; l < NL; l += 256) {
    int idx = (k * l) % NL;
    lc[l] = ct[idx]; ls[l] = st[idx];
  }
  __syncthreads();
  int c0 = tid, c1 = tid + 256;
  float r0 = 0.f, i0 = 0.f, r1 = 0.f, i1 = 0.f;
  const float* fb = f + (size_t)b * NL * NDIN;
  for (int l = 0; l < NL; ++l) {
    float cl = lc[l], sl = ls[l];
    float v0 = fb[(size_t)l * NDIN + c0];
    float v1 = fb[(size_t)l * NDIN + c1];
    r0 += v0 * cl; i0 -= v0 * sl;
    r1 += v1 * cl; i1 -= v1 * sl;
  }
  size_t o = ((size_t)b * NFREQ + k) * NDIN;
  RF[o + c0] = r0 * (1.f / 24.f); RF[o + c1] = r1 * (1.f / 24.f);
  IF[o + c0] = i0 * (1.f / 24.f); IF[o + c1] = i1 * (1.f / 24.f);
}

// complex channel mix: xre=relu(RF@Wr - IF@Wi + rb), xim=relu(IF@Wr + RF@Wi + ib)
__global__ __launch_bounds__(256) void mix_kernel(
    const float* __restrict__ RF, const float* __restrict__ IFm,
    const float* __restrict__ Wr, const float* __restrict__ Wi,
    const float* __restrict__ rb, const float* __restrict__ ib,
    float* __restrict__ xre, float* __restrict__ xim) {
  __shared__ float Ars[16][65], Ais[16][65];
  __shared__ float Brs[16][68], Bis[16][68];
  int b = blockIdx.z;
  int m0 = blockIdx.y * 64, n0 = blockIdx.x * 64;
  int tid = threadIdx.x;
  int tx = tid & 15, ty = tid >> 4;
  int am = tid >> 2, ak = (tid & 3) * 4;
  int bk = tid >> 4, bn = (tid & 15) * 4;
  const float* Ar = RF + (size_t)b * NFREQ * NDIN;
  const float* Ai = IFm + (size_t)b * NFREQ * NDIN;
  float accR[4][4] = {}, accI[4][4] = {};
  for (int k0 = 0; k0 < NDIN; k0 += 16) {
    float4 ar4 = make_float4(0.f, 0.f, 0.f, 0.f), ai4 = make_float4(0.f, 0.f, 0.f, 0.f);
    if (m0 + am < NFREQ) {
      ar4 = *reinterpret_cast<const float4*>(Ar + (size_t)(m0 + am) * NDIN + k0 + ak);
      ai4 = *reinterpret_cast<const float4*>(Ai + (size_t)(m0 + am) * NDIN + k0 + ak);
    }
    Ars[ak + 0][am] = ar4.x; Ars[ak + 1][am] = ar4.y;
    Ars[ak + 2][am] = ar4.z; Ars[ak + 3][am] = ar4.w;
    Ais[ak + 0][am] = ai4.x; Ais[ak + 1][am] = ai4.y;
    Ais[ak + 2][am] = ai4.z; Ais[ak + 3][am] = ai4.w;
    *reinterpret_cast<float4*>(&Brs[bk][bn]) =
        *reinterpret_cast<const float4*>(Wr + (size_t)(k0 + bk) * NDIN + n0 + bn);
    *reinterpret_cast<float4*>(&Bis[bk][bn]) =
        *reinterpret_cast<const float4*>(Wi + (size_t)(k0 + bk) * NDIN + n0 + bn);
    __syncthreads();
#pragma unroll
    for (int kk = 0; kk < 16; ++kk) {
      float ar[4], ai[4], br[4], bi[4];
#pragma unroll
      for (int i = 0; i < 4; ++i) { ar[i] = Ars[kk][ty * 4 + i]; ai[i] = Ais[kk][ty * 4 + i]; }
#pragma unroll
      for (int j = 0; j < 4; ++j) { br[j] = Brs[kk][tx * 4 + j]; bi[j] = Bis[kk][tx * 4 + j]; }
#pragma unroll
      for (int i = 0; i < 4; ++i)
#pragma unroll
        for (int j = 0; j < 4; ++j) {
          accR[i][j] += ar[i] * br[j] - ai[i] * bi[j];
          accI[i][j] += ai[i] * br[j] + ar[i] * bi[j];
        }
    }
    __syncthreads();
  }
#pragma unroll
  for (int i = 0; i < 4; ++i) {
    int gm = m0 + ty * 4 + i;
    if (gm >= NFREQ) continue;
#pragma unroll
    for (int j = 0; j < 4; ++j) {
      int gn = n0 + tx * 4 + j;
      size_t o = ((size_t)b * NFREQ + gm) * NDIN + gn;
      xre[o] = fmaxf(accR[i][j] + rb[gn], 0.f);
      xim[o] = fmaxf(accI[i][j] + ib[gn], 0.f);
    }
  }
}

// irfft: ff[b,l,d] = (1/24) * sum_k w_k (xre*cos - xim*sin), w=1 at k=0,288 else 2
__global__ void idft_kernel(const float* __restrict__ xre,
                            const float* __restrict__ xim,
                            const float* __restrict__ ct,
                            const float* __restrict__ st,
                            float* __restrict__ ff) {
  int l = blockIdx.x, b = blockIdx.y, tid = threadIdx.x;
  __shared__ float wc[NFREQ], wsn[NFREQ];
  for (int k = tid; k < NFREQ; k += 256) {
    int idx = (k * l) % NL;
    float w = (k == 0 || k == NFREQ - 1) ? 1.f : 2.f;
    wc[k] = w * ct[idx]; wsn[k] = w * st[idx];
  }
  __syncthreads();
  int d0 = tid, d1 = tid + 256;
  float a0 = 0.f, a1 = 0.f;
  const float* xr_ = xre + (size_t)b * NFREQ * NDIN;
  const float* xi_ = xim + (size_t)b * NFREQ * NDIN;
  for (int k = 0; k < NFREQ; ++k) {
    float c = wc[k], s = wsn[k];
    a0 += xr_[(size_t)k * NDIN + d0] * c - xi_[(size_t)k * NDIN + d0] * s;
    a1 += xr_[(size_t)k * NDIN + d1] * c - xi_[(size_t)k * NDIN + d1] * s;
  }
  size_t o = ((size_t)b * NL + l) * NDIN;
  ff[o + d0] = a0 * (1.f / 24.f);
  ff[o + d1] = a1 * (1.f / 24.f);
}

extern "C" void kernel_launch(void* const* d_in, const int* in_sizes, int n_in,
                              void* d_out, int out_size, void* d_ws, size_t ws_size,
                              hipStream_t stream) {
  const float* x      = (const float*)d_in[0];
  const float* ln1_g  = (const float*)d_in[1];
  const float* ln1_b  = (const float*)d_in[2];
  const float* mln_g  = (const float*)d_in[3];
  const float* mln_b  = (const float*)d_in[4];
  const float* w_in   = (const float*)d_in[5];
  const float* conv_w = (const float*)d_in[6];
  const float* conv_b = (const float*)d_in[7];
  const float* w_xprj = (const float*)d_in[8];
  const float* w_dt   = (const float*)d_in[9];
  const float* b_dt   = (const float*)d_in[10];
  const float* A_log  = (const float*)d_in[11];
  const float* Dp     = (const float*)d_in[12];
  const float* w_out  = (const float*)d_in[13];
  const float* ln2_g  = (const float*)d_in[14];
  const float* ln2_b  = (const float*)d_in[15];
  const float* fc1_w  = (const float*)d_in[16];
  const float* bn1_s  = (const float*)d_in[17];
  const float* bn1_b  = (const float*)d_in[18];
  const float* Wr     = (const float*)d_in[19];
  const float* Wi     = (const float*)d_in[20];
  const float* rb     = (const float*)d_in[21];
  const float* ib     = (const float*)d_in[22];
  const float* fc2_w  = (const float*)d_in[23];
  const float* bn2_s  = (const float*)d_in[24];
  const float* bn2_b  = (const float*)d_in[25];

  float* ws   = (float*)d_ws;
  float* h    = ws + OFF_H;
  float* xr   = ws + OFF_XR;
  float* xc   = ws + OFF_XC;
  float* xdbl = ws + OFF_XDBL;
  float* delta= ws + OFF_DELTA;
  float* yf   = ws + OFF_YF;
  float* x2   = ws + OFF_X2;
  float* h2   = ws + OFF_H2;
  float* f    = ws + OFF_F;
  float* RF   = ws + OFF_RF;
  float* IFm  = ws + OFF_IF;
  float* xre  = ws + OFF_XRE;
  float* xim  = ws + OFF_XIM;
  float* ff   = ws + OFF_FF;
  float* ct   = ws + OFF_CT;
  float* st   = ws + OFF_ST;
  float* out  = (float*)d_out;

  trig_kernel<<<1, NL, 0, stream>>>(ct, st);
  // h = LN(LN(x))
  ln_kernel<<<NTOK, 64, 0, stream>>>(x, h, ln1_g, ln1_b, mln_g, mln_b, 1);
  // xr = h @ w_in  (2304x1024)
  gemm_f32<<<dim3(16, 36), 256, 0, stream>>>(h, NC, w_in, NWIN, xr, NWIN,
                                             NTOK, NWIN, NC, 0, nullptr, nullptr, nullptr, 0);
  // xc = silu(causal depthwise conv(xm) + conv_b)
  conv_silu_kernel<<<(NTOK * NDIN + 255) / 256, 256, 0, stream>>>(xr, conv_w, conv_b, xc);
  // x_dbl = xc @ w_xproj (2304x112)
  gemm_f32<<<dim3(2, 36), 256, 0, stream>>>(xc, NDIN, w_xprj, NXD, xdbl, NXD,
                                            NTOK, NXD, NDIN, 0, nullptr, nullptr, nullptr, 0);
  // delta = softplus(dt @ w_dt + b_dt)  (dt = x_dbl[:, :16])
  gemm_f32<<<dim3(8, 36), 256, 0, stream>>>(xdbl, NXD, w_dt, NDIN, delta, NDIN,
                                            NTOK, NDIN, NDTR, 1, nullptr, b_dt, nullptr, 0);
  // yf = (selective_scan + u*D) * silu(res)
  scan_kernel<<<NB * NDIN, 64, 0, stream>>>(delta, xc, xdbl, A_log, Dp, xr, yf);
  // x2 = x + yf @ w_out
  gemm_f32<<<dim3(4, 36), 256, 0, stream>>>(yf, NDIN, w_out, NC, x2, NC,
                                            NTOK, NC, NDIN, 2, nullptr, nullptr, x, NC);
  // h2 = LN(x2)
  ln_kernel<<<NTOK, 64, 0, stream>>>(x2, h2, ln2_g, ln2_b, nullptr, nullptr, 0);
  // f = relu(h2 @ fc1_w * bn1_s + bn1_b)
  gemm_f32<<<dim3(8, 36), 256, 0, stream>>>(h2, NC, fc1_w, NDIN, f, NDIN,
                                            NTOK, NDIN, NC, 3, bn1_s, bn1_b, nullptr, 0);
  // rfft (scaled)
  dft_fwd_kernel<<<dim3(NFREQ, NB), 256, 0, stream>>>(f, ct, st, RF, IFm);
  // complex mix + relu
  mix_kernel<<<dim3(8, 5, NB), 256, 0, stream>>>(RF, IFm, Wr, Wi, rb, ib, xre, xim);
  // irfft (scaled)
  idft_kernel<<<dim3(NL, NB), 256, 0, stream>>>(xre, xim, ct, st, ff);
  // out = x2 + ff @ fc2_w * bn2_s + bn2_b
  gemm_f32<<<dim3(4, 36), 256, 0, stream>>>(ff, NDIN, fc2_w, NC, out, NC,
                                            NTOK, NC, NDIN, 4, bn2_s, bn2_b, x2, NC);
}

// Round 2
// 628.142 us; speedup vs baseline: 1.5682x; 1.5682x over previous
//
#include <hip/hip_runtime.h>
#include <math.h>

#define NB 4
#define NL 576
#define NC 256
#define NTOK (NB*NL)      // 2304
#define NDIN 512
#define NXD 112
#define NDTR 16
#define NDST 48
#define NFREQ 289
#define NWIN 1024         // w_in output width

// ---- workspace layout (floats) ----
#define OFF_H     0u
#define OFF_XR    589824u
#define OFF_XC    2949120u
#define OFF_XDBL  4128768u
#define OFF_DELTA 4386816u
#define OFF_YF    5566464u
#define OFF_X2    6746112u
#define OFF_H2    7335936u
#define OFF_F     7925760u
#define OFF_RF    9105408u
#define OFF_IF    9697280u
#define OFF_XRE   10289152u
#define OFF_XIM   10881024u
#define OFF_FF    11472896u
#define OFF_CT    12652544u
#define OFF_ST    12653120u

__device__ __forceinline__ float wave_sum(float v) {
#pragma unroll
  for (int o = 32; o > 0; o >>= 1) v += __shfl_xor(v, o);
  return v;
}

__global__ void trig_kernel(float* ct, float* st) {
  int i = threadIdx.x;
  if (i < NL) {
    double a = (6.283185307179586476925286766559 * (double)i) / (double)NL;
    ct[i] = (float)cos(a);
    st[i] = (float)sin(a);
  }
}

// one wave per token row; C=256 -> 4 elems/lane. dbl=1: two chained LNs.
__global__ void ln_kernel(const float* __restrict__ in, float* __restrict__ out,
                          const float* __restrict__ g1, const float* __restrict__ b1,
                          const float* __restrict__ g2, const float* __restrict__ b2,
                          int dbl) {
  int row = blockIdx.x, lane = threadIdx.x;
  const float* p = in + (size_t)row * NC;
  float v[4];
#pragma unroll
  for (int j = 0; j < 4; ++j) v[j] = p[lane + j * 64];
  float s = wave_sum(v[0] + v[1] + v[2] + v[3]);
  float m = s * (1.f / NC);
  float q = 0.f;
#pragma unroll
  for (int j = 0; j < 4; ++j) { float d = v[j] - m; q += d * d; }
  q = wave_sum(q);
  float rs = 1.f / sqrtf(q * (1.f / NC) + 1e-3f);
#pragma unroll
  for (int j = 0; j < 4; ++j) {
    int c = lane + j * 64;
    v[j] = (v[j] - m) * rs * g1[c] + b1[c];
  }
  if (dbl) {
    s = wave_sum(v[0] + v[1] + v[2] + v[3]);
    m = s * (1.f / NC);
    q = 0.f;
#pragma unroll
    for (int j = 0; j < 4; ++j) { float d = v[j] - m; q += d * d; }
    q = wave_sum(q);
    rs = 1.f / sqrtf(q * (1.f / NC) + 1e-3f);
#pragma unroll
    for (int j = 0; j < 4; ++j) {
      int c = lane + j * 64;
      v[j] = (v[j] - m) * rs * g2[c] + b2[c];
    }
  }
  float* o = out + (size_t)row * NC;
#pragma unroll
  for (int j = 0; j < 4; ++j) o[lane + j * 64] = v[j];
}

// generic tiled f32 GEMM: C[M,N] = A[M,K(lda)] @ B[K,N(ldb)], fused epilogues.
// mode 0: store; 1: softplus(v+bias); 2: v+add; 3: relu(v*scl+bias); 4: v*scl+bias+add
__global__ __launch_bounds__(256) void gemm_f32(
    const float* __restrict__ A, int lda, const float* __restrict__ B, int ldb,
    float* __restrict__ C, int ldc, int M, int N, int K, int mode,
    const float* __restrict__ scl, const float* __restrict__ bias,
    const float* __restrict__ add, int ldadd) {
  __shared__ float As[16][65];   // [k][m]
  __shared__ float Bs[16][68];   // [k][n]
  int tid = threadIdx.x;
  int tx = tid & 15, ty = tid >> 4;
  int m0 = blockIdx.y * 64, n0 = blockIdx.x * 64;
  int am = tid >> 2, ak = (tid & 3) * 4;
  int bk = tid >> 4, bn = (tid & 15) * 4;
  float acc[4][4] = {};
  for (int k0 = 0; k0 < K; k0 += 16) {
    float4 av = make_float4(0.f, 0.f, 0.f, 0.f);
    if (m0 + am < M)
      av = *reinterpret_cast<const float4*>(A + (size_t)(m0 + am) * lda + k0 + ak);
    As[ak + 0][am] = av.x; As[ak + 1][am] = av.y;
    As[ak + 2][am] = av.z; As[ak + 3][am] = av.w;
    float4 bv = make_float4(0.f, 0.f, 0.f, 0.f);
    if (n0 + bn < N)
      bv = *reinterpret_cast<const float4*>(B + (size_t)(k0 + bk) * ldb + n0 + bn);
    *reinterpret_cast<float4*>(&Bs[bk][bn]) = bv;
    __syncthreads();
#pragma unroll
    for (int kk = 0; kk < 16; ++kk) {
      float a[4], b[4];
#pragma unroll
      for (int i = 0; i < 4; ++i) a[i] = As[kk][ty * 4 + i];
#pragma unroll
      for (int j = 0; j < 4; ++j) b[j] = Bs[kk][tx * 4 + j];
#pragma unroll
      for (int i = 0; i < 4; ++i)
#pragma unroll
        for (int j = 0; j < 4; ++j) acc[i][j] += a[i] * b[j];
    }
    __syncthreads();
  }
#pragma unroll
  for (int i = 0; i < 4; ++i) {
    int gm = m0 + ty * 4 + i;
    if (gm >= M) continue;
#pragma unroll
    for (int j = 0; j < 4; ++j) {
      int gn = n0 + tx * 4 + j;
      if (gn >= N) continue;
      float v = acc[i][j];
      if (mode == 1) { v += bias[gn]; v = fmaxf(v, 0.f) + log1pf(expf(-fabsf(v))); }
      else if (mode == 2) { v += add[(size_t)gm * ldadd + gn]; }
      else if (mode == 3) { v = fmaxf(v * scl[gn] + bias[gn], 0.f); }
      else if (mode == 4) { v = v * scl[gn] + bias[gn] + add[(size_t)gm * ldadd + gn]; }
      C[(size_t)gm * ldc + gn] = v;
    }
  }
}

// causal depthwise conv (width 4) over xm = xr[:, :512], then silu.
__global__ void conv_silu_kernel(const float* __restrict__ xr,
                                 const float* __restrict__ cw,
                                 const float* __restrict__ cb,
                                 float* __restrict__ xc) {
  int id = blockIdx.x * blockDim.x + threadIdx.x;
  if (id >= NTOK * NDIN) return;
  int d = id & 511, row = id >> 9;
  int b = row / NL, l = row % NL;
  float acc = cb[d];
#pragma unroll
  for (int k = 0; k < 4; ++k) {
    int l2 = l - 3 + k;
    if (l2 >= 0) acc += xr[((size_t)(b * NL + l2)) * NWIN + d] * cw[k * NDIN + d];
  }
  xc[(size_t)row * NDIN + d] = acc / (1.f + expf(-acc));
}

// selective scan via block-parallel prefix sums.
// One block of 576 threads (9 waves) per (b,d); thread = sequence position l.
// Reference-faithful: Tsuf suffix-sum, e=exp(An*Tsuf), xs=cumsum(w)/(e+1e-12).
__global__ __launch_bounds__(576) void scan2_kernel(
    const float* __restrict__ delta, const float* __restrict__ xc,
    const float* __restrict__ xdbl, const float* __restrict__ A_log,
    const float* __restrict__ Dp, const float* __restrict__ xr,
    float* __restrict__ yf) {
  __shared__ float part[9];        // wave partials (Tsuf scan)
  __shared__ float part8[8][9];    // wave partials (8 batched scans)
  int b = blockIdx.x >> 9, d = blockIdx.x & 511;
  int l = threadIdx.x;
  int lane = l & 63, wv = l >> 6;  // 9 waves
  size_t row = (size_t)(b * NL + l);
  float dl = delta[row * NDIN + d];
  float ul = xc[row * NDIN + d];
  float rl = xr[row * NWIN + NDIN + d];
  // ---- block inclusive scan of delta -> Tsuf = total - inclusive ----
  float s = dl;
#pragma unroll
  for (int o = 1; o < 64; o <<= 1) { float t = __shfl_up(s, o); if (lane >= o) s += t; }
  if (lane == 63) part[wv] = s;
  __syncthreads();
  float off = 0.f, tot = 0.f;
#pragma unroll
  for (int i = 0; i < 9; ++i) { float p = part[i]; tot += p; if (i < wv) off += p; }
  float Tsuf = tot - (s + off);
  __syncthreads();

  const float* xrow = xdbl + row * NXD;
  const float* Arow = A_log + (size_t)d * NDST;
  float y = 0.f;
  for (int c = 0; c < 6; ++c) {
    // B/C values for THIS thread's row only -> registers, no LDS
    float4 b0 = *reinterpret_cast<const float4*>(xrow + NDTR + c * 8);
    float4 b1 = *reinterpret_cast<const float4*>(xrow + NDTR + c * 8 + 4);
    float4 c0 = *reinterpret_cast<const float4*>(xrow + NDTR + NDST + c * 8);
    float4 c1 = *reinterpret_cast<const float4*>(xrow + NDTR + NDST + c * 8 + 4);
    float bb[8] = {b0.x, b0.y, b0.z, b0.w, b1.x, b1.y, b1.z, b1.w};
    float cc[8] = {c0.x, c0.y, c0.z, c0.w, c1.x, c1.y, c1.z, c1.w};
    float e[8], w[8];
#pragma unroll
    for (int j = 0; j < 8; ++j) {
      float An = -expf(Arow[c * 8 + j]);
      e[j] = expf(An * Tsuf);
      w[j] = dl * ul * bb[j] * e[j];
    }
    // batched intra-wave inclusive scans
#pragma unroll
    for (int o = 1; o < 64; o <<= 1) {
#pragma unroll
      for (int j = 0; j < 8; ++j) {
        float t = __shfl_up(w[j], o);
        if (lane >= o) w[j] += t;
      }
    }
    if (lane == 63) {
#pragma unroll
      for (int j = 0; j < 8; ++j) part8[j][wv] = w[j];
    }
    __syncthreads();
#pragma unroll
    for (int j = 0; j < 8; ++j) {
      float o2 = 0.f;
#pragma unroll
      for (int i = 0; i < 9; ++i) { float p = part8[j][i]; if (i < wv) o2 += p; }
      float ps = w[j] + o2;
      y += __fdividef(ps, e[j] + 1e-12f) * cc[j];
    }
    __syncthreads();
  }
  float yv = y + ul * Dp[d];
  float sr = rl / (1.f + expf(-rl));
  yf[row * NDIN + d] = yv * sr;
}

// forward DFT along L (rfft): RF/IF[b,k,c], trig from table via (k*l)%576.
__global__ void dft_fwd_kernel(const float* __restrict__ f,
                               const float* __restrict__ ct,
                               const float* __restrict__ st,
                               float* __restrict__ RF, float* __restrict__ IF) {
  int k = blockIdx.x, b = blockIdx.y, tid = threadIdx.x;
  __shared__ float lc[NL], ls[NL];
  for (int l = tid; l < NL; l += 256) {
    int idx = (k * l) % NL;
    lc[l] = ct[idx]; ls[l] = st[idx];
  }
  __syncthreads();
  int c0 = tid, c1 = tid + 256;
  float r0 = 0.f, i0 = 0.f, r1 = 0.f, i1 = 0.f;
  const float* fb = f + (size_t)b * NL * NDIN;
  for (int l = 0; l < NL; ++l) {
    float cl = lc[l], sl = ls[l];
    float v0 = fb[(size_t)l * NDIN + c0];
    float v1 = fb[(size_t)l * NDIN + c1];
    r0 += v0 * cl; i0 -= v0 * sl;
    r1 += v1 * cl; i1 -= v1 * sl;
  }
  size_t o = ((size_t)b * NFREQ + k) * NDIN;
  RF[o + c0] = r0 * (1.f / 24.f); RF[o + c1] = r1 * (1.f / 24.f);
  IF[o + c0] = i0 * (1.f / 24.f); IF[o + c1] = i1 * (1.f / 24.f);
}

// complex channel mix: xre=relu(RF@Wr - IF@Wi + rb), xim=relu(IF@Wr + RF@Wi + ib)
__global__ __launch_bounds__(256) void mix_kernel(
    const float* __restrict__ RF, const float* __restrict__ IFm,
    const float* __restrict__ Wr, const float* __restrict__ Wi,
    const float* __restrict__ rb, const float* __restrict__ ib,
    float* __restrict__ xre, float* __restrict__ xim) {
  __shared__ float Ars[16][65], Ais[16][65];
  __shared__ float Brs[16][68], Bis[16][68];
  int b = blockIdx.z;
  int m0 = blockIdx.y * 64, n0 = blockIdx.x * 64;
  int tid = threadIdx.x;
  int tx = tid & 15, ty = tid >> 4;
  int am = tid >> 2, ak = (tid & 3) * 4;
  int bk = tid >> 4, bn = (tid & 15) * 4;
  const float* Ar = RF + (size_t)b * NFREQ * NDIN;
  const float* Ai = IFm + (size_t)b * NFREQ * NDIN;
  float accR[4][4] = {}, accI[4][4] = {};
  for (int k0 = 0; k0 < NDIN; k0 += 16) {
    float4 ar4 = make_float4(0.f, 0.f, 0.f, 0.f), ai4 = make_float4(0.f, 0.f, 0.f, 0.f);
    if (m0 + am < NFREQ) {
      ar4 = *reinterpret_cast<const float4*>(Ar + (size_t)(m0 + am) * NDIN + k0 + ak);
      ai4 = *reinterpret_cast<const float4*>(Ai + (size_t)(m0 + am) * NDIN + k0 + ak);
    }
    Ars[ak + 0][am] = ar4.x; Ars[ak + 1][am] = ar4.y;
    Ars[ak + 2][am] = ar4.z; Ars[ak + 3][am] = ar4.w;
    Ais[ak + 0][am] = ai4.x; Ais[ak + 1][am] = ai4.y;
    Ais[ak + 2][am] = ai4.z; Ais[ak + 3][am] = ai4.w;
    *reinterpret_cast<float4*>(&Brs[bk][bn]) =
        *reinterpret_cast<const float4*>(Wr + (size_t)(k0 + bk) * NDIN + n0 + bn);
    *reinterpret_cast<float4*>(&Bis[bk][bn]) =
        *reinterpret_cast<const float4*>(Wi + (size_t)(k0 + bk) * NDIN + n0 + bn);
    __syncthreads();
#pragma unroll
    for (int kk = 0; kk < 16; ++kk) {
      float ar[4], ai[4], br[4], bi[4];
#pragma unroll
      for (int i = 0; i < 4; ++i) { ar[i] = Ars[kk][ty * 4 + i]; ai[i] = Ais[kk][ty * 4 + i]; }
#pragma unroll
      for (int j = 0; j < 4; ++j) { br[j] = Brs[kk][tx * 4 + j]; bi[j] = Bis[kk][tx * 4 + j]; }
#pragma unroll
      for (int i = 0; i < 4; ++i)
#pragma unroll
        for (int j = 0; j < 4; ++j) {
          accR[i][j] += ar[i] * br[j] - ai[i] * bi[j];
          accI[i][j] += ai[i] * br[j] + ar[i] * bi[j];
        }
    }
    __syncthreads();
  }
#pragma unroll
  for (int i = 0; i < 4; ++i) {
    int gm = m0 + ty * 4 + i;
    if (gm >= NFREQ) continue;
#pragma unroll
    for (int j = 0; j < 4; ++j) {
      int gn = n0 + tx * 4 + j;
      size_t o = ((size_t)b * NFREQ + gm) * NDIN + gn;
      xre[o] = fmaxf(accR[i][j] + rb[gn], 0.f);
      xim[o] = fmaxf(accI[i][j] + ib[gn], 0.f);
    }
  }
}

// irfft: ff[b,l,d] = (1/24) * sum_k w_k (xre*cos - xim*sin), w=1 at k=0,288 else 2
__global__ void idft_kernel(const float* __restrict__ xre,
                            const float* __restrict__ xim,
                            const float* __restrict__ ct,
                            const float* __restrict__ st,
                            float* __restrict__ ff) {
  int l = blockIdx.x, b = blockIdx.y, tid = threadIdx.x;
  __shared__ float wc[NFREQ], wsn[NFREQ];
  for (int k = tid; k < NFREQ; k += 256) {
    int idx = (k * l) % NL;
    float w = (k == 0 || k == NFREQ - 1) ? 1.f : 2.f;
    wc[k] = w * ct[idx]; wsn[k] = w * st[idx];
  }
  __syncthreads();
  int d0 = tid, d1 = tid + 256;
  float a0 = 0.f, a1 = 0.f;
  const float* xr_ = xre + (size_t)b * NFREQ * NDIN;
  const float* xi_ = xim + (size_t)b * NFREQ * NDIN;
  for (int k = 0; k < NFREQ; ++k) {
    float c = wc[k], s = wsn[k];
    a0 += xr_[(size_t)k * NDIN + d0] * c - xi_[(size_t)k * NDIN + d0] * s;
    a1 += xr_[(size_t)k * NDIN + d1] * c - xi_[(size_t)k * NDIN + d1] * s;
  }
  size_t o = ((size_t)b * NL + l) * NDIN;
  ff[o + d0] = a0 * (1.f / 24.f);
  ff[o + d1] = a1 * (1.f / 24.f);
}

extern "C" void kernel_launch(void* const* d_in, const int* in_sizes, int n_in,
                              void* d_out, int out_size, void* d_ws, size_t ws_size,
                              hipStream_t stream) {
  const float* x      = (const float*)d_in[0];
  const float* ln1_g  = (const float*)d_in[1];
  const float* ln1_b  = (const float*)d_in[2];
  const float* mln_g  = (const float*)d_in[3];
  const float* mln_b  = (const float*)d_in[4];
  const float* w_in   = (const float*)d_in[5];
  const float* conv_w = (const float*)d_in[6];
  const float* conv_b = (const float*)d_in[7];
  const float* w_xprj = (const float*)d_in[8];
  const float* w_dt   = (const float*)d_in[9];
  const float* b_dt   = (const float*)d_in[10];
  const float* A_log  = (const float*)d_in[11];
  const float* Dp     = (const float*)d_in[12];
  const float* w_out  = (const float*)d_in[13];
  const float* ln2_g  = (const float*)d_in[14];
  const float* ln2_b  = (const float*)d_in[15];
  const float* fc1_w  = (const float*)d_in[16];
  const float* bn1_s  = (const float*)d_in[17];
  const float* bn1_b  = (const float*)d_in[18];
  const float* Wr     = (const float*)d_in[19];
  const float* Wi     = (const float*)d_in[20];
  const float* rb     = (const float*)d_in[21];
  const float* ib     = (const float*)d_in[22];
  const float* fc2_w  = (const float*)d_in[23];
  const float* bn2_s  = (const float*)d_in[24];
  const float* bn2_b  = (const float*)d_in[25];

  float* ws   = (float*)d_ws;
  float* h    = ws + OFF_H;
  float* xr   = ws + OFF_XR;
  float* xc   = ws + OFF_XC;
  float* xdbl = ws + OFF_XDBL;
  float* delta= ws + OFF_DELTA;
  float* yf   = ws + OFF_YF;
  float* x2   = ws + OFF_X2;
  float* h2   = ws + OFF_H2;
  float* f    = ws + OFF_F;
  float* RF   = ws + OFF_RF;
  float* IFm  = ws + OFF_IF;
  float* xre  = ws + OFF_XRE;
  float* xim  = ws + OFF_XIM;
  float* ff   = ws + OFF_FF;
  float* ct   = ws + OFF_CT;
  float* st   = ws + OFF_ST;
  float* out  = (float*)d_out;

  trig_kernel<<<1, NL, 0, stream>>>(ct, st);
  // h = LN(LN(x))
  ln_kernel<<<NTOK, 64, 0, stream>>>(x, h, ln1_g, ln1_b, mln_g, mln_b, 1);
  // xr = h @ w_in  (2304x1024)
  gemm_f32<<<dim3(16, 36), 256, 0, stream>>>(h, NC, w_in, NWIN, xr, NWIN,
                                             NTOK, NWIN, NC, 0, nullptr, nullptr, nullptr, 0);
  // xc = silu(causal depthwise conv(xm) + conv_b)
  conv_silu_kernel<<<(NTOK * NDIN + 255) / 256, 256, 0, stream>>>(xr, conv_w, conv_b, xc);
  // x_dbl = xc @ w_xproj (2304x112)
  gemm_f32<<<dim3(2, 36), 256, 0, stream>>>(xc, NDIN, w_xprj, NXD, xdbl, NXD,
                                            NTOK, NXD, NDIN, 0, nullptr, nullptr, nullptr, 0);
  // delta = softplus(dt @ w_dt + b_dt)  (dt = x_dbl[:, :16])
  gemm_f32<<<dim3(8, 36), 256, 0, stream>>>(xdbl, NXD, w_dt, NDIN, delta, NDIN,
                                            NTOK, NDIN, NDTR, 1, nullptr, b_dt, nullptr, 0);
  // yf = (selective_scan + u*D) * silu(res)  -- block-parallel prefix-sum scan
  scan2_kernel<<<NB * NDIN, 576, 0, stream>>>(delta, xc, xdbl, A_log, Dp, xr, yf);
  // x2 = x + yf @ w_out
  gemm_f32<<<dim3(4, 36), 256, 0, stream>>>(yf, NDIN, w_out, NC, x2, NC,
                                            NTOK, NC, NDIN, 2, nullptr, nullptr, x, NC);
  // h2 = LN(x2)
  ln_kernel<<<NTOK, 64, 0, stream>>>(x2, h2, ln2_g, ln2_b, nullptr, nullptr, 0);
  // f = relu(h2 @ fc1_w * bn1_s + bn1_b)
  gemm_f32<<<dim3(8, 36), 256, 0, stream>>>(h2, NC, fc1_w, NDIN, f, NDIN,
                                            NTOK, NDIN, NC, 3, bn1_s, bn1_b, nullptr, 0);
  // rfft (scaled)
  dft_fwd_kernel<<<dim3(NFREQ, NB), 256, 0, stream>>>(f, ct, st, RF, IFm);
  // complex mix + relu
  mix_kernel<<<dim3(8, 5, NB), 256, 0, stream>>>(RF, IFm, Wr, Wi, rb, ib, xre, xim);
  // irfft (scaled)
  idft_kernel<<<dim3(NL, NB), 256, 0, stream>>>(xre, xim, ct, st, ff);
  // out = x2 + ff @ fc2_w * bn2_s + bn2_b
  gemm_f32<<<dim3(4, 36), 256, 0, stream>>>(ff, NDIN, fc2_w, NC, out, NC,
                                            NTOK, NC, NDIN, 4, bn2_s, bn2_b, x2, NC);
}

// Round 3
// 574.223 us; speedup vs baseline: 1.7155x; 1.0939x over previous
//
#include <hip/hip_runtime.h>
#include <math.h>

#define NB 4
#define NL 576
#define NC 256
#define NTOK (NB*NL)      // 2304
#define NDIN 512
#define NXD 112
#define NDTR 16
#define NDST 48
#define NFREQ 289
#define NWIN 1024         // w_in output width

// ---- workspace layout (floats) ----
#define OFF_H     0u
#define OFF_XR    589824u
#define OFF_XC    2949120u
#define OFF_XDBL  4128768u
#define OFF_DELTA 4386816u
#define OFF_YF    5566464u
#define OFF_X2    6746112u
#define OFF_H2    7335936u
#define OFF_F     7925760u
#define OFF_RF    9105408u
#define OFF_IF    9697280u
#define OFF_XRE   10289152u
#define OFF_XIM   10881024u
#define OFF_FF    11472896u
#define OFF_CT    12652544u
#define OFF_ST    12653120u

__device__ __forceinline__ float wave_sum(float v) {
#pragma unroll
  for (int o = 32; o > 0; o >>= 1) v += __shfl_xor(v, o);
  return v;
}

// 64-lane inclusive prefix sum, no LDS: 4 DPP row_shr adds (per-16 scan)
// + 3 readlane row-total broadcasts.
__device__ __forceinline__ float wave_iscan(float x, int lane) {
  x += __int_as_float(__builtin_amdgcn_update_dpp(0, __float_as_int(x), 0x111, 0xf, 0xf, true));
  x += __int_as_float(__builtin_amdgcn_update_dpp(0, __float_as_int(x), 0x112, 0xf, 0xf, true));
  x += __int_as_float(__builtin_amdgcn_update_dpp(0, __float_as_int(x), 0x114, 0xf, 0xf, true));
  x += __int_as_float(__builtin_amdgcn_update_dpp(0, __float_as_int(x), 0x118, 0xf, 0xf, true));
  int xi = __float_as_int(x);
  float s15 = __int_as_float(__builtin_amdgcn_readlane(xi, 15));
  float s31 = __int_as_float(__builtin_amdgcn_readlane(xi, 31));
  float s47 = __int_as_float(__builtin_amdgcn_readlane(xi, 47));
  float off = 0.f;
  if (lane >= 16) off += s15;
  if (lane >= 32) off += s31;
  if (lane >= 48) off += s47;
  return x + off;
}

__global__ void trig_kernel(float* ct, float* st) {
  int i = threadIdx.x;
  if (i < NL) {
    double a = (6.283185307179586476925286766559 * (double)i) / (double)NL;
    ct[i] = (float)cos(a);
    st[i] = (float)sin(a);
  }
}

// one wave per token row; C=256 -> 4 elems/lane. dbl=1: two chained LNs.
__global__ void ln_kernel(const float* __restrict__ in, float* __restrict__ out,
                          const float* __restrict__ g1, const float* __restrict__ b1,
                          const float* __restrict__ g2, const float* __restrict__ b2,
                          int dbl) {
  int row = blockIdx.x, lane = threadIdx.x;
  const float* p = in + (size_t)row * NC;
  float v[4];
#pragma unroll
  for (int j = 0; j < 4; ++j) v[j] = p[lane + j * 64];
  float s = wave_sum(v[0] + v[1] + v[2] + v[3]);
  float m = s * (1.f / NC);
  float q = 0.f;
#pragma unroll
  for (int j = 0; j < 4; ++j) { float d = v[j] - m; q += d * d; }
  q = wave_sum(q);
  float rs = 1.f / sqrtf(q * (1.f / NC) + 1e-3f);
#pragma unroll
  for (int j = 0; j < 4; ++j) {
    int c = lane + j * 64;
    v[j] = (v[j] - m) * rs * g1[c] + b1[c];
  }
  if (dbl) {
    s = wave_sum(v[0] + v[1] + v[2] + v[3]);
    m = s * (1.f / NC);
    q = 0.f;
#pragma unroll
    for (int j = 0; j < 4; ++j) { float d = v[j] - m; q += d * d; }
    q = wave_sum(q);
    rs = 1.f / sqrtf(q * (1.f / NC) + 1e-3f);
#pragma unroll
    for (int j = 0; j < 4; ++j) {
      int c = lane + j * 64;
      v[j] = (v[j] - m) * rs * g2[c] + b2[c];
    }
  }
  float* o = out + (size_t)row * NC;
#pragma unroll
  for (int j = 0; j < 4; ++j) o[lane + j * 64] = v[j];
}

// generic tiled f32 GEMM: C[M,N] = A[M,K(lda)] @ B[K,N(ldb)], fused epilogues.
// mode 0: store; 1: softplus(v+bias); 2: v+add; 3: relu(v*scl+bias); 4: v*scl+bias+add
__global__ __launch_bounds__(256) void gemm_f32(
    const float* __restrict__ A, int lda, const float* __restrict__ B, int ldb,
    float* __restrict__ C, int ldc, int M, int N, int K, int mode,
    const float* __restrict__ scl, const float* __restrict__ bias,
    const float* __restrict__ add, int ldadd) {
  __shared__ float As[16][65];   // [k][m]
  __shared__ float Bs[16][68];   // [k][n]
  int tid = threadIdx.x;
  int tx = tid & 15, ty = tid >> 4;
  int m0 = blockIdx.y * 64, n0 = blockIdx.x * 64;
  int am = tid >> 2, ak = (tid & 3) * 4;
  int bk = tid >> 4, bn = (tid & 15) * 4;
  float acc[4][4] = {};
  for (int k0 = 0; k0 < K; k0 += 16) {
    float4 av = make_float4(0.f, 0.f, 0.f, 0.f);
    if (m0 + am < M)
      av = *reinterpret_cast<const float4*>(A + (size_t)(m0 + am) * lda + k0 + ak);
    As[ak + 0][am] = av.x; As[ak + 1][am] = av.y;
    As[ak + 2][am] = av.z; As[ak + 3][am] = av.w;
    float4 bv = make_float4(0.f, 0.f, 0.f, 0.f);
    if (n0 + bn < N)
      bv = *reinterpret_cast<const float4*>(B + (size_t)(k0 + bk) * ldb + n0 + bn);
    *reinterpret_cast<float4*>(&Bs[bk][bn]) = bv;
    __syncthreads();
#pragma unroll
    for (int kk = 0; kk < 16; ++kk) {
      float a[4], b[4];
#pragma unroll
      for (int i = 0; i < 4; ++i) a[i] = As[kk][ty * 4 + i];
#pragma unroll
      for (int j = 0; j < 4; ++j) b[j] = Bs[kk][tx * 4 + j];
#pragma unroll
      for (int i = 0; i < 4; ++i)
#pragma unroll
        for (int j = 0; j < 4; ++j) acc[i][j] += a[i] * b[j];
    }
    __syncthreads();
  }
#pragma unroll
  for (int i = 0; i < 4; ++i) {
    int gm = m0 + ty * 4 + i;
    if (gm >= M) continue;
#pragma unroll
    for (int j = 0; j < 4; ++j) {
      int gn = n0 + tx * 4 + j;
      if (gn >= N) continue;
      float v = acc[i][j];
      if (mode == 1) { v += bias[gn]; v = fmaxf(v, 0.f) + log1pf(expf(-fabsf(v))); }
      else if (mode == 2) { v += add[(size_t)gm * ldadd + gn]; }
      else if (mode == 3) { v = fmaxf(v * scl[gn] + bias[gn], 0.f); }
      else if (mode == 4) { v = v * scl[gn] + bias[gn] + add[(size_t)gm * ldadd + gn]; }
      C[(size_t)gm * ldc + gn] = v;
    }
  }
}

// causal depthwise conv (width 4) over xm = xr[:, :512], then silu.
__global__ void conv_silu_kernel(const float* __restrict__ xr,
                                 const float* __restrict__ cw,
                                 const float* __restrict__ cb,
                                 float* __restrict__ xc) {
  int id = blockIdx.x * blockDim.x + threadIdx.x;
  if (id >= NTOK * NDIN) return;
  int d = id & 511, row = id >> 9;
  int b = row / NL, l = row % NL;
  float acc = cb[d];
#pragma unroll
  for (int k = 0; k < 4; ++k) {
    int l2 = l - 3 + k;
    if (l2 >= 0) acc += xr[((size_t)(b * NL + l2)) * NWIN + d] * cw[k * NDIN + d];
  }
  xc[(size_t)row * NDIN + d] = acc / (1.f + expf(-acc));
}

// selective scan via block-parallel prefix sums (DPP in-register wave scan).
// One block of 576 threads (9 waves) per (b,d); thread = sequence position l.
// Reference-faithful: Tsuf suffix-sum, e=exp(An*Tsuf), xs=cumsum(w)/(e+1e-12).
__global__ __launch_bounds__(576) void scan3_kernel(
    const float* __restrict__ delta, const float* __restrict__ xc,
    const float* __restrict__ xdbl, const float* __restrict__ A_log,
    const float* __restrict__ Dp, const float* __restrict__ xr,
    float* __restrict__ yf) {
  __shared__ float part[9];        // wave partials (Tsuf scan)
  __shared__ float part8[9][8];    // wave partials (8 batched scans)
  int b = blockIdx.x >> 9, d = blockIdx.x & 511;
  int l = threadIdx.x;
  int lane = l & 63, wv = l >> 6;  // 9 waves
  size_t row = (size_t)(b * NL + l);
  float dl = delta[row * NDIN + d];
  float ul = xc[row * NDIN + d];
  float rl = xr[row * NWIN + NDIN + d];
  // ---- block inclusive scan of delta -> Tsuf = total - inclusive ----
  float s = wave_iscan(dl, lane);
  if (lane == 63) part[wv] = s;
  __syncthreads();
  float off = 0.f, tot = 0.f;
#pragma unroll
  for (int i = 0; i < 9; ++i) { float p = part[i]; tot += p; if (i < wv) off += p; }
  float Tsuf = tot - (s + off);

  const float* xrow = xdbl + row * NXD;
  const float* Arow = A_log + (size_t)d * NDST;
  float dlul = dl * ul;
  float y = 0.f;
  for (int c = 0; c < 6; ++c) {
    // B/C values for THIS thread's row only -> registers, no LDS
    float4 b0 = *reinterpret_cast<const float4*>(xrow + NDTR + c * 8);
    float4 b1 = *reinterpret_cast<const float4*>(xrow + NDTR + c * 8 + 4);
    float4 c0 = *reinterpret_cast<const float4*>(xrow + NDTR + NDST + c * 8);
    float4 c1 = *reinterpret_cast<const float4*>(xrow + NDTR + NDST + c * 8 + 4);
    float bb[8] = {b0.x, b0.y, b0.z, b0.w, b1.x, b1.y, b1.z, b1.w};
    float cc[8] = {c0.x, c0.y, c0.z, c0.w, c1.x, c1.y, c1.z, c1.w};
    float e[8], w[8];
#pragma unroll
    for (int j = 0; j < 8; ++j) {
      float An = -__expf(Arow[c * 8 + j]);
      e[j] = __expf(An * Tsuf);
      w[j] = dlul * bb[j] * e[j];
    }
    // 8 batched in-register wave scans
#pragma unroll
    for (int j = 0; j < 8; ++j) w[j] = wave_iscan(w[j], lane);
    if (lane == 63) {
#pragma unroll
      for (int j = 0; j < 8; ++j) part8[wv][j] = w[j];
    }
    __syncthreads();
    // lanes 0..7 gather the preceding-wave offsets for state (lane)
    float po = 0.f;
    if (lane < 8) {
#pragma unroll
      for (int i = 0; i < 8; ++i) { if (i < wv) po += part8[i][lane]; }
    }
    int poi = __float_as_int(po);
#pragma unroll
    for (int j = 0; j < 8; ++j) {
      float offj = __int_as_float(__builtin_amdgcn_readlane(poi, j));
      float ps = w[j] + offj;
      y += __fdividef(ps, e[j] + 1e-12f) * cc[j];
    }
    __syncthreads();
  }
  float yv = y + ul * Dp[d];
  float sr = rl / (1.f + __expf(-rl));
  yf[row * NDIN + d] = yv * sr;
}

// forward DFT along L (rfft): RF/IF[b,k,c], trig from table via (k*l)%576.
__global__ void dft_fwd_kernel(const float* __restrict__ f,
                               const float* __restrict__ ct,
                               const float* __restrict__ st,
                               float* __restrict__ RF, float* __restrict__ IF) {
  int k = blockIdx.x, b = blockIdx.y, tid = threadIdx.x;
  __shared__ float lc[NL], ls[NL];
  for (int l = tid; l < NL; l += 256) {
    int idx = (k * l) % NL;
    lc[l] = ct[idx]; ls[l] = st[idx];
  }
  __syncthreads();
  int c0 = tid, c1 = tid + 256;
  float r0 = 0.f, i0 = 0.f, r1 = 0.f, i1 = 0.f;
  const float* fb = f + (size_t)b * NL * NDIN;
  for (int l = 0; l < NL; ++l) {
    float cl = lc[l], sl = ls[l];
    float v0 = fb[(size_t)l * NDIN + c0];
    float v1 = fb[(size_t)l * NDIN + c1];
    r0 += v0 * cl; i0 -= v0 * sl;
    r1 += v1 * cl; i1 -= v1 * sl;
  }
  size_t o = ((size_t)b * NFREQ + k) * NDIN;
  RF[o + c0] = r0 * (1.f / 24.f); RF[o + c1] = r1 * (1.f / 24.f);
  IF[o + c0] = i0 * (1.f / 24.f); IF[o + c1] = i1 * (1.f / 24.f);
}

// complex channel mix: xre=relu(RF@Wr - IF@Wi + rb), xim=relu(IF@Wr + RF@Wi + ib)
__global__ __launch_bounds__(256) void mix_kernel(
    const float* __restrict__ RF, const float* __restrict__ IFm,
    const float* __restrict__ Wr, const float* __restrict__ Wi,
    const float* __restrict__ rb, const float* __restrict__ ib,
    float* __restrict__ xre, float* __restrict__ xim) {
  __shared__ float Ars[16][65], Ais[16][65];
  __shared__ float Brs[16][68], Bis[16][68];
  int b = blockIdx.z;
  int m0 = blockIdx.y * 64, n0 = blockIdx.x * 64;
  int tid = threadIdx.x;
  int tx = tid & 15, ty = tid >> 4;
  int am = tid >> 2, ak = (tid & 3) * 4;
  int bk = tid >> 4, bn = (tid & 15) * 4;
  const float* Ar = RF + (size_t)b * NFREQ * NDIN;
  const float* Ai = IFm + (size_t)b * NFREQ * NDIN;
  float accR[4][4] = {}, accI[4][4] = {};
  for (int k0 = 0; k0 < NDIN; k0 += 16) {
    float4 ar4 = make_float4(0.f, 0.f, 0.f, 0.f), ai4 = make_float4(0.f, 0.f, 0.f, 0.f);
    if (m0 + am < NFREQ) {
      ar4 = *reinterpret_cast<const float4*>(Ar + (size_t)(m0 + am) * NDIN + k0 + ak);
      ai4 = *reinterpret_cast<const float4*>(Ai + (size_t)(m0 + am) * NDIN + k0 + ak);
    }
    Ars[ak + 0][am] = ar4.x; Ars[ak + 1][am] = ar4.y;
    Ars[ak + 2][am] = ar4.z; Ars[ak + 3][am] = ar4.w;
    Ais[ak + 0][am] = ai4.x; Ais[ak + 1][am] = ai4.y;
    Ais[ak + 2][am] = ai4.z; Ais[ak + 3][am] = ai4.w;
    *reinterpret_cast<float4*>(&Brs[bk][bn]) =
        *reinterpret_cast<const float4*>(Wr + (size_t)(k0 + bk) * NDIN + n0 + bn);
    *reinterpret_cast<float4*>(&Bis[bk][bn]) =
        *reinterpret_cast<const float4*>(Wi + (size_t)(k0 + bk) * NDIN + n0 + bn);
    __syncthreads();
#pragma unroll
    for (int kk = 0; kk < 16; ++kk) {
      float ar[4], ai[4], br[4], bi[4];
#pragma unroll
      for (int i = 0; i < 4; ++i) { ar[i] = Ars[kk][ty * 4 + i]; ai[i] = Ais[kk][ty * 4 + i]; }
#pragma unroll
      for (int j = 0; j < 4; ++j) { br[j] = Brs[kk][tx * 4 + j]; bi[j] = Bis[kk][tx * 4 + j]; }
#pragma unroll
      for (int i = 0; i < 4; ++i)
#pragma unroll
        for (int j = 0; j < 4; ++j) {
          accR[i][j] += ar[i] * br[j] - ai[i] * bi[j];
          accI[i][j] += ai[i] * br[j] + ar[i] * bi[j];
        }
    }
    __syncthreads();
  }
#pragma unroll
  for (int i = 0; i < 4; ++i) {
    int gm = m0 + ty * 4 + i;
    if (gm >= NFREQ) continue;
#pragma unroll
    for (int j = 0; j < 4; ++j) {
      int gn = n0 + tx * 4 + j;
      size_t o = ((size_t)b * NFREQ + gm) * NDIN + gn;
      xre[o] = fmaxf(accR[i][j] + rb[gn], 0.f);
      xim[o] = fmaxf(accI[i][j] + ib[gn], 0.f);
    }
  }
}

// irfft: ff[b,l,d] = (1/24) * sum_k w_k (xre*cos - xim*sin), w=1 at k=0,288 else 2
__global__ void idft_kernel(const float* __restrict__ xre,
                            const float* __restrict__ xim,
                            const float* __restrict__ ct,
                            const float* __restrict__ st,
                            float* __restrict__ ff) {
  int l = blockIdx.x, b = blockIdx.y, tid = threadIdx.x;
  __shared__ float wc[NFREQ], wsn[NFREQ];
  for (int k = tid; k < NFREQ; k += 256) {
    int idx = (k * l) % NL;
    float w = (k == 0 || k == NFREQ - 1) ? 1.f : 2.f;
    wc[k] = w * ct[idx]; wsn[k] = w * st[idx];
  }
  __syncthreads();
  int d0 = tid, d1 = tid + 256;
  float a0 = 0.f, a1 = 0.f;
  const float* xr_ = xre + (size_t)b * NFREQ * NDIN;
  const float* xi_ = xim + (size_t)b * NFREQ * NDIN;
  for (int k = 0; k < NFREQ; ++k) {
    float c = wc[k], s = wsn[k];
    a0 += xr_[(size_t)k * NDIN + d0] * c - xi_[(size_t)k * NDIN + d0] * s;
    a1 += xr_[(size_t)k * NDIN + d1] * c - xi_[(size_t)k * NDIN + d1] * s;
  }
  size_t o = ((size_t)b * NL + l) * NDIN;
  ff[o + d0] = a0 * (1.f / 24.f);
  ff[o + d1] = a1 * (1.f / 24.f);
}

extern "C" void kernel_launch(void* const* d_in, const int* in_sizes, int n_in,
                              void* d_out, int out_size, void* d_ws, size_t ws_size,
                              hipStream_t stream) {
  const float* x      = (const float*)d_in[0];
  const float* ln1_g  = (const float*)d_in[1];
  const float* ln1_b  = (const float*)d_in[2];
  const float* mln_g  = (const float*)d_in[3];
  const float* mln_b  = (const float*)d_in[4];
  const float* w_in   = (const float*)d_in[5];
  const float* conv_w = (const float*)d_in[6];
  const float* conv_b = (const float*)d_in[7];
  const float* w_xprj = (const float*)d_in[8];
  const float* w_dt   = (const float*)d_in[9];
  const float* b_dt   = (const float*)d_in[10];
  const float* A_log  = (const float*)d_in[11];
  const float* Dp     = (const float*)d_in[12];
  const float* w_out  = (const float*)d_in[13];
  const float* ln2_g  = (const float*)d_in[14];
  const float* ln2_b  = (const float*)d_in[15];
  const float* fc1_w  = (const float*)d_in[16];
  const float* bn1_s  = (const float*)d_in[17];
  const float* bn1_b  = (const float*)d_in[18];
  const float* Wr     = (const float*)d_in[19];
  const float* Wi     = (const float*)d_in[20];
  const float* rb     = (const float*)d_in[21];
  const float* ib     = (const float*)d_in[22];
  const float* fc2_w  = (const float*)d_in[23];
  const float* bn2_s  = (const float*)d_in[24];
  const float* bn2_b  = (const float*)d_in[25];

  float* ws   = (float*)d_ws;
  float* h    = ws + OFF_H;
  float* xr   = ws + OFF_XR;
  float* xc   = ws + OFF_XC;
  float* xdbl = ws + OFF_XDBL;
  float* delta= ws + OFF_DELTA;
  float* yf   = ws + OFF_YF;
  float* x2   = ws + OFF_X2;
  float* h2   = ws + OFF_H2;
  float* f    = ws + OFF_F;
  float* RF   = ws + OFF_RF;
  float* IFm  = ws + OFF_IF;
  float* xre  = ws + OFF_XRE;
  float* xim  = ws + OFF_XIM;
  float* ff   = ws + OFF_FF;
  float* ct   = ws + OFF_CT;
  float* st   = ws + OFF_ST;
  float* out  = (float*)d_out;

  trig_kernel<<<1, NL, 0, stream>>>(ct, st);
  // h = LN(LN(x))
  ln_kernel<<<NTOK, 64, 0, stream>>>(x, h, ln1_g, ln1_b, mln_g, mln_b, 1);
  // xr = h @ w_in  (2304x1024)
  gemm_f32<<<dim3(16, 36), 256, 0, stream>>>(h, NC, w_in, NWIN, xr, NWIN,
                                             NTOK, NWIN, NC, 0, nullptr, nullptr, nullptr, 0);
  // xc = silu(causal depthwise conv(xm) + conv_b)
  conv_silu_kernel<<<(NTOK * NDIN + 255) / 256, 256, 0, stream>>>(xr, conv_w, conv_b, xc);
  // x_dbl = xc @ w_xproj (2304x112)
  gemm_f32<<<dim3(2, 36), 256, 0, stream>>>(xc, NDIN, w_xprj, NXD, xdbl, NXD,
                                            NTOK, NXD, NDIN, 0, nullptr, nullptr, nullptr, 0);
  // delta = softplus(dt @ w_dt + b_dt)  (dt = x_dbl[:, :16])
  gemm_f32<<<dim3(8, 36), 256, 0, stream>>>(xdbl, NXD, w_dt, NDIN, delta, NDIN,
                                            NTOK, NDIN, NDTR, 1, nullptr, b_dt, nullptr, 0);
  // yf = (selective_scan + u*D) * silu(res)  -- DPP block-parallel scan
  scan3_kernel<<<NB * NDIN, 576, 0, stream>>>(delta, xc, xdbl, A_log, Dp, xr, yf);
  // x2 = x + yf @ w_out
  gemm_f32<<<dim3(4, 36), 256, 0, stream>>>(yf, NDIN, w_out, NC, x2, NC,
                                            NTOK, NC, NDIN, 2, nullptr, nullptr, x, NC);
  // h2 = LN(x2)
  ln_kernel<<<NTOK, 64, 0, stream>>>(x2, h2, ln2_g, ln2_b, nullptr, nullptr, 0);
  // f = relu(h2 @ fc1_w * bn1_s + bn1_b)
  gemm_f32<<<dim3(8, 36), 256, 0, stream>>>(h2, NC, fc1_w, NDIN, f, NDIN,
                                            NTOK, NDIN, NC, 3, bn1_s, bn1_b, nullptr, 0);
  // rfft (scaled)
  dft_fwd_kernel<<<dim3(NFREQ, NB), 256, 0, stream>>>(f, ct, st, RF, IFm);
  // complex mix + relu
  mix_kernel<<<dim3(8, 5, NB), 256, 0, stream>>>(RF, IFm, Wr, Wi, rb, ib, xre, xim);
  // irfft (scaled)
  idft_kernel<<<dim3(NL, NB), 256, 0, stream>>>(xre, xim, ct, st, ff);
  // out = x2 + ff @ fc2_w * bn2_s + bn2_b
  gemm_f32<<<dim3(4, 36), 256, 0, stream>>>(ff, NDIN, fc2_w, NC, out, NC,
                                            NTOK, NC, NDIN, 4, bn2_s, bn2_b, x2, NC);
}

// Round 4
// 486.583 us; speedup vs baseline: 2.0244x; 1.1801x over previous
//
#include <hip/hip_runtime.h>
#include <math.h>

#define NB 4
#define NL 576
#define NC 256
#define NTOK (NB*NL)      // 2304
#define NDIN 512
#define NXD 112
#define NDTR 16
#define NDST 48
#define NFREQ 289
#define NWIN 1024         // w_in output width
#define NMROW (NB*NFREQ)  // 1156 rows in freq space

// ---- workspace layout (floats) ----
#define OFF_H     0u
#define OFF_XR    589824u
#define OFF_XC    2949120u
#define OFF_XDBL  4128768u
#define OFF_DELTA 4386816u
#define OFF_YF    5566464u
#define OFF_X2    6746112u
#define OFF_H2    7335936u
#define OFF_F     7925760u   // f (reads done by dft_fwd) -> then reused for Wrt/Wit
#define OFF_RF    9105408u   // RFb (bf16) lives here
#define OFF_IF    9697280u   // IFb (bf16) lives here
#define OFF_XRE   10289152u
#define OFF_XIM   10881024u
#define OFF_FF    11472896u
#define OFF_CT    12652544u
#define OFF_ST    12653120u

typedef __attribute__((ext_vector_type(8))) short bf16x8;
typedef __attribute__((ext_vector_type(4))) float f32x4;
typedef __attribute__((ext_vector_type(4))) int   i32x4;

__device__ __forceinline__ float wave_sum(float v) {
#pragma unroll
  for (int o = 32; o > 0; o >>= 1) v += __shfl_xor(v, o);
  return v;
}

__device__ __forceinline__ unsigned short f2bf(float f) {
  unsigned int u = __float_as_uint(f);
  unsigned int r = (u + 0x7fffu + ((u >> 16) & 1u)) >> 16;  // RNE
  return (unsigned short)r;
}

// 64-lane inclusive prefix sum, no LDS: 4 DPP row_shr adds (per-16 scan)
// + 3 readlane row-total broadcasts.
__device__ __forceinline__ float wave_iscan(float x, int lane) {
  x += __int_as_float(__builtin_amdgcn_update_dpp(0, __float_as_int(x), 0x111, 0xf, 0xf, true));
  x += __int_as_float(__builtin_amdgcn_update_dpp(0, __float_as_int(x), 0x112, 0xf, 0xf, true));
  x += __int_as_float(__builtin_amdgcn_update_dpp(0, __float_as_int(x), 0x114, 0xf, 0xf, true));
  x += __int_as_float(__builtin_amdgcn_update_dpp(0, __float_as_int(x), 0x118, 0xf, 0xf, true));
  int xi = __float_as_int(x);
  float s15 = __int_as_float(__builtin_amdgcn_readlane(xi, 15));
  float s31 = __int_as_float(__builtin_amdgcn_readlane(xi, 31));
  float s47 = __int_as_float(__builtin_amdgcn_readlane(xi, 47));
  float off = 0.f;
  if (lane >= 16) off += s15;
  if (lane >= 32) off += s31;
  if (lane >= 48) off += s47;
  return x + off;
}

__global__ void trig_kernel(float* ct, float* st) {
  int i = threadIdx.x;
  if (i < NL) {
    double a = (6.283185307179586476925286766559 * (double)i) / (double)NL;
    ct[i] = (float)cos(a);
    st[i] = (float)sin(a);
  }
}

// one wave per token row; C=256 -> 4 elems/lane. dbl=1: two chained LNs.
__global__ void ln_kernel(const float* __restrict__ in, float* __restrict__ out,
                          const float* __restrict__ g1, const float* __restrict__ b1,
                          const float* __restrict__ g2, const float* __restrict__ b2,
                          int dbl) {
  int row = blockIdx.x, lane = threadIdx.x;
  const float* p = in + (size_t)row * NC;
  float v[4];
#pragma unroll
  for (int j = 0; j < 4; ++j) v[j] = p[lane + j * 64];
  float s = wave_sum(v[0] + v[1] + v[2] + v[3]);
  float m = s * (1.f / NC);
  float q = 0.f;
#pragma unroll
  for (int j = 0; j < 4; ++j) { float d = v[j] - m; q += d * d; }
  q = wave_sum(q);
  float rs = 1.f / sqrtf(q * (1.f / NC) + 1e-3f);
#pragma unroll
  for (int j = 0; j < 4; ++j) {
    int c = lane + j * 64;
    v[j] = (v[j] - m) * rs * g1[c] + b1[c];
  }
  if (dbl) {
    s = wave_sum(v[0] + v[1] + v[2] + v[3]);
    m = s * (1.f / NC);
    q = 0.f;
#pragma unroll
    for (int j = 0; j < 4; ++j) { float d = v[j] - m; q += d * d; }
    q = wave_sum(q);
    rs = 1.f / sqrtf(q * (1.f / NC) + 1e-3f);
#pragma unroll
    for (int j = 0; j < 4; ++j) {
      int c = lane + j * 64;
      v[j] = (v[j] - m) * rs * g2[c] + b2[c];
    }
  }
  float* o = out + (size_t)row * NC;
#pragma unroll
  for (int j = 0; j < 4; ++j) o[lane + j * 64] = v[j];
}

// generic tiled f32 GEMM: C[M,N] = A[M,K(lda)] @ B[K,N(ldb)], fused epilogues.
// mode 0: store; 1: softplus(v+bias); 2: v+add; 3: relu(v*scl+bias); 4: v*scl+bias+add
__global__ __launch_bounds__(256) void gemm_f32(
    const float* __restrict__ A, int lda, const float* __restrict__ B, int ldb,
    float* __restrict__ C, int ldc, int M, int N, int K, int mode,
    const float* __restrict__ scl, const float* __restrict__ bias,
    const float* __restrict__ add, int ldadd) {
  __shared__ float As[16][65];   // [k][m]
  __shared__ float Bs[16][68];   // [k][n]
  int tid = threadIdx.x;
  int tx = tid & 15, ty = tid >> 4;
  int m0 = blockIdx.y * 64, n0 = blockIdx.x * 64;
  int am = tid >> 2, ak = (tid & 3) * 4;
  int bk = tid >> 4, bn = (tid & 15) * 4;
  float acc[4][4] = {};
  for (int k0 = 0; k0 < K; k0 += 16) {
    float4 av = make_float4(0.f, 0.f, 0.f, 0.f);
    if (m0 + am < M)
      av = *reinterpret_cast<const float4*>(A + (size_t)(m0 + am) * lda + k0 + ak);
    As[ak + 0][am] = av.x; As[ak + 1][am] = av.y;
    As[ak + 2][am] = av.z; As[ak + 3][am] = av.w;
    float4 bv = make_float4(0.f, 0.f, 0.f, 0.f);
    if (n0 + bn < N)
      bv = *reinterpret_cast<const float4*>(B + (size_t)(k0 + bk) * ldb + n0 + bn);
    *reinterpret_cast<float4*>(&Bs[bk][bn]) = bv;
    __syncthreads();
#pragma unroll
    for (int kk = 0; kk < 16; ++kk) {
      float a[4], b[4];
#pragma unroll
      for (int i = 0; i < 4; ++i) a[i] = As[kk][ty * 4 + i];
#pragma unroll
      for (int j = 0; j < 4; ++j) b[j] = Bs[kk][tx * 4 + j];
#pragma unroll
      for (int i = 0; i < 4; ++i)
#pragma unroll
        for (int j = 0; j < 4; ++j) acc[i][j] += a[i] * b[j];
    }
    __syncthreads();
  }
#pragma unroll
  for (int i = 0; i < 4; ++i) {
    int gm = m0 + ty * 4 + i;
    if (gm >= M) continue;
#pragma unroll
    for (int j = 0; j < 4; ++j) {
      int gn = n0 + tx * 4 + j;
      if (gn >= N) continue;
      float v = acc[i][j];
      if (mode == 1) { v += bias[gn]; v = fmaxf(v, 0.f) + log1pf(expf(-fabsf(v))); }
      else if (mode == 2) { v += add[(size_t)gm * ldadd + gn]; }
      else if (mode == 3) { v = fmaxf(v * scl[gn] + bias[gn], 0.f); }
      else if (mode == 4) { v = v * scl[gn] + bias[gn] + add[(size_t)gm * ldadd + gn]; }
      C[(size_t)gm * ldc + gn] = v;
    }
  }
}

// causal depthwise conv (width 4) over xm = xr[:, :512], then silu.
__global__ void conv_silu_kernel(const float* __restrict__ xr,
                                 const float* __restrict__ cw,
                                 const float* __restrict__ cb,
                                 float* __restrict__ xc) {
  int id = blockIdx.x * blockDim.x + threadIdx.x;
  if (id >= NTOK * NDIN) return;
  int d = id & 511, row = id >> 9;
  int b = row / NL, l = row % NL;
  float acc = cb[d];
#pragma unroll
  for (int k = 0; k < 4; ++k) {
    int l2 = l - 3 + k;
    if (l2 >= 0) acc += xr[((size_t)(b * NL + l2)) * NWIN + d] * cw[k * NDIN + d];
  }
  xc[(size_t)row * NDIN + d] = acc / (1.f + expf(-acc));
}

// selective scan via block-parallel prefix sums (DPP in-register wave scan).
__global__ __launch_bounds__(576) void scan3_kernel(
    const float* __restrict__ delta, const float* __restrict__ xc,
    const float* __restrict__ xdbl, const float* __restrict__ A_log,
    const float* __restrict__ Dp, const float* __restrict__ xr,
    float* __restrict__ yf) {
  __shared__ float part[9];        // wave partials (Tsuf scan)
  __shared__ float part8[9][8];    // wave partials (8 batched scans)
  int b = blockIdx.x >> 9, d = blockIdx.x & 511;
  int l = threadIdx.x;
  int lane = l & 63, wv = l >> 6;  // 9 waves
  size_t row = (size_t)(b * NL + l);
  float dl = delta[row * NDIN + d];
  float ul = xc[row * NDIN + d];
  float rl = xr[row * NWIN + NDIN + d];
  float s = wave_iscan(dl, lane);
  if (lane == 63) part[wv] = s;
  __syncthreads();
  float off = 0.f, tot = 0.f;
#pragma unroll
  for (int i = 0; i < 9; ++i) { float p = part[i]; tot += p; if (i < wv) off += p; }
  float Tsuf = tot - (s + off);

  const float* xrow = xdbl + row * NXD;
  const float* Arow = A_log + (size_t)d * NDST;
  float dlul = dl * ul;
  float y = 0.f;
  for (int c = 0; c < 6; ++c) {
    float4 b0 = *reinterpret_cast<const float4*>(xrow + NDTR + c * 8);
    float4 b1 = *reinterpret_cast<const float4*>(xrow + NDTR + c * 8 + 4);
    float4 c0 = *reinterpret_cast<const float4*>(xrow + NDTR + NDST + c * 8);
    float4 c1 = *reinterpret_cast<const float4*>(xrow + NDTR + NDST + c * 8 + 4);
    float bb[8] = {b0.x, b0.y, b0.z, b0.w, b1.x, b1.y, b1.z, b1.w};
    float cc[8] = {c0.x, c0.y, c0.z, c0.w, c1.x, c1.y, c1.z, c1.w};
    float e[8], w[8];
#pragma unroll
    for (int j = 0; j < 8; ++j) {
      float An = -__expf(Arow[c * 8 + j]);
      e[j] = __expf(An * Tsuf);
      w[j] = dlul * bb[j] * e[j];
    }
#pragma unroll
    for (int j = 0; j < 8; ++j) w[j] = wave_iscan(w[j], lane);
    if (lane == 63) {
#pragma unroll
      for (int j = 0; j < 8; ++j) part8[wv][j] = w[j];
    }
    __syncthreads();
    float po = 0.f;
    if (lane < 8) {
#pragma unroll
      for (int i = 0; i < 8; ++i) { if (i < wv) po += part8[i][lane]; }
    }
    int poi = __float_as_int(po);
#pragma unroll
    for (int j = 0; j < 8; ++j) {
      float offj = __int_as_float(__builtin_amdgcn_readlane(poi, j));
      float ps = w[j] + offj;
      y += __fdividef(ps, e[j] + 1e-12f) * cc[j];
    }
    __syncthreads();
  }
  float yv = y + ul * Dp[d];
  float sr = rl / (1.f + __expf(-rl));
  yf[row * NDIN + d] = yv * sr;
}

// forward DFT along L (rfft): writes bf16 RFb/IFb [1156][512].
__global__ void dft_fwd_kernel(const float* __restrict__ f,
                               const float* __restrict__ ct,
                               const float* __restrict__ st,
                               unsigned short* __restrict__ RFb,
                               unsigned short* __restrict__ IFb) {
  int k = blockIdx.x, b = blockIdx.y, tid = threadIdx.x;
  __shared__ float lc[NL], ls[NL];
  for (int l = tid; l < NL; l += 256) {
    int idx = (k * l) % NL;
    lc[l] = ct[idx]; ls[l] = st[idx];
  }
  __syncthreads();
  int c0 = tid, c1 = tid + 256;
  float r0 = 0.f, i0 = 0.f, r1 = 0.f, i1 = 0.f;
  const float* fb = f + (size_t)b * NL * NDIN;
  for (int l = 0; l < NL; ++l) {
    float cl = lc[l], sl = ls[l];
    float v0 = fb[(size_t)l * NDIN + c0];
    float v1 = fb[(size_t)l * NDIN + c1];
    r0 += v0 * cl; i0 -= v0 * sl;
    r1 += v1 * cl; i1 -= v1 * sl;
  }
  size_t o = ((size_t)b * NFREQ + k) * NDIN;
  RFb[o + c0] = f2bf(r0 * (1.f / 24.f)); RFb[o + c1] = f2bf(r1 * (1.f / 24.f));
  IFb[o + c0] = f2bf(i0 * (1.f / 24.f)); IFb[o + c1] = f2bf(i1 * (1.f / 24.f));
}

// transpose+bf16 pack: Wt[n][c] = bf16(W[c][n]), 512x512. z=0: Wr, z=1: Wi.
__global__ __launch_bounds__(256) void packw_kernel(
    const float* __restrict__ Wr, const float* __restrict__ Wi,
    unsigned short* __restrict__ Wrt, unsigned short* __restrict__ Wit) {
  __shared__ float tile[64][65];
  const float* W = blockIdx.z ? Wi : Wr;
  unsigned short* Wt = blockIdx.z ? Wit : Wrt;
  int c0 = blockIdx.y * 64, n0 = blockIdx.x * 64;
  int tid = threadIdx.x;
  int r = tid >> 2, q = tid & 3;
#pragma unroll
  for (int j = 0; j < 4; ++j) {
    float4 v = *reinterpret_cast<const float4*>(W + (size_t)(c0 + r) * 512 + n0 + q * 16 + j * 4);
    tile[r][q * 16 + j * 4 + 0] = v.x; tile[r][q * 16 + j * 4 + 1] = v.y;
    tile[r][q * 16 + j * 4 + 2] = v.z; tile[r][q * 16 + j * 4 + 3] = v.w;
  }
  __syncthreads();
  unsigned int pk[8];
#pragma unroll
  for (int i = 0; i < 8; ++i) {
    unsigned int lo = f2bf(tile[q * 16 + 2 * i + 0][r]);
    unsigned int hi = f2bf(tile[q * 16 + 2 * i + 1][r]);
    pk[i] = lo | (hi << 16);
  }
  unsigned int* dst = (unsigned int*)(Wt + (size_t)(n0 + r) * 512 + c0 + q * 16);
  *reinterpret_cast<uint4*>(dst)     = make_uint4(pk[0], pk[1], pk[2], pk[3]);
  *reinterpret_cast<uint4*>(dst + 4) = make_uint4(pk[4], pk[5], pk[6], pk[7]);
}

// complex channel mix on matrix cores:
// xre = relu(RF@Wr - IF@Wi + rb), xim = relu(IF@Wr + RF@Wi + ib)
// A = RFb/IFb [1156][512] bf16 (c contiguous); B = Wrt/Wit [n][c] bf16.
__global__ __launch_bounds__(256) void mix_mfma_kernel(
    const unsigned short* __restrict__ RFb, const unsigned short* __restrict__ IFb,
    const unsigned short* __restrict__ Wrt, const unsigned short* __restrict__ Wit,
    const float* __restrict__ rb, const float* __restrict__ ib,
    float* __restrict__ xre, float* __restrict__ xim) {
  __shared__ unsigned short AsR[64][40], AsI[64][40], BsR[64][40], BsI[64][40];
  int tid = threadIdx.x;
  int lane = tid & 63, wv = tid >> 6;
  int m0 = blockIdx.y * 64, n0 = blockIdx.x * 64;
  int sm = tid >> 2, part = tid & 3;

  f32x4 accR[4] = {}, accI[4] = {};

  for (int k0 = 0; k0 < 512; k0 += 32) {
    size_t arow = (size_t)(m0 + sm) * 512 + k0 + part * 8;
    size_t brow = (size_t)(n0 + sm) * 512 + k0 + part * 8;
    *(bf16x8*)&AsR[sm][part * 8] = *(const bf16x8*)(RFb + arow);
    *(bf16x8*)&AsI[sm][part * 8] = *(const bf16x8*)(IFb + arow);
    *(bf16x8*)&BsR[sm][part * 8] = *(const bf16x8*)(Wrt + brow);
    *(bf16x8*)&BsI[sm][part * 8] = *(const bf16x8*)(Wit + brow);
    __syncthreads();

    int am = wv * 16 + (lane & 15);
    int koff = (lane >> 4) * 8;
    bf16x8 a_rf = *(bf16x8*)&AsR[am][koff];
    bf16x8 a_if = *(bf16x8*)&AsI[am][koff];
    union { bf16x8 h; i32x4 i; } un;
    un.h = a_if;
    un.i = un.i ^ (int)0x80008000;
    bf16x8 a_ifn = un.h;
#pragma unroll
    for (int t = 0; t < 4; ++t) {
      int bn = t * 16 + (lane & 15);
      bf16x8 b_wr = *(bf16x8*)&BsR[bn][koff];
      bf16x8 b_wi = *(bf16x8*)&BsI[bn][koff];
      accR[t] = __builtin_amdgcn_mfma_f32_16x16x32_bf16(a_rf, b_wr, accR[t], 0, 0, 0);
      accR[t] = __builtin_amdgcn_mfma_f32_16x16x32_bf16(a_ifn, b_wi, accR[t], 0, 0, 0);
      accI[t] = __builtin_amdgcn_mfma_f32_16x16x32_bf16(a_if, b_wr, accI[t], 0, 0, 0);
      accI[t] = __builtin_amdgcn_mfma_f32_16x16x32_bf16(a_rf, b_wi, accI[t], 0, 0, 0);
    }
    __syncthreads();
  }

#pragma unroll
  for (int t = 0; t < 4; ++t) {
    int gn = n0 + t * 16 + (lane & 15);
    float rbv = rb[gn], ibv = ib[gn];
#pragma unroll
    for (int r = 0; r < 4; ++r) {
      int gm = m0 + wv * 16 + (lane >> 4) * 4 + r;
      if (gm < NMROW) {
        size_t o = (size_t)gm * NDIN + gn;
        xre[o] = fmaxf(accR[t][r] + rbv, 0.f);
        xim[o] = fmaxf(accI[t][r] + ibv, 0.f);
      }
    }
  }
}

// irfft: ff[b,l,d] = (1/24) * sum_k w_k (xre*cos - xim*sin), w=1 at k=0,288 else 2
__global__ void idft_kernel(const float* __restrict__ xre,
                            const float* __restrict__ xim,
                            const float* __restrict__ ct,
                            const float* __restrict__ st,
                            float* __restrict__ ff) {
  int l = blockIdx.x, b = blockIdx.y, tid = threadIdx.x;
  __shared__ float wc[NFREQ], wsn[NFREQ];
  for (int k = tid; k < NFREQ; k += 256) {
    int idx = (k * l) % NL;
    float w = (k == 0 || k == NFREQ - 1) ? 1.f : 2.f;
    wc[k] = w * ct[idx]; wsn[k] = w * st[idx];
  }
  __syncthreads();
  int d0 = tid, d1 = tid + 256;
  float a0 = 0.f, a1 = 0.f;
  const float* xr_ = xre + (size_t)b * NFREQ * NDIN;
  const float* xi_ = xim + (size_t)b * NFREQ * NDIN;
  for (int k = 0; k < NFREQ; ++k) {
    float c = wc[k], s = wsn[k];
    a0 += xr_[(size_t)k * NDIN + d0] * c - xi_[(size_t)k * NDIN + d0] * s;
    a1 += xr_[(size_t)k * NDIN + d1] * c - xi_[(size_t)k * NDIN + d1] * s;
  }
  size_t o = ((size_t)b * NL + l) * NDIN;
  ff[o + d0] = a0 * (1.f / 24.f);
  ff[o + d1] = a1 * (1.f / 24.f);
}

extern "C" void kernel_launch(void* const* d_in, const int* in_sizes, int n_in,
                              void* d_out, int out_size, void* d_ws, size_t ws_size,
                              hipStream_t stream) {
  const float* x      = (const float*)d_in[0];
  const float* ln1_g  = (const float*)d_in[1];
  const float* ln1_b  = (const float*)d_in[2];
  const float* mln_g  = (const float*)d_in[3];
  const float* mln_b  = (const float*)d_in[4];
  const float* w_in   = (const float*)d_in[5];
  const float* conv_w = (const float*)d_in[6];
  const float* conv_b = (const float*)d_in[7];
  const float* w_xprj = (const float*)d_in[8];
  const float* w_dt   = (const float*)d_in[9];
  const float* b_dt   = (const float*)d_in[10];
  const float* A_log  = (const float*)d_in[11];
  const float* Dp     = (const float*)d_in[12];
  const float* w_out  = (const float*)d_in[13];
  const float* ln2_g  = (const float*)d_in[14];
  const float* ln2_b  = (const float*)d_in[15];
  const float* fc1_w  = (const float*)d_in[16];
  const float* bn1_s  = (const float*)d_in[17];
  const float* bn1_b  = (const float*)d_in[18];
  const float* Wr     = (const float*)d_in[19];
  const float* Wi     = (const float*)d_in[20];
  const float* rb     = (const float*)d_in[21];
  const float* ib     = (const float*)d_in[22];
  const float* fc2_w  = (const float*)d_in[23];
  const float* bn2_s  = (const float*)d_in[24];
  const float* bn2_b  = (const float*)d_in[25];

  float* ws   = (float*)d_ws;
  float* h    = ws + OFF_H;
  float* xr   = ws + OFF_XR;
  float* xc   = ws + OFF_XC;
  float* xdbl = ws + OFF_XDBL;
  float* delta= ws + OFF_DELTA;
  float* yf   = ws + OFF_YF;
  float* x2   = ws + OFF_X2;
  float* h2   = ws + OFF_H2;
  float* f    = ws + OFF_F;
  float* xre  = ws + OFF_XRE;
  float* xim  = ws + OFF_XIM;
  float* ff   = ws + OFF_FF;
  float* ct   = ws + OFF_CT;
  float* st   = ws + OFF_ST;
  unsigned short* RFb = (unsigned short*)(ws + OFF_RF);
  unsigned short* IFb = (unsigned short*)(ws + OFF_IF);
  unsigned short* Wrt = (unsigned short*)(ws + OFF_F);            // reuse dead f region
  unsigned short* Wit = (unsigned short*)(ws + OFF_F + 131072u);  // after dft_fwd
  float* out  = (float*)d_out;

  trig_kernel<<<1, NL, 0, stream>>>(ct, st);
  // h = LN(LN(x))
  ln_kernel<<<NTOK, 64, 0, stream>>>(x, h, ln1_g, ln1_b, mln_g, mln_b, 1);
  // xr = h @ w_in  (2304x1024)
  gemm_f32<<<dim3(16, 36), 256, 0, stream>>>(h, NC, w_in, NWIN, xr, NWIN,
                                             NTOK, NWIN, NC, 0, nullptr, nullptr, nullptr, 0);
  // xc = silu(causal depthwise conv(xm) + conv_b)
  conv_silu_kernel<<<(NTOK * NDIN + 255) / 256, 256, 0, stream>>>(xr, conv_w, conv_b, xc);
  // x_dbl = xc @ w_xproj (2304x112)
  gemm_f32<<<dim3(2, 36), 256, 0, stream>>>(xc, NDIN, w_xprj, NXD, xdbl, NXD,
                                            NTOK, NXD, NDIN, 0, nullptr, nullptr, nullptr, 0);
  // delta = softplus(dt @ w_dt + b_dt)  (dt = x_dbl[:, :16])
  gemm_f32<<<dim3(8, 36), 256, 0, stream>>>(xdbl, NXD, w_dt, NDIN, delta, NDIN,
                                            NTOK, NDIN, NDTR, 1, nullptr, b_dt, nullptr, 0);
  // yf = (selective_scan + u*D) * silu(res)  -- DPP block-parallel scan
  scan3_kernel<<<NB * NDIN, 576, 0, stream>>>(delta, xc, xdbl, A_log, Dp, xr, yf);
  // x2 = x + yf @ w_out
  gemm_f32<<<dim3(4, 36), 256, 0, stream>>>(yf, NDIN, w_out, NC, x2, NC,
                                            NTOK, NC, NDIN, 2, nullptr, nullptr, x, NC);
  // h2 = LN(x2)
  ln_kernel<<<NTOK, 64, 0, stream>>>(x2, h2, ln2_g, ln2_b, nullptr, nullptr, 0);
  // f = relu(h2 @ fc1_w * bn1_s + bn1_b)
  gemm_f32<<<dim3(8, 36), 256, 0, stream>>>(h2, NC, fc1_w, NDIN, f, NDIN,
                                            NTOK, NDIN, NC, 3, bn1_s, bn1_b, nullptr, 0);
  // rfft (scaled) -> bf16
  dft_fwd_kernel<<<dim3(NFREQ, NB), 256, 0, stream>>>(f, ct, st, RFb, IFb);
  // pack Wr/Wi transposed to bf16 (into dead f region)
  packw_kernel<<<dim3(8, 8, 2), 256, 0, stream>>>(Wr, Wi, Wrt, Wit);
  // complex mix + relu on matrix cores
  mix_mfma_kernel<<<dim3(8, 19), 256, 0, stream>>>(RFb, IFb, Wrt, Wit, rb, ib, xre, xim);
  // irfft (scaled)
  idft_kernel<<<dim3(NL, NB), 256, 0, stream>>>(xre, xim, ct, st, ff);
  // out = x2 + ff @ fc2_w * bn2_s + bn2_b
  gemm_f32<<<dim3(4, 36), 256, 0, stream>>>(ff, NDIN, fc2_w, NC, out, NC,
                                            NTOK, NC, NDIN, 4, bn2_s, bn2_b, x2, NC);
}

// Round 5
// 477.870 us; speedup vs baseline: 2.0613x; 1.0182x over previous
//
#include <hip/hip_runtime.h>
#include <math.h>

#define NB 4
#define NL 576
#define NC 256
#define NTOK (NB*NL)      // 2304
#define NDIN 512
#define NXD 112
#define NDTR 16
#define NDST 48
#define NFREQ 289
#define NWIN 1024         // w_in output width
#define NMROW (NB*NFREQ)  // 1156 rows in freq space

// ---- workspace layout (floats), with lifetime reuse ----
#define OFF_H     0u         // h (589824) -> h2 later
#define OFF_XR    589824u    // xr (2359296) -> xre(591872)+xim(591872) later
#define OFF_XCT   2949120u   // xc_t (1179648)
#define OFF_REST  4128768u   // res_t (1179648)
#define OFF_XDBL  5308416u   // xdbl_t (258048)
#define OFF_DELT  5566464u   // delta_t (1179648) -> ff later
#define OFF_YFT   6746112u   // yf_t (1179648)
#define OFF_X2    7925760u   // x2 (589824)
#define OFF_F     8515584u   // f (1179648) -> Wrt/Wit later
#define OFF_RF    9695232u   // RFb bf16 (295936 f32-equiv)
#define OFF_IF    9991168u   // IFb bf16
#define OFF_CT    10287104u
#define OFF_ST    10287680u

typedef __attribute__((ext_vector_type(8))) short bf16x8;
typedef __attribute__((ext_vector_type(4))) float f32x4;
typedef __attribute__((ext_vector_type(4))) int   i32x4;

__device__ __forceinline__ float wave_sum(float v) {
#pragma unroll
  for (int o = 32; o > 0; o >>= 1) v += __shfl_xor(v, o);
  return v;
}

__device__ __forceinline__ unsigned short f2bf(float f) {
  unsigned int u = __float_as_uint(f);
  unsigned int r = (u + 0x7fffu + ((u >> 16) & 1u)) >> 16;  // RNE
  return (unsigned short)r;
}

// 64-lane inclusive prefix sum, no LDS: 4 DPP row_shr adds (per-16 scan)
// + 3 readlane row-total broadcasts.
__device__ __forceinline__ float wave_iscan(float x, int lane) {
  x += __int_as_float(__builtin_amdgcn_update_dpp(0, __float_as_int(x), 0x111, 0xf, 0xf, true));
  x += __int_as_float(__builtin_amdgcn_update_dpp(0, __float_as_int(x), 0x112, 0xf, 0xf, true));
  x += __int_as_float(__builtin_amdgcn_update_dpp(0, __float_as_int(x), 0x114, 0xf, 0xf, true));
  x += __int_as_float(__builtin_amdgcn_update_dpp(0, __float_as_int(x), 0x118, 0xf, 0xf, true));
  int xi = __float_as_int(x);
  float s15 = __int_as_float(__builtin_amdgcn_readlane(xi, 15));
  float s31 = __int_as_float(__builtin_amdgcn_readlane(xi, 31));
  float s47 = __int_as_float(__builtin_amdgcn_readlane(xi, 47));
  float off = 0.f;
  if (lane >= 16) off += s15;
  if (lane >= 32) off += s31;
  if (lane >= 48) off += s47;
  return x + off;
}

__global__ void trig_kernel(float* ct, float* st) {
  int i = threadIdx.x;
  if (i < NL) {
    double a = (6.283185307179586476925286766559 * (double)i) / (double)NL;
    ct[i] = (float)cos(a);
    st[i] = (float)sin(a);
  }
}

// one wave per token row; C=256 -> 4 elems/lane. dbl=1: two chained LNs.
__global__ void ln_kernel(const float* __restrict__ in, float* __restrict__ out,
                          const float* __restrict__ g1, const float* __restrict__ b1,
                          const float* __restrict__ g2, const float* __restrict__ b2,
                          int dbl) {
  int row = blockIdx.x, lane = threadIdx.x;
  const float* p = in + (size_t)row * NC;
  float v[4];
#pragma unroll
  for (int j = 0; j < 4; ++j) v[j] = p[lane + j * 64];
  float s = wave_sum(v[0] + v[1] + v[2] + v[3]);
  float m = s * (1.f / NC);
  float q = 0.f;
#pragma unroll
  for (int j = 0; j < 4; ++j) { float d = v[j] - m; q += d * d; }
  q = wave_sum(q);
  float rs = 1.f / sqrtf(q * (1.f / NC) + 1e-3f);
#pragma unroll
  for (int j = 0; j < 4; ++j) {
    int c = lane + j * 64;
    v[j] = (v[j] - m) * rs * g1[c] + b1[c];
  }
  if (dbl) {
    s = wave_sum(v[0] + v[1] + v[2] + v[3]);
    m = s * (1.f / NC);
    q = 0.f;
#pragma unroll
    for (int j = 0; j < 4; ++j) { float d = v[j] - m; q += d * d; }
    q = wave_sum(q);
    rs = 1.f / sqrtf(q * (1.f / NC) + 1e-3f);
#pragma unroll
    for (int j = 0; j < 4; ++j) {
      int c = lane + j * 64;
      v[j] = (v[j] - m) * rs * g2[c] + b2[c];
    }
  }
  float* o = out + (size_t)row * NC;
#pragma unroll
  for (int j = 0; j < 4; ++j) o[lane + j * 64] = v[j];
}

// generic tiled f32 GEMM: C[M,N] = A @ B[K,N(ldb)], fused epilogues.
// flags bit0: A stored K-major (A_t[k][m], lda = m-stride)
// flags bit1: store C transposed (C[n*ldc + m])
// mode 0: store; 1: softplus(v+bias); 2: v+add; 3: relu(v*scl+bias); 4: v*scl+bias+add
__global__ __launch_bounds__(256) void gemm_f32(
    const float* __restrict__ A, int lda, const float* __restrict__ B, int ldb,
    float* __restrict__ C, int ldc, int M, int N, int K, int mode, int flags,
    const float* __restrict__ scl, const float* __restrict__ bias,
    const float* __restrict__ add, int ldadd) {
  __shared__ float As[16][65];   // [k][m]
  __shared__ float Bs[16][68];   // [k][n]
  int tid = threadIdx.x;
  int tx = tid & 15, ty = tid >> 4;
  int m0 = blockIdx.y * 64, n0 = blockIdx.x * 64;
  int am = tid >> 2, ak = (tid & 3) * 4;
  int akr = tid >> 4, am4 = (tid & 15) * 4;
  int bk = tid >> 4, bn = (tid & 15) * 4;
  float acc[4][4] = {};
  for (int k0 = 0; k0 < K; k0 += 16) {
    if (flags & 1) {
      float4 av = make_float4(0.f, 0.f, 0.f, 0.f);
      if (m0 + am4 < M)
        av = *reinterpret_cast<const float4*>(A + (size_t)(k0 + akr) * lda + m0 + am4);
      As[akr][am4 + 0] = av.x; As[akr][am4 + 1] = av.y;
      As[akr][am4 + 2] = av.z; As[akr][am4 + 3] = av.w;
    } else {
      float4 av = make_float4(0.f, 0.f, 0.f, 0.f);
      if (m0 + am < M)
        av = *reinterpret_cast<const float4*>(A + (size_t)(m0 + am) * lda + k0 + ak);
      As[ak + 0][am] = av.x; As[ak + 1][am] = av.y;
      As[ak + 2][am] = av.z; As[ak + 3][am] = av.w;
    }
    float4 bv = make_float4(0.f, 0.f, 0.f, 0.f);
    if (n0 + bn < N)
      bv = *reinterpret_cast<const float4*>(B + (size_t)(k0 + bk) * ldb + n0 + bn);
    *reinterpret_cast<float4*>(&Bs[bk][bn]) = bv;
    __syncthreads();
#pragma unroll
    for (int kk = 0; kk < 16; ++kk) {
      float a[4], b[4];
#pragma unroll
      for (int i = 0; i < 4; ++i) a[i] = As[kk][ty * 4 + i];
#pragma unroll
      for (int j = 0; j < 4; ++j) b[j] = Bs[kk][tx * 4 + j];
#pragma unroll
      for (int i = 0; i < 4; ++i)
#pragma unroll
        for (int j = 0; j < 4; ++j) acc[i][j] += a[i] * b[j];
    }
    __syncthreads();
  }
#pragma unroll
  for (int i = 0; i < 4; ++i) {
    int gm = m0 + ty * 4 + i;
    if (gm >= M) continue;
#pragma unroll
    for (int j = 0; j < 4; ++j) {
      int gn = n0 + tx * 4 + j;
      if (gn >= N) continue;
      float v = acc[i][j];
      if (mode == 1) { v += bias[gn]; v = fmaxf(v, 0.f) + log1pf(expf(-fabsf(v))); }
      else if (mode == 2) { v += add[(size_t)gm * ldadd + gn]; }
      else if (mode == 3) { v = fmaxf(v * scl[gn] + bias[gn], 0.f); }
      else if (mode == 4) { v = v * scl[gn] + bias[gn] + add[(size_t)gm * ldadd + gn]; }
      if (flags & 2) C[(size_t)gn * ldc + gm] = v;
      else           C[(size_t)gm * ldc + gn] = v;
    }
  }
}

// Fused causal depthwise conv(4)+silu with transposed output, plus res transpose.
// z=0: xc_t[d][row] = silu(conv(xr[:,:512])); z=1: res_t[d][row] = xr[:,512:].
__global__ __launch_bounds__(256) void convT_kernel(
    const float* __restrict__ xr, const float* __restrict__ cw,
    const float* __restrict__ cb, float* __restrict__ xc_t,
    float* __restrict__ res_t) {
  __shared__ float tile[67][65];
  int d0 = blockIdx.x * 64;
  int rt = blockIdx.y;             // 0..35
  int b = rt / 9, l0 = (rt % 9) * 64;
  int tid = threadIdx.x;
  int li = tid & 63, dj0 = tid >> 6;
  if (blockIdx.z == 0) {
    for (int u = tid; u < 67 * 16; u += 256) {
      int r = u >> 4, c4 = (u & 15) * 4;
      int l = l0 - 3 + r;
      float4 v = make_float4(0.f, 0.f, 0.f, 0.f);
      if (l >= 0) v = *reinterpret_cast<const float4*>(xr + (size_t)(b * NL + l) * NWIN + d0 + c4);
      tile[r][c4 + 0] = v.x; tile[r][c4 + 1] = v.y;
      tile[r][c4 + 2] = v.z; tile[r][c4 + 3] = v.w;
    }
    __syncthreads();
    for (int dj = dj0; dj < 64; dj += 4) {
      int d = d0 + dj;
      float acc = cb[d];
#pragma unroll
      for (int k = 0; k < 4; ++k) acc += cw[k * NDIN + d] * tile[li + k][dj];
      acc = acc / (1.f + __expf(-acc));
      xc_t[(size_t)d * NTOK + b * NL + l0 + li] = acc;
    }
  } else {
    for (int u = tid; u < 64 * 16; u += 256) {
      int r = u >> 4, c4 = (u & 15) * 4;
      float4 v = *reinterpret_cast<const float4*>(xr + (size_t)(b * NL + l0 + r) * NWIN + NDIN + d0 + c4);
      tile[r][c4 + 0] = v.x; tile[r][c4 + 1] = v.y;
      tile[r][c4 + 2] = v.z; tile[r][c4 + 3] = v.w;
    }
    __syncthreads();
    for (int dj = dj0; dj < 64; dj += 4)
      res_t[(size_t)(d0 + dj) * NTOK + b * NL + l0 + li] = tile[li][dj];
  }
}

// selective scan, all operands d-major (coalesced). DPP block-parallel scans.
__global__ __launch_bounds__(576) void scan4_kernel(
    const float* __restrict__ delta_t, const float* __restrict__ xc_t,
    const float* __restrict__ xdbl_t, const float* __restrict__ A_log,
    const float* __restrict__ Dp, const float* __restrict__ res_t,
    float* __restrict__ yf_t) {
  __shared__ float part[9];
  __shared__ float part8[9][8];
  int b = blockIdx.x >> 9, d = blockIdx.x & 511;
  int l = threadIdx.x;
  int lane = l & 63, wv = l >> 6;
  int col = b * NL + l;
  float dl = delta_t[(size_t)d * NTOK + col];
  float ul = xc_t[(size_t)d * NTOK + col];
  float rl = res_t[(size_t)d * NTOK + col];
  float s = wave_iscan(dl, lane);
  if (lane == 63) part[wv] = s;
  __syncthreads();
  float off = 0.f, tot = 0.f;
#pragma unroll
  for (int i = 0; i < 9; ++i) { float p = part[i]; tot += p; if (i < wv) off += p; }
  float Tsuf = tot - (s + off);

  const float* Arow = A_log + (size_t)d * NDST;
  float dlul = dl * ul;
  float y = 0.f;
  for (int c = 0; c < 6; ++c) {
    float bb[8], cc[8], e[8], w[8];
#pragma unroll
    for (int j = 0; j < 8; ++j) {
      bb[j] = xdbl_t[(size_t)(NDTR + c * 8 + j) * NTOK + col];
      cc[j] = xdbl_t[(size_t)(NDTR + NDST + c * 8 + j) * NTOK + col];
    }
#pragma unroll
    for (int j = 0; j < 8; ++j) {
      float An = -__expf(Arow[c * 8 + j]);
      e[j] = __expf(An * Tsuf);
      w[j] = dlul * bb[j] * e[j];
    }
#pragma unroll
    for (int j = 0; j < 8; ++j) w[j] = wave_iscan(w[j], lane);
    if (lane == 63) {
#pragma unroll
      for (int j = 0; j < 8; ++j) part8[wv][j] = w[j];
    }
    __syncthreads();
    float po = 0.f;
    if (lane < 8) {
#pragma unroll
      for (int i = 0; i < 8; ++i) { if (i < wv) po += part8[i][lane]; }
    }
    int poi = __float_as_int(po);
#pragma unroll
    for (int j = 0; j < 8; ++j) {
      float offj = __int_as_float(__builtin_amdgcn_readlane(poi, j));
      float ps = w[j] + offj;
      y += __fdividef(ps, e[j] + 1e-12f) * cc[j];
    }
    __syncthreads();
  }
  float yv = y + ul * Dp[d];
  float sr = rl / (1.f + __expf(-rl));
  yf_t[(size_t)d * NTOK + col] = yv * sr;
}

// forward DFT along L (rfft): writes bf16 RFb/IFb [1156][512].
__global__ void dft_fwd_kernel(const float* __restrict__ f,
                               const float* __restrict__ ct,
                               const float* __restrict__ st,
                               unsigned short* __restrict__ RFb,
                               unsigned short* __restrict__ IFb) {
  int k = blockIdx.x, b = blockIdx.y, tid = threadIdx.x;
  __shared__ float lc[NL], ls[NL];
  for (int l = tid; l < NL; l += 256) {
    int idx = (k * l) % NL;
    lc[l] = ct[idx]; ls[l] = st[idx];
  }
  __syncthreads();
  int c0 = tid, c1 = tid + 256;
  float r0 = 0.f, i0 = 0.f, r1 = 0.f, i1 = 0.f;
  const float* fb = f + (size_t)b * NL * NDIN;
  for (int l = 0; l < NL; ++l) {
    float cl = lc[l], sl = ls[l];
    float v0 = fb[(size_t)l * NDIN + c0];
    float v1 = fb[(size_t)l * NDIN + c1];
    r0 += v0 * cl; i0 -= v0 * sl;
    r1 += v1 * cl; i1 -= v1 * sl;
  }
  size_t o = ((size_t)b * NFREQ + k) * NDIN;
  RFb[o + c0] = f2bf(r0 * (1.f / 24.f)); RFb[o + c1] = f2bf(r1 * (1.f / 24.f));
  IFb[o + c0] = f2bf(i0 * (1.f / 24.f)); IFb[o + c1] = f2bf(i1 * (1.f / 24.f));
}

// transpose+bf16 pack: Wt[n][c] = bf16(W[c][n]), 512x512. z=0: Wr, z=1: Wi.
__global__ __launch_bounds__(256) void packw_kernel(
    const float* __restrict__ Wr, const float* __restrict__ Wi,
    unsigned short* __restrict__ Wrt, unsigned short* __restrict__ Wit) {
  __shared__ float tile[64][65];
  const float* W = blockIdx.z ? Wi : Wr;
  unsigned short* Wt = blockIdx.z ? Wit : Wrt;
  int c0 = blockIdx.y * 64, n0 = blockIdx.x * 64;
  int tid = threadIdx.x;
  int r = tid >> 2, q = tid & 3;
#pragma unroll
  for (int j = 0; j < 4; ++j) {
    float4 v = *reinterpret_cast<const float4*>(W + (size_t)(c0 + r) * 512 + n0 + q * 16 + j * 4);
    tile[r][q * 16 + j * 4 + 0] = v.x; tile[r][q * 16 + j * 4 + 1] = v.y;
    tile[r][q * 16 + j * 4 + 2] = v.z; tile[r][q * 16 + j * 4 + 3] = v.w;
  }
  __syncthreads();
  unsigned int pk[8];
#pragma unroll
  for (int i = 0; i < 8; ++i) {
    unsigned int lo = f2bf(tile[q * 16 + 2 * i + 0][r]);
    unsigned int hi = f2bf(tile[q * 16 + 2 * i + 1][r]);
    pk[i] = lo | (hi << 16);
  }
  unsigned int* dst = (unsigned int*)(Wt + (size_t)(n0 + r) * 512 + c0 + q * 16);
  *reinterpret_cast<uint4*>(dst)     = make_uint4(pk[0], pk[1], pk[2], pk[3]);
  *reinterpret_cast<uint4*>(dst + 4) = make_uint4(pk[4], pk[5], pk[6], pk[7]);
}

// complex channel mix on matrix cores:
// xre = relu(RF@Wr - IF@Wi + rb), xim = relu(IF@Wr + RF@Wi + ib)
__global__ __launch_bounds__(256) void mix_mfma_kernel(
    const unsigned short* __restrict__ RFb, const unsigned short* __restrict__ IFb,
    const unsigned short* __restrict__ Wrt, const unsigned short* __restrict__ Wit,
    const float* __restrict__ rb, const float* __restrict__ ib,
    float* __restrict__ xre, float* __restrict__ xim) {
  __shared__ unsigned short AsR[64][40], AsI[64][40], BsR[64][40], BsI[64][40];
  int tid = threadIdx.x;
  int lane = tid & 63, wv = tid >> 6;
  int m0 = blockIdx.y * 64, n0 = blockIdx.x * 64;
  int sm = tid >> 2, part = tid & 3;

  f32x4 accR[4] = {}, accI[4] = {};

  for (int k0 = 0; k0 < 512; k0 += 32) {
    size_t arow = (size_t)(m0 + sm) * 512 + k0 + part * 8;
    size_t brow = (size_t)(n0 + sm) * 512 + k0 + part * 8;
    *(bf16x8*)&AsR[sm][part * 8] = *(const bf16x8*)(RFb + arow);
    *(bf16x8*)&AsI[sm][part * 8] = *(const bf16x8*)(IFb + arow);
    *(bf16x8*)&BsR[sm][part * 8] = *(const bf16x8*)(Wrt + brow);
    *(bf16x8*)&BsI[sm][part * 8] = *(const bf16x8*)(Wit + brow);
    __syncthreads();

    int am = wv * 16 + (lane & 15);
    int koff = (lane >> 4) * 8;
    bf16x8 a_rf = *(bf16x8*)&AsR[am][koff];
    bf16x8 a_if = *(bf16x8*)&AsI[am][koff];
    union { bf16x8 h; i32x4 i; } un;
    un.h = a_if;
    un.i = un.i ^ (int)0x80008000;
    bf16x8 a_ifn = un.h;
#pragma unroll
    for (int t = 0; t < 4; ++t) {
      int bn = t * 16 + (lane & 15);
      bf16x8 b_wr = *(bf16x8*)&BsR[bn][koff];
      bf16x8 b_wi = *(bf16x8*)&BsI[bn][koff];
      accR[t] = __builtin_amdgcn_mfma_f32_16x16x32_bf16(a_rf, b_wr, accR[t], 0, 0, 0);
      accR[t] = __builtin_amdgcn_mfma_f32_16x16x32_bf16(a_ifn, b_wi, accR[t], 0, 0, 0);
      accI[t] = __builtin_amdgcn_mfma_f32_16x16x32_bf16(a_if, b_wr, accI[t], 0, 0, 0);
      accI[t] = __builtin_amdgcn_mfma_f32_16x16x32_bf16(a_rf, b_wi, accI[t], 0, 0, 0);
    }
    __syncthreads();
  }

#pragma unroll
  for (int t = 0; t < 4; ++t) {
    int gn = n0 + t * 16 + (lane & 15);
    float rbv = rb[gn], ibv = ib[gn];
#pragma unroll
    for (int r = 0; r < 4; ++r) {
      int gm = m0 + wv * 16 + (lane >> 4) * 4 + r;
      if (gm < NMROW) {
        size_t o = (size_t)gm * NDIN + gn;
        xre[o] = fmaxf(accR[t][r] + rbv, 0.f);
        xim[o] = fmaxf(accI[t][r] + ibv, 0.f);
      }
    }
  }
}

// irfft: ff[b,l,d] = (1/24) * sum_k w_k (xre*cos - xim*sin), w=1 at k=0,288 else 2
__global__ void idft_kernel(const float* __restrict__ xre,
                            const float* __restrict__ xim,
                            const float* __restrict__ ct,
                            const float* __restrict__ st,
                            float* __restrict__ ff) {
  int l = blockIdx.x, b = blockIdx.y, tid = threadIdx.x;
  __shared__ float wc[NFREQ], wsn[NFREQ];
  for (int k = tid; k < NFREQ; k += 256) {
    int idx = (k * l) % NL;
    float w = (k == 0 || k == NFREQ - 1) ? 1.f : 2.f;
    wc[k] = w * ct[idx]; wsn[k] = w * st[idx];
  }
  __syncthreads();
  int d0 = tid, d1 = tid + 256;
  float a0 = 0.f, a1 = 0.f;
  const float* xr_ = xre + (size_t)b * NFREQ * NDIN;
  const float* xi_ = xim + (size_t)b * NFREQ * NDIN;
  for (int k = 0; k < NFREQ; ++k) {
    float c = wc[k], s = wsn[k];
    a0 += xr_[(size_t)k * NDIN + d0] * c - xi_[(size_t)k * NDIN + d0] * s;
    a1 += xr_[(size_t)k * NDIN + d1] * c - xi_[(size_t)k * NDIN + d1] * s;
  }
  size_t o = ((size_t)b * NL + l) * NDIN;
  ff[o + d0] = a0 * (1.f / 24.f);
  ff[o + d1] = a1 * (1.f / 24.f);
}

extern "C" void kernel_launch(void* const* d_in, const int* in_sizes, int n_in,
                              void* d_out, int out_size, void* d_ws, size_t ws_size,
                              hipStream_t stream) {
  const float* x      = (const float*)d_in[0];
  const float* ln1_g  = (const float*)d_in[1];
  const float* ln1_b  = (const float*)d_in[2];
  const float* mln_g  = (const float*)d_in[3];
  const float* mln_b  = (const float*)d_in[4];
  const float* w_in   = (const float*)d_in[5];
  const float* conv_w = (const float*)d_in[6];
  const float* conv_b = (const float*)d_in[7];
  const float* w_xprj = (const float*)d_in[8];
  const float* w_dt   = (const float*)d_in[9];
  const float* b_dt   = (const float*)d_in[10];
  const float* A_log  = (const float*)d_in[11];
  const float* Dp     = (const float*)d_in[12];
  const float* w_out  = (const float*)d_in[13];
  const float* ln2_g  = (const float*)d_in[14];
  const float* ln2_b  = (const float*)d_in[15];
  const float* fc1_w  = (const float*)d_in[16];
  const float* bn1_s  = (const float*)d_in[17];
  const float* bn1_b  = (const float*)d_in[18];
  const float* Wr     = (const float*)d_in[19];
  const float* Wi     = (const float*)d_in[20];
  const float* rb     = (const float*)d_in[21];
  const float* ib     = (const float*)d_in[22];
  const float* fc2_w  = (const float*)d_in[23];
  const float* bn2_s  = (const float*)d_in[24];
  const float* bn2_b  = (const float*)d_in[25];

  float* ws     = (float*)d_ws;
  float* h      = ws + OFF_H;      // -> h2 later
  float* xr     = ws + OFF_XR;     // -> xre/xim later
  float* xc_t   = ws + OFF_XCT;
  float* res_t  = ws + OFF_REST;
  float* xdbl_t = ws + OFF_XDBL;
  float* delta_t= ws + OFF_DELT;   // -> ff later
  float* yf_t   = ws + OFF_YFT;
  float* x2     = ws + OFF_X2;
  float* f      = ws + OFF_F;      // -> Wrt/Wit later
  float* ct     = ws + OFF_CT;
  float* st     = ws + OFF_ST;
  float* h2     = ws + OFF_H;
  float* xre    = ws + OFF_XR;
  float* xim    = ws + OFF_XR + 591872u;
  float* ff     = ws + OFF_DELT;
  unsigned short* RFb = (unsigned short*)(ws + OFF_RF);
  unsigned short* IFb = (unsigned short*)(ws + OFF_IF);
  unsigned short* Wrt = (unsigned short*)(ws + OFF_F);
  unsigned short* Wit = (unsigned short*)(ws + OFF_F + 131072u);
  float* out  = (float*)d_out;

  trig_kernel<<<1, NL, 0, stream>>>(ct, st);
  // h = LN(LN(x))
  ln_kernel<<<NTOK, 64, 0, stream>>>(x, h, ln1_g, ln1_b, mln_g, mln_b, 1);
  // xr = h @ w_in  (2304x1024)
  gemm_f32<<<dim3(16, 36), 256, 0, stream>>>(h, NC, w_in, NWIN, xr, NWIN,
                                             NTOK, NWIN, NC, 0, 0, nullptr, nullptr, nullptr, 0);
  // xc_t = silu(conv(xm))^T ; res_t = res^T
  convT_kernel<<<dim3(8, 36, 2), 256, 0, stream>>>(xr, conv_w, conv_b, xc_t, res_t);
  // xdbl_t = (xc @ w_xproj)^T   (A = xc_t K-major, transposed store)
  gemm_f32<<<dim3(2, 36), 256, 0, stream>>>(xc_t, NTOK, w_xprj, NXD, xdbl_t, NTOK,
                                            NTOK, NXD, NDIN, 0, 3, nullptr, nullptr, nullptr, 0);
  // delta_t = softplus(dt @ w_dt + b_dt)^T  (A = xdbl_t rows 0..15, K=16)
  gemm_f32<<<dim3(8, 36), 256, 0, stream>>>(xdbl_t, NTOK, w_dt, NDIN, delta_t, NTOK,
                                            NTOK, NDIN, NDTR, 1, 3, nullptr, b_dt, nullptr, 0);
  // yf_t = ((selective_scan + u*D) * silu(res))^T  -- fully coalesced
  scan4_kernel<<<NB * NDIN, 576, 0, stream>>>(delta_t, xc_t, xdbl_t, A_log, Dp, res_t, yf_t);
  // x2 = x + yf @ w_out   (A = yf_t K-major)
  gemm_f32<<<dim3(4, 36), 256, 0, stream>>>(yf_t, NTOK, w_out, NC, x2, NC,
                                            NTOK, NC, NDIN, 2, 1, nullptr, nullptr, x, NC);
  // h2 = LN(x2)
  ln_kernel<<<NTOK, 64, 0, stream>>>(x2, h2, ln2_g, ln2_b, nullptr, nullptr, 0);
  // f = relu(h2 @ fc1_w * bn1_s + bn1_b)
  gemm_f32<<<dim3(8, 36), 256, 0, stream>>>(h2, NC, fc1_w, NDIN, f, NDIN,
                                            NTOK, NDIN, NC, 3, 0, bn1_s, bn1_b, nullptr, 0);
  // rfft (scaled) -> bf16
  dft_fwd_kernel<<<dim3(NFREQ, NB), 256, 0, stream>>>(f, ct, st, RFb, IFb);
  // pack Wr/Wi transposed to bf16 (into dead f region)
  packw_kernel<<<dim3(8, 8, 2), 256, 0, stream>>>(Wr, Wi, Wrt, Wit);
  // complex mix + relu on matrix cores
  mix_mfma_kernel<<<dim3(8, 19), 256, 0, stream>>>(RFb, IFb, Wrt, Wit, rb, ib, xre, xim);
  // irfft (scaled)
  idft_kernel<<<dim3(NL, NB), 256, 0, stream>>>(xre, xim, ct, st, ff);
  // out = x2 + ff @ fc2_w * bn2_s + bn2_b
  gemm_f32<<<dim3(4, 36), 256, 0, stream>>>(ff, NDIN, fc2_w, NC, out, NC,
                                            NTOK, NC, NDIN, 4, 0, bn2_s, bn2_b, x2, NC);
}

// Round 7
// 362.376 us; speedup vs baseline: 2.7183x; 1.3187x over previous
//
#include <hip/hip_runtime.h>
#include <math.h>

#define NB 4
#define NL 576
#define NC 256
#define NTOK (NB*NL)      // 2304
#define NDIN 512
#define NXD 112
#define NDTR 16
#define NDST 48
#define NFREQ 289
#define NWIN 1024         // w_in output width
#define NMROW (NB*NFREQ)  // 1156 rows in freq space
#define NKPK 608          // padded packed-K for irfft (2*289 -> 608)

// ---- workspace layout (floats), with lifetime reuse ----
#define OFF_H     0u         // h (589824) -> h2 later
#define OFF_XR    589824u    // xr (2359296) -> Cf/Sf/Ci bf16 later
#define OFF_XCT   2949120u   // xc_t (1179648)
#define OFF_REST  4128768u   // res_t (1179648)
#define OFF_XDBL  5308416u   // xdbl_t (258048)
#define OFF_DELT  5566464u   // delta_t (1179648) -> ff later
#define OFF_YFT   6746112u   // yf_t (1179648) -> PK bf16 later
#define OFF_X2    7925760u   // x2 (589824)
#define OFF_F     8515584u   // f_t bf16 (589824) + Wrt (131072) + Wit (131072)
#define OFF_RF    9695232u   // RFb bf16 (295936 f32-equiv)
#define OFF_IF    9991168u   // IFb bf16
#define OFF_CT    10287104u
#define OFF_ST    10287680u

typedef __attribute__((ext_vector_type(8))) short bf16x8;
typedef __attribute__((ext_vector_type(4))) float f32x4;
typedef __attribute__((ext_vector_type(4))) int   i32x4;

__device__ __forceinline__ float wave_sum(float v) {
#pragma unroll
  for (int o = 32; o > 0; o >>= 1) v += __shfl_xor(v, o);
  return v;
}

__device__ __forceinline__ unsigned short f2bf(float f) {
  unsigned int u = __float_as_uint(f);
  unsigned int r = (u + 0x7fffu + ((u >> 16) & 1u)) >> 16;  // RNE
  return (unsigned short)r;
}

// 64-lane inclusive prefix sum, no LDS: 4 DPP row_shr adds + 3 readlane bcasts.
__device__ __forceinline__ float wave_iscan(float x, int lane) {
  x += __int_as_float(__builtin_amdgcn_update_dpp(0, __float_as_int(x), 0x111, 0xf, 0xf, true));
  x += __int_as_float(__builtin_amdgcn_update_dpp(0, __float_as_int(x), 0x112, 0xf, 0xf, true));
  x += __int_as_float(__builtin_amdgcn_update_dpp(0, __float_as_int(x), 0x114, 0xf, 0xf, true));
  x += __int_as_float(__builtin_amdgcn_update_dpp(0, __float_as_int(x), 0x118, 0xf, 0xf, true));
  int xi = __float_as_int(x);
  float s15 = __int_as_float(__builtin_amdgcn_readlane(xi, 15));
  float s31 = __int_as_float(__builtin_amdgcn_readlane(xi, 31));
  float s47 = __int_as_float(__builtin_amdgcn_readlane(xi, 47));
  float off = 0.f;
  if (lane >= 16) off += s15;
  if (lane >= 32) off += s31;
  if (lane >= 48) off += s47;
  return x + off;
}

__global__ void trig_kernel(float* ct, float* st) {
  int i = threadIdx.x;
  if (i < NL) {
    double a = (6.283185307179586476925286766559 * (double)i) / (double)NL;
    ct[i] = (float)cos(a);
    st[i] = (float)sin(a);
  }
}

// bf16 trig matrices for forward rfft: Cf[m][l]=cos/24, Sf[m][l]=-sin/24 (m<289)
__global__ void build_cfsf_kernel(const float* __restrict__ ct, const float* __restrict__ st,
                                  unsigned short* __restrict__ Cf, unsigned short* __restrict__ Sf) {
  int m = blockIdx.x, l = threadIdx.x;   // 320 x 576
  float c = 0.f, s = 0.f;
  if (m < NFREQ) {
    int idx = (m * l) % NL;
    c = ct[idx] * (1.f / 24.f);
    s = -st[idx] * (1.f / 24.f);
  }
  Cf[(size_t)m * NL + l] = f2bf(c);
  Sf[(size_t)m * NL + l] = f2bf(s);
}

// bf16 packed irfft matrix: Ci[l][k]: k<289 -> w_k cos/24 ; 289<=k<578 -> -w_kk sin/24 ; else 0
__global__ void build_ci_kernel(const float* __restrict__ ct, const float* __restrict__ st,
                                unsigned short* __restrict__ Ci) {
  int l = blockIdx.x, k = threadIdx.x;   // 576 x 640 (guard 608)
  if (k >= NKPK) return;
  float v = 0.f;
  if (k < NFREQ) {
    float w = (k == 0 || k == NFREQ - 1) ? 1.f : 2.f;
    v = w * ct[(k * l) % NL] * (1.f / 24.f);
  } else if (k < 2 * NFREQ) {
    int kk = k - NFREQ;
    float w = (kk == 0 || kk == NFREQ - 1) ? 1.f : 2.f;
    v = -w * st[(kk * l) % NL] * (1.f / 24.f);
  }
  Ci[(size_t)l * NKPK + k] = f2bf(v);
}

// zero PK pad columns 578..607 (stale bytes there can be bf16 NaN/Inf; 0*NaN=NaN in MFMA)
__global__ void zero_pkpad_kernel(unsigned short* __restrict__ PK) {
  int i = blockIdx.x * blockDim.x + threadIdx.x;   // 2048 rows * 32
  int row = i >> 5, c = i & 31;
  if (row < NDIN * NB && c < NKPK - 2 * NFREQ)
    PK[(size_t)row * NKPK + 2 * NFREQ + c] = 0;
}

// one wave per token row; C=256 -> 4 elems/lane. dbl=1: two chained LNs.
__global__ void ln_kernel(const float* __restrict__ in, float* __restrict__ out,
                          const float* __restrict__ g1, const float* __restrict__ b1,
                          const float* __restrict__ g2, const float* __restrict__ b2,
                          int dbl) {
  int row = blockIdx.x, lane = threadIdx.x;
  const float* p = in + (size_t)row * NC;
  float v[4];
#pragma unroll
  for (int j = 0; j < 4; ++j) v[j] = p[lane + j * 64];
  float s = wave_sum(v[0] + v[1] + v[2] + v[3]);
  float m = s * (1.f / NC);
  float q = 0.f;
#pragma unroll
  for (int j = 0; j < 4; ++j) { float d = v[j] - m; q += d * d; }
  q = wave_sum(q);
  float rs = 1.f / sqrtf(q * (1.f / NC) + 1e-3f);
#pragma unroll
  for (int j = 0; j < 4; ++j) {
    int c = lane + j * 64;
    v[j] = (v[j] - m) * rs * g1[c] + b1[c];
  }
  if (dbl) {
    s = wave_sum(v[0] + v[1] + v[2] + v[3]);
    m = s * (1.f / NC);
    q = 0.f;
#pragma unroll
    for (int j = 0; j < 4; ++j) { float d = v[j] - m; q += d * d; }
    q = wave_sum(q);
    rs = 1.f / sqrtf(q * (1.f / NC) + 1e-3f);
#pragma unroll
    for (int j = 0; j < 4; ++j) {
      int c = lane + j * 64;
      v[j] = (v[j] - m) * rs * g2[c] + b2[c];
    }
  }
  float* o = out + (size_t)row * NC;
#pragma unroll
  for (int j = 0; j < 4; ++j) o[lane + j * 64] = v[j];
}

// generic tiled f32 GEMM: C[M,N] = A @ B[K,N(ldb)], fused epilogues.
// flags bit0: A stored K-major (A_t[k][m], lda = m-stride)
// flags bit1: store C transposed (C[n*ldc + m])
// flags bit2: store C as bf16
// mode 0: store; 1: softplus(v+bias); 2: v+add; 3: relu(v*scl+bias); 4: v*scl+bias+add
__global__ __launch_bounds__(256) void gemm_f32(
    const float* __restrict__ A, int lda, const float* __restrict__ B, int ldb,
    float* __restrict__ C, int ldc, int M, int N, int K, int mode, int flags,
    const float* __restrict__ scl, const float* __restrict__ bias,
    const float* __restrict__ add, int ldadd) {
  __shared__ float As[16][65];   // [k][m]
  __shared__ float Bs[16][68];   // [k][n]
  int tid = threadIdx.x;
  int tx = tid & 15, ty = tid >> 4;
  int m0 = blockIdx.y * 64, n0 = blockIdx.x * 64;
  int am = tid >> 2, ak = (tid & 3) * 4;
  int akr = tid >> 4, am4 = (tid & 15) * 4;
  int bk = tid >> 4, bn = (tid & 15) * 4;
  float acc[4][4] = {};
  for (int k0 = 0; k0 < K; k0 += 16) {
    if (flags & 1) {
      float4 av = make_float4(0.f, 0.f, 0.f, 0.f);
      if (m0 + am4 < M)
        av = *reinterpret_cast<const float4*>(A + (size_t)(k0 + akr) * lda + m0 + am4);
      As[akr][am4 + 0] = av.x; As[akr][am4 + 1] = av.y;
      As[akr][am4 + 2] = av.z; As[akr][am4 + 3] = av.w;
    } else {
      float4 av = make_float4(0.f, 0.f, 0.f, 0.f);
      if (m0 + am < M)
        av = *reinterpret_cast<const float4*>(A + (size_t)(m0 + am) * lda + k0 + ak);
      As[ak + 0][am] = av.x; As[ak + 1][am] = av.y;
      As[ak + 2][am] = av.z; As[ak + 3][am] = av.w;
    }
    float4 bv = make_float4(0.f, 0.f, 0.f, 0.f);
    if (n0 + bn < N)
      bv = *reinterpret_cast<const float4*>(B + (size_t)(k0 + bk) * ldb + n0 + bn);
    *reinterpret_cast<float4*>(&Bs[bk][bn]) = bv;
    __syncthreads();
#pragma unroll
    for (int kk = 0; kk < 16; ++kk) {
      float a[4], b[4];
#pragma unroll
      for (int i = 0; i < 4; ++i) a[i] = As[kk][ty * 4 + i];
#pragma unroll
      for (int j = 0; j < 4; ++j) b[j] = Bs[kk][tx * 4 + j];
#pragma unroll
      for (int i = 0; i < 4; ++i)
#pragma unroll
        for (int j = 0; j < 4; ++j) acc[i][j] += a[i] * b[j];
    }
    __syncthreads();
  }
#pragma unroll
  for (int i = 0; i < 4; ++i) {
    int gm = m0 + ty * 4 + i;
    if (gm >= M) continue;
#pragma unroll
    for (int j = 0; j < 4; ++j) {
      int gn = n0 + tx * 4 + j;
      if (gn >= N) continue;
      float v = acc[i][j];
      if (mode == 1) { v += bias[gn]; v = fmaxf(v, 0.f) + log1pf(expf(-fabsf(v))); }
      else if (mode == 2) { v += add[(size_t)gm * ldadd + gn]; }
      else if (mode == 3) { v = fmaxf(v * scl[gn] + bias[gn], 0.f); }
      else if (mode == 4) { v = v * scl[gn] + bias[gn] + add[(size_t)gm * ldadd + gn]; }
      if (flags & 4) {
        unsigned short* Cb = (unsigned short*)C;
        if (flags & 2) Cb[(size_t)gn * ldc + gm] = f2bf(v);
        else           Cb[(size_t)gm * ldc + gn] = f2bf(v);
      } else if (flags & 2) C[(size_t)gn * ldc + gm] = v;
      else                  C[(size_t)gm * ldc + gn] = v;
    }
  }
}

// Fused causal depthwise conv(4)+silu with transposed output, plus res transpose.
__global__ __launch_bounds__(256) void convT_kernel(
    const float* __restrict__ xr, const float* __restrict__ cw,
    const float* __restrict__ cb, float* __restrict__ xc_t,
    float* __restrict__ res_t) {
  __shared__ float tile[67][65];
  int d0 = blockIdx.x * 64;
  int rt = blockIdx.y;             // 0..35
  int b = rt / 9, l0 = (rt % 9) * 64;
  int tid = threadIdx.x;
  int li = tid & 63, dj0 = tid >> 6;
  if (blockIdx.z == 0) {
    for (int u = tid; u < 67 * 16; u += 256) {
      int r = u >> 4, c4 = (u & 15) * 4;
      int l = l0 - 3 + r;
      float4 v = make_float4(0.f, 0.f, 0.f, 0.f);
      if (l >= 0) v = *reinterpret_cast<const float4*>(xr + (size_t)(b * NL + l) * NWIN + d0 + c4);
      tile[r][c4 + 0] = v.x; tile[r][c4 + 1] = v.y;
      tile[r][c4 + 2] = v.z; tile[r][c4 + 3] = v.w;
    }
    __syncthreads();
    for (int dj = dj0; dj < 64; dj += 4) {
      int d = d0 + dj;
      float acc = cb[d];
#pragma unroll
      for (int k = 0; k < 4; ++k) acc += cw[k * NDIN + d] * tile[li + k][dj];
      acc = acc / (1.f + __expf(-acc));
      xc_t[(size_t)d * NTOK + b * NL + l0 + li] = acc;
    }
  } else {
    for (int u = tid; u < 64 * 16; u += 256) {
      int r = u >> 4, c4 = (u & 15) * 4;
      float4 v = *reinterpret_cast<const float4*>(xr + (size_t)(b * NL + l0 + r) * NWIN + NDIN + d0 + c4);
      tile[r][c4 + 0] = v.x; tile[r][c4 + 1] = v.y;
      tile[r][c4 + 2] = v.z; tile[r][c4 + 3] = v.w;
    }
    __syncthreads();
    for (int dj = dj0; dj < 64; dj += 4)
      res_t[(size_t)(d0 + dj) * NTOK + b * NL + l0 + li] = tile[li][dj];
  }
}

// selective scan, all operands d-major (coalesced). DPP block-parallel scans.
__global__ __launch_bounds__(576) void scan4_kernel(
    const float* __restrict__ delta_t, const float* __restrict__ xc_t,
    const float* __restrict__ xdbl_t, const float* __restrict__ A_log,
    const float* __restrict__ Dp, const float* __restrict__ res_t,
    float* __restrict__ yf_t) {
  __shared__ float part[9];
  __shared__ float part8[9][8];
  int b = blockIdx.x >> 9, d = blockIdx.x & 511;
  int l = threadIdx.x;
  int lane = l & 63, wv = l >> 6;
  int col = b * NL + l;
  float dl = delta_t[(size_t)d * NTOK + col];
  float ul = xc_t[(size_t)d * NTOK + col];
  float rl = res_t[(size_t)d * NTOK + col];
  float s = wave_iscan(dl, lane);
  if (lane == 63) part[wv] = s;
  __syncthreads();
  float off = 0.f, tot = 0.f;
#pragma unroll
  for (int i = 0; i < 9; ++i) { float p = part[i]; tot += p; if (i < wv) off += p; }
  float Tsuf = tot - (s + off);

  const float* Arow = A_log + (size_t)d * NDST;
  float dlul = dl * ul;
  float y = 0.f;
  for (int c = 0; c < 6; ++c) {
    float bb[8], cc[8], e[8], w[8];
#pragma unroll
    for (int j = 0; j < 8; ++j) {
      bb[j] = xdbl_t[(size_t)(NDTR + c * 8 + j) * NTOK + col];
      cc[j] = xdbl_t[(size_t)(NDTR + NDST + c * 8 + j) * NTOK + col];
    }
#pragma unroll
    for (int j = 0; j < 8; ++j) {
      float An = -__expf(Arow[c * 8 + j]);
      e[j] = __expf(An * Tsuf);
      w[j] = dlul * bb[j] * e[j];
    }
#pragma unroll
    for (int j = 0; j < 8; ++j) w[j] = wave_iscan(w[j], lane);
    if (lane == 63) {
#pragma unroll
      for (int j = 0; j < 8; ++j) part8[wv][j] = w[j];
    }
    __syncthreads();
    float po = 0.f;
    if (lane < 8) {
#pragma unroll
      for (int i = 0; i < 8; ++i) { if (i < wv) po += part8[i][lane]; }
    }
    int poi = __float_as_int(po);
#pragma unroll
    for (int j = 0; j < 8; ++j) {
      float offj = __int_as_float(__builtin_amdgcn_readlane(poi, j));
      float ps = w[j] + offj;
      y += __fdividef(ps, e[j] + 1e-12f) * cc[j];
    }
    __syncthreads();
  }
  float yv = y + ul * Dp[d];
  float sr = rl / (1.f + __expf(-rl));
  yf_t[(size_t)d * NTOK + col] = yv * sr;
}

// transpose+bf16 pack: Wt[n][c] = bf16(W[c][n]), 512x512. z=0: Wr, z=1: Wi.
__global__ __launch_bounds__(256) void packw_kernel(
    const float* __restrict__ Wr, const float* __restrict__ Wi,
    unsigned short* __restrict__ Wrt, unsigned short* __restrict__ Wit) {
  __shared__ float tile[64][65];
  const float* W = blockIdx.z ? Wi : Wr;
  unsigned short* Wt = blockIdx.z ? Wit : Wrt;
  int c0 = blockIdx.y * 64, n0 = blockIdx.x * 64;
  int tid = threadIdx.x;
  int r = tid >> 2, q = tid & 3;
#pragma unroll
  for (int j = 0; j < 4; ++j) {
    float4 v = *reinterpret_cast<const float4*>(W + (size_t)(c0 + r) * 512 + n0 + q * 16 + j * 4);
    tile[r][q * 16 + j * 4 + 0] = v.x; tile[r][q * 16 + j * 4 + 1] = v.y;
    tile[r][q * 16 + j * 4 + 2] = v.z; tile[r][q * 16 + j * 4 + 3] = v.w;
  }
  __syncthreads();
  unsigned int pk[8];
#pragma unroll
  for (int i = 0; i < 8; ++i) {
    unsigned int lo = f2bf(tile[q * 16 + 2 * i + 0][r]);
    unsigned int hi = f2bf(tile[q * 16 + 2 * i + 1][r]);
    pk[i] = lo | (hi << 16);
  }
  unsigned int* dst = (unsigned int*)(Wt + (size_t)(n0 + r) * 512 + c0 + q * 16);
  *reinterpret_cast<uint4*>(dst)     = make_uint4(pk[0], pk[1], pk[2], pk[3]);
  *reinterpret_cast<uint4*>(dst + 4) = make_uint4(pk[4], pk[5], pk[6], pk[7]);
}

// forward rfft on matrix cores: RF = Cf@f, IF = Sf@f (signs folded).
// A = Cf/Sf [320][576]; B = f_t [512][2304] (k = l within batch b).
__global__ __launch_bounds__(256) void dftf_mfma_kernel(
    const unsigned short* __restrict__ Cf, const unsigned short* __restrict__ Sf,
    const unsigned short* __restrict__ ft,
    unsigned short* __restrict__ RFb, unsigned short* __restrict__ IFb) {
  __shared__ unsigned short AsC[64][40], AsS[64][40], Bs[64][40];
  int tid = threadIdx.x;
  int lane = tid & 63, wv = tid >> 6;
  int n0 = blockIdx.x * 64, m0 = blockIdx.y * 64, b = blockIdx.z;
  int sm = tid >> 2, part = tid & 3;
  f32x4 accR[4] = {}, accI[4] = {};
  for (int k0 = 0; k0 < NL; k0 += 32) {
    *(bf16x8*)&AsC[sm][part * 8] = *(const bf16x8*)(Cf + (size_t)(m0 + sm) * NL + k0 + part * 8);
    *(bf16x8*)&AsS[sm][part * 8] = *(const bf16x8*)(Sf + (size_t)(m0 + sm) * NL + k0 + part * 8);
    *(bf16x8*)&Bs[sm][part * 8]  = *(const bf16x8*)(ft + (size_t)(n0 + sm) * NTOK + b * NL + k0 + part * 8);
    __syncthreads();
    int am = wv * 16 + (lane & 15);
    int koff = (lane >> 4) * 8;
    bf16x8 ac = *(bf16x8*)&AsC[am][koff];
    bf16x8 as = *(bf16x8*)&AsS[am][koff];
#pragma unroll
    for (int t = 0; t < 4; ++t) {
      bf16x8 bv = *(bf16x8*)&Bs[t * 16 + (lane & 15)][koff];
      accR[t] = __builtin_amdgcn_mfma_f32_16x16x32_bf16(ac, bv, accR[t], 0, 0, 0);
      accI[t] = __builtin_amdgcn_mfma_f32_16x16x32_bf16(as, bv, accI[t], 0, 0, 0);
    }
    __syncthreads();
  }
#pragma unroll
  for (int t = 0; t < 4; ++t) {
    int gn = n0 + t * 16 + (lane & 15);
#pragma unroll
    for (int r = 0; r < 4; ++r) {
      int gm = m0 + wv * 16 + (lane >> 4) * 4 + r;
      if (gm < NFREQ) {
        size_t o = ((size_t)(b * NFREQ + gm)) * NDIN + gn;
        RFb[o] = f2bf(accR[t][r]);
        IFb[o] = f2bf(accI[t][r]);
      }
    }
  }
}

// complex mix, transposed output into packed irfft B-matrix:
// PK[c][b][k]: k<289 -> relu(xre); 289..577 -> relu(xim) (bf16)
__global__ __launch_bounds__(256) void mix_mfma_kernel(
    const unsigned short* __restrict__ RFb, const unsigned short* __restrict__ IFb,
    const unsigned short* __restrict__ Wrt, const unsigned short* __restrict__ Wit,
    const float* __restrict__ rb, const float* __restrict__ ib,
    unsigned short* __restrict__ PK) {
  __shared__ unsigned short AsR[64][40], AsI[64][40], BsR[64][40], BsI[64][40];
  int tid = threadIdx.x;
  int lane = tid & 63, wv = tid >> 6;
  int n0 = blockIdx.x * 64, m0 = blockIdx.y * 64;
  int sm = tid >> 2, part = tid & 3;
  f32x4 accR[4] = {}, accI[4] = {};
  for (int k0 = 0; k0 < NDIN; k0 += 32) {
    *(bf16x8*)&AsR[sm][part * 8] = *(const bf16x8*)(Wrt + (size_t)(m0 + sm) * NDIN + k0 + part * 8);
    *(bf16x8*)&AsI[sm][part * 8] = *(const bf16x8*)(Wit + (size_t)(m0 + sm) * NDIN + k0 + part * 8);
    bf16x8 brf = {}, bif = {};
    if (n0 + sm < NMROW) {
      brf = *(const bf16x8*)(RFb + (size_t)(n0 + sm) * NDIN + k0 + part * 8);
      bif = *(const bf16x8*)(IFb + (size_t)(n0 + sm) * NDIN + k0 + part * 8);
    }
    *(bf16x8*)&BsR[sm][part * 8] = brf;
    *(bf16x8*)&BsI[sm][part * 8] = bif;
    __syncthreads();
    int am = wv * 16 + (lane & 15);
    int koff = (lane >> 4) * 8;
    bf16x8 a_wr = *(bf16x8*)&AsR[am][koff];
    bf16x8 a_wi = *(bf16x8*)&AsI[am][koff];
    union { bf16x8 h; i32x4 i; } un;
    un.h = a_wi;
    un.i = un.i ^ (int)0x80008000;
    bf16x8 a_win = un.h;
#pragma unroll
    for (int t = 0; t < 4; ++t) {
      bf16x8 b_rf = *(bf16x8*)&BsR[t * 16 + (lane & 15)][koff];
      bf16x8 b_if = *(bf16x8*)&BsI[t * 16 + (lane & 15)][koff];
      accR[t] = __builtin_amdgcn_mfma_f32_16x16x32_bf16(a_wr, b_rf, accR[t], 0, 0, 0);
      accR[t] = __builtin_amdgcn_mfma_f32_16x16x32_bf16(a_win, b_if, accR[t], 0, 0, 0);
      accI[t] = __builtin_amdgcn_mfma_f32_16x16x32_bf16(a_wr, b_if, accI[t], 0, 0, 0);
      accI[t] = __builtin_amdgcn_mfma_f32_16x16x32_bf16(a_wi, b_rf, accI[t], 0, 0, 0);
    }
    __syncthreads();
  }
#pragma unroll
  for (int t = 0; t < 4; ++t) {
    int gn = n0 + t * 16 + (lane & 15);   // freq global
    int bb = (gn >= 3 * NFREQ) ? 3 : (gn >= 2 * NFREQ) ? 2 : (gn >= NFREQ) ? 1 : 0;
    int kf = gn - bb * NFREQ;
    bool ok = gn < NMROW;
#pragma unroll
    for (int r = 0; r < 4; ++r) {
      int gm = m0 + wv * 16 + (lane >> 4) * 4 + r;   // c_out
      if (ok) {
        float vr = fmaxf(accR[t][r] + rb[gm], 0.f);
        float vi = fmaxf(accI[t][r] + ib[gm], 0.f);
        size_t base = ((size_t)gm * NB + bb) * NKPK;
        PK[base + kf] = f2bf(vr);
        PK[base + NFREQ + kf] = f2bf(vi);
      }
    }
  }
}

// irfft on matrix cores: ff[b,l,d] = sum_k Ci[l][k] * PK[d][b][k]  (f32 out)
__global__ __launch_bounds__(256) void idft_mfma_kernel(
    const unsigned short* __restrict__ Ci, const unsigned short* __restrict__ PK,
    float* __restrict__ ff) {
  __shared__ unsigned short As[64][40], Bs[64][40];
  int tid = threadIdx.x;
  int lane = tid & 63, wv = tid >> 6;
  int n0 = blockIdx.x * 64, m0 = blockIdx.y * 64, b = blockIdx.z;
  int sm = tid >> 2, part = tid & 3;
  f32x4 acc[4] = {};
  for (int k0 = 0; k0 < NKPK; k0 += 32) {
    *(bf16x8*)&As[sm][part * 8] = *(const bf16x8*)(Ci + (size_t)(m0 + sm) * NKPK + k0 + part * 8);
    *(bf16x8*)&Bs[sm][part * 8] = *(const bf16x8*)(PK + ((size_t)(n0 + sm) * NB + b) * NKPK + k0 + part * 8);
    __syncthreads();
    int am = wv * 16 + (lane & 15);
    int koff = (lane >> 4) * 8;
    bf16x8 av = *(bf16x8*)&As[am][koff];
#pragma unroll
    for (int t = 0; t < 4; ++t) {
      bf16x8 bv = *(bf16x8*)&Bs[t * 16 + (lane & 15)][koff];
      acc[t] = __builtin_amdgcn_mfma_f32_16x16x32_bf16(av, bv, acc[t], 0, 0, 0);
    }
    __syncthreads();
  }
#pragma unroll
  for (int t = 0; t < 4; ++t) {
    int gn = n0 + t * 16 + (lane & 15);     // d
#pragma unroll
    for (int r = 0; r < 4; ++r) {
      int gm = m0 + wv * 16 + (lane >> 4) * 4 + r;   // l
      ff[((size_t)(b * NL + gm)) * NDIN + gn] = acc[t][r];
    }
  }
}

extern "C" void kernel_launch(void* const* d_in, const int* in_sizes, int n_in,
                              void* d_out, int out_size, void* d_ws, size_t ws_size,
                              hipStream_t stream) {
  const float* x      = (const float*)d_in[0];
  const float* ln1_g  = (const float*)d_in[1];
  const float* ln1_b  = (const float*)d_in[2];
  const float* mln_g  = (const float*)d_in[3];
  const float* mln_b  = (const float*)d_in[4];
  const float* w_in   = (const float*)d_in[5];
  const float* conv_w = (const float*)d_in[6];
  const float* conv_b = (const float*)d_in[7];
  const float* w_xprj = (const float*)d_in[8];
  const float* w_dt   = (const float*)d_in[9];
  const float* b_dt   = (const float*)d_in[10];
  const float* A_log  = (const float*)d_in[11];
  const float* Dp     = (const float*)d_in[12];
  const float* w_out  = (const float*)d_in[13];
  const float* ln2_g  = (const float*)d_in[14];
  const float* ln2_b  = (const float*)d_in[15];
  const float* fc1_w  = (const float*)d_in[16];
  const float* bn1_s  = (const float*)d_in[17];
  const float* bn1_b  = (const float*)d_in[18];
  const float* Wr     = (const float*)d_in[19];
  const float* Wi     = (const float*)d_in[20];
  const float* rb     = (const float*)d_in[21];
  const float* ib     = (const float*)d_in[22];
  const float* fc2_w  = (const float*)d_in[23];
  const float* bn2_s  = (const float*)d_in[24];
  const float* bn2_b  = (const float*)d_in[25];

  float* ws     = (float*)d_ws;
  float* h      = ws + OFF_H;
  float* xr     = ws + OFF_XR;
  float* xc_t   = ws + OFF_XCT;
  float* res_t  = ws + OFF_REST;
  float* xdbl_t = ws + OFF_XDBL;
  float* delta_t= ws + OFF_DELT;
  float* yf_t   = ws + OFF_YFT;
  float* x2     = ws + OFF_X2;
  float* ct     = ws + OFF_CT;
  float* st     = ws + OFF_ST;
  float* h2     = ws + OFF_H;
  float* ff     = ws + OFF_DELT;
  unsigned short* Cfb = (unsigned short*)(ws + OFF_XR);             // 320x576
  unsigned short* Sfb = (unsigned short*)(ws + OFF_XR + 92160u);    // 320x576
  unsigned short* Cib = (unsigned short*)(ws + OFF_XR + 184320u);   // 576x608
  unsigned short* PK  = (unsigned short*)(ws + OFF_YFT);            // 512x4x608
  unsigned short* ftb = (unsigned short*)(ws + OFF_F);              // 512x2304
  unsigned short* Wrt = (unsigned short*)(ws + OFF_F + 589824u);
  unsigned short* Wit = (unsigned short*)(ws + OFF_F + 720896u);
  unsigned short* RFb = (unsigned short*)(ws + OFF_RF);
  unsigned short* IFb = (unsigned short*)(ws + OFF_IF);
  float* out  = (float*)d_out;

  trig_kernel<<<1, NL, 0, stream>>>(ct, st);
  // h = LN(LN(x))
  ln_kernel<<<NTOK, 64, 0, stream>>>(x, h, ln1_g, ln1_b, mln_g, mln_b, 1);
  // xr = h @ w_in  (2304x1024)
  gemm_f32<<<dim3(16, 36), 256, 0, stream>>>(h, NC, w_in, NWIN, xr, NWIN,
                                             NTOK, NWIN, NC, 0, 0, nullptr, nullptr, nullptr, 0);
  // xc_t = silu(conv(xm))^T ; res_t = res^T
  convT_kernel<<<dim3(8, 36, 2), 256, 0, stream>>>(xr, conv_w, conv_b, xc_t, res_t);
  // xdbl_t = (xc @ w_xproj)^T
  gemm_f32<<<dim3(2, 36), 256, 0, stream>>>(xc_t, NTOK, w_xprj, NXD, xdbl_t, NTOK,
                                            NTOK, NXD, NDIN, 0, 3, nullptr, nullptr, nullptr, 0);
  // delta_t = softplus(dt @ w_dt + b_dt)^T
  gemm_f32<<<dim3(8, 36), 256, 0, stream>>>(xdbl_t, NTOK, w_dt, NDIN, delta_t, NTOK,
                                            NTOK, NDIN, NDTR, 1, 3, nullptr, b_dt, nullptr, 0);
  // yf_t = ((selective_scan + u*D) * silu(res))^T
  scan4_kernel<<<NB * NDIN, 576, 0, stream>>>(delta_t, xc_t, xdbl_t, A_log, Dp, res_t, yf_t);
  // x2 = x + yf @ w_out   (last reader of yf_t; PK overlays it)
  gemm_f32<<<dim3(4, 36), 256, 0, stream>>>(yf_t, NTOK, w_out, NC, x2, NC,
                                            NTOK, NC, NDIN, 2, 1, nullptr, nullptr, x, NC);
  // build bf16 trig matrices (xr region is dead now)
  build_cfsf_kernel<<<320, NL, 0, stream>>>(ct, st, Cfb, Sfb);
  build_ci_kernel<<<NL, 640, 0, stream>>>(ct, st, Cib);
  // zero PK pad columns (yf_t is dead now; stale bytes would be NaN under 0*x in MFMA)
  zero_pkpad_kernel<<<256, 256, 0, stream>>>(PK);
  // h2 = LN(x2)
  ln_kernel<<<NTOK, 64, 0, stream>>>(x2, h2, ln2_g, ln2_b, nullptr, nullptr, 0);
  // f_t = relu(h2 @ fc1_w * bn1_s + bn1_b)^T as bf16  [512][2304]
  gemm_f32<<<dim3(8, 36), 256, 0, stream>>>(h2, NC, fc1_w, NDIN, (float*)ftb, NTOK,
                                            NTOK, NDIN, NC, 3, 6, bn1_s, bn1_b, nullptr, 0);
  // pack Wr/Wi transposed to bf16
  packw_kernel<<<dim3(8, 8, 2), 256, 0, stream>>>(Wr, Wi, Wrt, Wit);
  // rfft on MFMA -> RFb/IFb bf16
  dftf_mfma_kernel<<<dim3(8, 5, NB), 256, 0, stream>>>(Cfb, Sfb, ftb, RFb, IFb);
  // complex mix + relu on MFMA -> packed PK bf16
  mix_mfma_kernel<<<dim3(19, 8), 256, 0, stream>>>(RFb, IFb, Wrt, Wit, rb, ib, PK);
  // irfft on MFMA -> ff f32
  idft_mfma_kernel<<<dim3(8, 9, NB), 256, 0, stream>>>(Cib, PK, ff);
  // out = x2 + ff @ fc2_w * bn2_s + bn2_b
  gemm_f32<<<dim3(4, 36), 256, 0, stream>>>(ff, NDIN, fc2_w, NC, out, NC,
                                            NTOK, NC, NDIN, 4, 0, bn2_s, bn2_b, x2, NC);
}

// Round 8
// 317.847 us; speedup vs baseline: 3.0992x; 1.1401x over previous
//
#include <hip/hip_runtime.h>
#include <math.h>

#define NB 4
#define NL 576
#define NC 256
#define NTOK (NB*NL)      // 2304
#define NDIN 512
#define NXD 112
#define NDTR 16
#define NDST 48
#define NFREQ 289
#define NWIN 1024         // w_in output width
#define NMROW (NB*NFREQ)  // 1156 rows in freq space
#define NKPK 608          // padded packed-K for irfft (2*289 -> 608)

// ---- workspace layout (floats), with lifetime reuse ----
#define OFF_H     0u         // h (589824) -> h2 later
#define OFF_XR    589824u    // xr (2359296) -> Cf/Sf/Ci bf16 later
#define OFF_XCT   2949120u   // xc_t (1179648)
#define OFF_REST  4128768u   // res_t (1179648)
#define OFF_XDBL  5308416u   // xdbl_t (258048)
#define OFF_DELT  5566464u   // delta_t (1179648) -> ff later
#define OFF_YFT   6746112u   // yf_t (1179648) -> PK bf16 later
#define OFF_X2    7925760u   // x2 (589824)
#define OFF_F     8515584u   // f_t bf16 (589824) + Wrt (131072) + Wit (131072)
#define OFF_RF    9695232u   // RFb bf16 (295936 f32-equiv)
#define OFF_IF    9991168u   // IFb bf16
#define OFF_CT    10287104u
#define OFF_ST    10287680u

typedef __attribute__((ext_vector_type(8))) short bf16x8;
typedef __attribute__((ext_vector_type(4))) float f32x4;
typedef __attribute__((ext_vector_type(4))) int   i32x4;

__device__ __forceinline__ float wave_sum(float v) {
#pragma unroll
  for (int o = 32; o > 0; o >>= 1) v += __shfl_xor(v, o);
  return v;
}

__device__ __forceinline__ unsigned short f2bf(float f) {
  unsigned int u = __float_as_uint(f);
  unsigned int r = (u + 0x7fffu + ((u >> 16) & 1u)) >> 16;  // RNE
  return (unsigned short)r;
}

// 64-lane inclusive prefix sum, no LDS: 4 DPP row_shr adds + 3 readlane bcasts.
__device__ __forceinline__ float wave_iscan(float x, int lane) {
  x += __int_as_float(__builtin_amdgcn_update_dpp(0, __float_as_int(x), 0x111, 0xf, 0xf, true));
  x += __int_as_float(__builtin_amdgcn_update_dpp(0, __float_as_int(x), 0x112, 0xf, 0xf, true));
  x += __int_as_float(__builtin_amdgcn_update_dpp(0, __float_as_int(x), 0x114, 0xf, 0xf, true));
  x += __int_as_float(__builtin_amdgcn_update_dpp(0, __float_as_int(x), 0x118, 0xf, 0xf, true));
  int xi = __float_as_int(x);
  float s15 = __int_as_float(__builtin_amdgcn_readlane(xi, 15));
  float s31 = __int_as_float(__builtin_amdgcn_readlane(xi, 31));
  float s47 = __int_as_float(__builtin_amdgcn_readlane(xi, 47));
  float off = 0.f;
  if (lane >= 16) off += s15;
  if (lane >= 32) off += s31;
  if (lane >= 48) off += s47;
  return x + off;
}

__global__ void trig_kernel(float* ct, float* st) {
  int i = threadIdx.x;
  if (i < NL) {
    double a = (6.283185307179586476925286766559 * (double)i) / (double)NL;
    ct[i] = (float)cos(a);
    st[i] = (float)sin(a);
  }
}

// bf16 trig matrices for forward rfft: Cf[m][l]=cos/24, Sf[m][l]=-sin/24 (m<289)
__global__ void build_cfsf_kernel(const float* __restrict__ ct, const float* __restrict__ st,
                                  unsigned short* __restrict__ Cf, unsigned short* __restrict__ Sf) {
  int m = blockIdx.x, l = threadIdx.x;   // 320 x 576
  float c = 0.f, s = 0.f;
  if (m < NFREQ) {
    int idx = (m * l) % NL;
    c = ct[idx] * (1.f / 24.f);
    s = -st[idx] * (1.f / 24.f);
  }
  Cf[(size_t)m * NL + l] = f2bf(c);
  Sf[(size_t)m * NL + l] = f2bf(s);
}

// bf16 packed irfft matrix: Ci[l][k]: k<289 -> w_k cos/24 ; 289<=k<578 -> -w_kk sin/24 ; else 0
__global__ void build_ci_kernel(const float* __restrict__ ct, const float* __restrict__ st,
                                unsigned short* __restrict__ Ci) {
  int l = blockIdx.x, k = threadIdx.x;   // 576 x 640 (guard 608)
  if (k >= NKPK) return;
  float v = 0.f;
  if (k < NFREQ) {
    float w = (k == 0 || k == NFREQ - 1) ? 1.f : 2.f;
    v = w * ct[(k * l) % NL] * (1.f / 24.f);
  } else if (k < 2 * NFREQ) {
    int kk = k - NFREQ;
    float w = (kk == 0 || kk == NFREQ - 1) ? 1.f : 2.f;
    v = -w * st[(kk * l) % NL] * (1.f / 24.f);
  }
  Ci[(size_t)l * NKPK + k] = f2bf(v);
}

// zero PK pad columns 578..607 (stale bytes there can be bf16 NaN/Inf; 0*NaN=NaN in MFMA)
__global__ void zero_pkpad_kernel(unsigned short* __restrict__ PK) {
  int i = blockIdx.x * blockDim.x + threadIdx.x;   // 2048 rows * 32
  int row = i >> 5, c = i & 31;
  if (row < NDIN * NB && c < NKPK - 2 * NFREQ)
    PK[(size_t)row * NKPK + 2 * NFREQ + c] = 0;
}

// one wave per token row; C=256 -> 4 elems/lane. dbl=1: two chained LNs.
__global__ void ln_kernel(const float* __restrict__ in, float* __restrict__ out,
                          const float* __restrict__ g1, const float* __restrict__ b1,
                          const float* __restrict__ g2, const float* __restrict__ b2,
                          int dbl) {
  int row = blockIdx.x, lane = threadIdx.x;
  const float* p = in + (size_t)row * NC;
  float v[4];
#pragma unroll
  for (int j = 0; j < 4; ++j) v[j] = p[lane + j * 64];
  float s = wave_sum(v[0] + v[1] + v[2] + v[3]);
  float m = s * (1.f / NC);
  float q = 0.f;
#pragma unroll
  for (int j = 0; j < 4; ++j) { float d = v[j] - m; q += d * d; }
  q = wave_sum(q);
  float rs = 1.f / sqrtf(q * (1.f / NC) + 1e-3f);
#pragma unroll
  for (int j = 0; j < 4; ++j) {
    int c = lane + j * 64;
    v[j] = (v[j] - m) * rs * g1[c] + b1[c];
  }
  if (dbl) {
    s = wave_sum(v[0] + v[1] + v[2] + v[3]);
    m = s * (1.f / NC);
    q = 0.f;
#pragma unroll
    for (int j = 0; j < 4; ++j) { float d = v[j] - m; q += d * d; }
    q = wave_sum(q);
    rs = 1.f / sqrtf(q * (1.f / NC) + 1e-3f);
#pragma unroll
    for (int j = 0; j < 4; ++j) {
      int c = lane + j * 64;
      v[j] = (v[j] - m) * rs * g2[c] + b2[c];
    }
  }
  float* o = out + (size_t)row * NC;
#pragma unroll
  for (int j = 0; j < 4; ++j) o[lane + j * 64] = v[j];
}

// generic tiled f32 GEMM: C[M,N] = A @ B[K,N(ldb)], fused epilogues.
// flags bit0: A stored K-major; bit1: store C^T; bit2: store bf16
// mode 0: store; 1: softplus(v+bias); 2: v+add; 3: relu(v*scl+bias); 4: v*scl+bias+add
__global__ __launch_bounds__(256) void gemm_f32(
    const float* __restrict__ A, int lda, const float* __restrict__ B, int ldb,
    float* __restrict__ C, int ldc, int M, int N, int K, int mode, int flags,
    const float* __restrict__ scl, const float* __restrict__ bias,
    const float* __restrict__ add, int ldadd) {
  __shared__ float As[16][65];   // [k][m]
  __shared__ float Bs[16][68];   // [k][n]
  int tid = threadIdx.x;
  int tx = tid & 15, ty = tid >> 4;
  int m0 = blockIdx.y * 64, n0 = blockIdx.x * 64;
  int am = tid >> 2, ak = (tid & 3) * 4;
  int akr = tid >> 4, am4 = (tid & 15) * 4;
  int bk = tid >> 4, bn = (tid & 15) * 4;
  float acc[4][4] = {};
  for (int k0 = 0; k0 < K; k0 += 16) {
    if (flags & 1) {
      float4 av = make_float4(0.f, 0.f, 0.f, 0.f);
      if (m0 + am4 < M)
        av = *reinterpret_cast<const float4*>(A + (size_t)(k0 + akr) * lda + m0 + am4);
      As[akr][am4 + 0] = av.x; As[akr][am4 + 1] = av.y;
      As[akr][am4 + 2] = av.z; As[akr][am4 + 3] = av.w;
    } else {
      float4 av = make_float4(0.f, 0.f, 0.f, 0.f);
      if (m0 + am < M)
        av = *reinterpret_cast<const float4*>(A + (size_t)(m0 + am) * lda + k0 + ak);
      As[ak + 0][am] = av.x; As[ak + 1][am] = av.y;
      As[ak + 2][am] = av.z; As[ak + 3][am] = av.w;
    }
    float4 bv = make_float4(0.f, 0.f, 0.f, 0.f);
    if (n0 + bn < N)
      bv = *reinterpret_cast<const float4*>(B + (size_t)(k0 + bk) * ldb + n0 + bn);
    *reinterpret_cast<float4*>(&Bs[bk][bn]) = bv;
    __syncthreads();
#pragma unroll
    for (int kk = 0; kk < 16; ++kk) {
      float a[4], b[4];
#pragma unroll
      for (int i = 0; i < 4; ++i) a[i] = As[kk][ty * 4 + i];
#pragma unroll
      for (int j = 0; j < 4; ++j) b[j] = Bs[kk][tx * 4 + j];
#pragma unroll
      for (int i = 0; i < 4; ++i)
#pragma unroll
        for (int j = 0; j < 4; ++j) acc[i][j] += a[i] * b[j];
    }
    __syncthreads();
  }
#pragma unroll
  for (int i = 0; i < 4; ++i) {
    int gm = m0 + ty * 4 + i;
    if (gm >= M) continue;
#pragma unroll
    for (int j = 0; j < 4; ++j) {
      int gn = n0 + tx * 4 + j;
      if (gn >= N) continue;
      float v = acc[i][j];
      if (mode == 1) { v += bias[gn]; v = fmaxf(v, 0.f) + log1pf(expf(-fabsf(v))); }
      else if (mode == 2) { v += add[(size_t)gm * ldadd + gn]; }
      else if (mode == 3) { v = fmaxf(v * scl[gn] + bias[gn], 0.f); }
      else if (mode == 4) { v = v * scl[gn] + bias[gn] + add[(size_t)gm * ldadd + gn]; }
      if (flags & 4) {
        unsigned short* Cb = (unsigned short*)C;
        if (flags & 2) Cb[(size_t)gn * ldc + gm] = f2bf(v);
        else           Cb[(size_t)gm * ldc + gn] = f2bf(v);
      } else if (flags & 2) C[(size_t)gn * ldc + gm] = v;
      else                  C[(size_t)gm * ldc + gn] = v;
    }
  }
}

// Fused causal depthwise conv(4)+silu with transposed output, plus res transpose.
__global__ __launch_bounds__(256) void convT_kernel(
    const float* __restrict__ xr, const float* __restrict__ cw,
    const float* __restrict__ cb, float* __restrict__ xc_t,
    float* __restrict__ res_t) {
  __shared__ float tile[67][65];
  int d0 = blockIdx.x * 64;
  int rt = blockIdx.y;             // 0..35
  int b = rt / 9, l0 = (rt % 9) * 64;
  int tid = threadIdx.x;
  int li = tid & 63, dj0 = tid >> 6;
  if (blockIdx.z == 0) {
    for (int u = tid; u < 67 * 16; u += 256) {
      int r = u >> 4, c4 = (u & 15) * 4;
      int l = l0 - 3 + r;
      float4 v = make_float4(0.f, 0.f, 0.f, 0.f);
      if (l >= 0) v = *reinterpret_cast<const float4*>(xr + (size_t)(b * NL + l) * NWIN + d0 + c4);
      tile[r][c4 + 0] = v.x; tile[r][c4 + 1] = v.y;
      tile[r][c4 + 2] = v.z; tile[r][c4 + 3] = v.w;
    }
    __syncthreads();
    for (int dj = dj0; dj < 64; dj += 4) {
      int d = d0 + dj;
      float acc = cb[d];
#pragma unroll
      for (int k = 0; k < 4; ++k) acc += cw[k * NDIN + d] * tile[li + k][dj];
      acc = acc / (1.f + __expf(-acc));
      xc_t[(size_t)d * NTOK + b * NL + l0 + li] = acc;
    }
  } else {
    for (int u = tid; u < 64 * 16; u += 256) {
      int r = u >> 4, c4 = (u & 15) * 4;
      float4 v = *reinterpret_cast<const float4*>(xr + (size_t)(b * NL + l0 + r) * NWIN + NDIN + d0 + c4);
      tile[r][c4 + 0] = v.x; tile[r][c4 + 1] = v.y;
      tile[r][c4 + 2] = v.z; tile[r][c4 + 3] = v.w;
    }
    __syncthreads();
    for (int dj = dj0; dj < 64; dj += 4)
      res_t[(size_t)(d0 + dj) * NTOK + b * NL + l0 + li] = tile[li][dj];
  }
}

// selective scan, thread-coarsened: one block = one (b,d); 4 waves x 12 states.
// Each lane owns 9 consecutive l: serial prefix in registers + ONE wave scan.
__global__ __launch_bounds__(256) void scan5_kernel(
    const float* __restrict__ delta_t, const float* __restrict__ xc_t,
    const float* __restrict__ xdbl_t, const float* __restrict__ A_log,
    const float* __restrict__ Dp, const float* __restrict__ res_t,
    float* __restrict__ yf_t) {
  __shared__ float yl[4][NL];
  int b = blockIdx.x >> 9, d = blockIdx.x & 511;
  int tid = threadIdx.x, lane = tid & 63, wv = tid >> 6;
  int bbase = b * NL;
  int col0 = bbase + lane * 9;
  const float* drow = delta_t + (size_t)d * NTOK;
  const float* urow = xc_t + (size_t)d * NTOK;

  float dl[9], ul[9];
#pragma unroll
  for (int j = 0; j < 9; ++j) { dl[j] = drow[col0 + j]; ul[j] = urow[col0 + j]; }
  // inclusive prefix within thread
  float pre[9];
  float s = 0.f;
#pragma unroll
  for (int j = 0; j < 9; ++j) { s += dl[j]; pre[j] = s; }
  // one wave scan of per-lane totals
  float isc = wave_iscan(s, lane);
  float total = __int_as_float(__builtin_amdgcn_readlane(__float_as_int(isc), 63));
  float excl = isc - s;
  float Ts[9], dlul[9];
#pragma unroll
  for (int j = 0; j < 9; ++j) {
    Ts[j] = total - excl - pre[j];     // suffix sum (exclusive of self)
    dlul[j] = dl[j] * ul[j];
  }

  const float* Arow = A_log + (size_t)d * NDST + wv * 12;
  float y[9] = {};
  for (int jj = 0; jj < 12; ++jj) {
    float An = -__expf(Arow[jj]);
    const float* bbp = xdbl_t + (size_t)(NDTR + wv * 12 + jj) * NTOK + col0;
    const float* ccp = xdbl_t + (size_t)(NDTR + NDST + wv * 12 + jj) * NTOK + col0;
    float e[9], w[9];
    float ps = 0.f;
#pragma unroll
    for (int j = 0; j < 9; ++j) {
      e[j] = __expf(An * Ts[j]);
      ps += dlul[j] * bbp[j] * e[j];
      w[j] = ps;
    }
    float wi = wave_iscan(ps, lane);
    float wexcl = wi - ps;
#pragma unroll
    for (int j = 0; j < 9; ++j)
      y[j] += __fdividef(w[j] + wexcl, e[j] + 1e-12f) * ccp[j];
  }
#pragma unroll
  for (int j = 0; j < 9; ++j) yl[wv][lane * 9 + j] = y[j];
  __syncthreads();

  const float* rrow = res_t + (size_t)d * NTOK;
  float* orow = yf_t + (size_t)d * NTOK;
  float Dd = Dp[d];
  for (int e0 = tid; e0 < NL; e0 += 256) {
    float yy = yl[0][e0] + yl[1][e0] + yl[2][e0] + yl[3][e0];
    float uu = urow[bbase + e0];
    float rr = rrow[bbase + e0];
    float yv = yy + uu * Dd;
    float sr = rr / (1.f + __expf(-rr));
    orow[bbase + e0] = yv * sr;
  }
}

// transpose+bf16 pack: Wt[n][c] = bf16(W[c][n]), 512x512. z=0: Wr, z=1: Wi.
__global__ __launch_bounds__(256) void packw_kernel(
    const float* __restrict__ Wr, const float* __restrict__ Wi,
    unsigned short* __restrict__ Wrt, unsigned short* __restrict__ Wit) {
  __shared__ float tile[64][65];
  const float* W = blockIdx.z ? Wi : Wr;
  unsigned short* Wt = blockIdx.z ? Wit : Wrt;
  int c0 = blockIdx.y * 64, n0 = blockIdx.x * 64;
  int tid = threadIdx.x;
  int r = tid >> 2, q = tid & 3;
#pragma unroll
  for (int j = 0; j < 4; ++j) {
    float4 v = *reinterpret_cast<const float4*>(W + (size_t)(c0 + r) * 512 + n0 + q * 16 + j * 4);
    tile[r][q * 16 + j * 4 + 0] = v.x; tile[r][q * 16 + j * 4 + 1] = v.y;
    tile[r][q * 16 + j * 4 + 2] = v.z; tile[r][q * 16 + j * 4 + 3] = v.w;
  }
  __syncthreads();
  unsigned int pk[8];
#pragma unroll
  for (int i = 0; i < 8; ++i) {
    unsigned int lo = f2bf(tile[q * 16 + 2 * i + 0][r]);
    unsigned int hi = f2bf(tile[q * 16 + 2 * i + 1][r]);
    pk[i] = lo | (hi << 16);
  }
  unsigned int* dst = (unsigned int*)(Wt + (size_t)(n0 + r) * 512 + c0 + q * 16);
  *reinterpret_cast<uint4*>(dst)     = make_uint4(pk[0], pk[1], pk[2], pk[3]);
  *reinterpret_cast<uint4*>(dst + 4) = make_uint4(pk[4], pk[5], pk[6], pk[7]);
}

// forward rfft on matrix cores: RF = Cf@f, IF = Sf@f (signs folded).
__global__ __launch_bounds__(256) void dftf_mfma_kernel(
    const unsigned short* __restrict__ Cf, const unsigned short* __restrict__ Sf,
    const unsigned short* __restrict__ ft,
    unsigned short* __restrict__ RFb, unsigned short* __restrict__ IFb) {
  __shared__ unsigned short AsC[64][40], AsS[64][40], Bs[64][40];
  int tid = threadIdx.x;
  int lane = tid & 63, wv = tid >> 6;
  int n0 = blockIdx.x * 64, m0 = blockIdx.y * 64, b = blockIdx.z;
  int sm = tid >> 2, part = tid & 3;
  f32x4 accR[4] = {}, accI[4] = {};
  for (int k0 = 0; k0 < NL; k0 += 32) {
    *(bf16x8*)&AsC[sm][part * 8] = *(const bf16x8*)(Cf + (size_t)(m0 + sm) * NL + k0 + part * 8);
    *(bf16x8*)&AsS[sm][part * 8] = *(const bf16x8*)(Sf + (size_t)(m0 + sm) * NL + k0 + part * 8);
    *(bf16x8*)&Bs[sm][part * 8]  = *(const bf16x8*)(ft + (size_t)(n0 + sm) * NTOK + b * NL + k0 + part * 8);
    __syncthreads();
    int am = wv * 16 + (lane & 15);
    int koff = (lane >> 4) * 8;
    bf16x8 ac = *(bf16x8*)&AsC[am][koff];
    bf16x8 as = *(bf16x8*)&AsS[am][koff];
#pragma unroll
    for (int t = 0; t < 4; ++t) {
      bf16x8 bv = *(bf16x8*)&Bs[t * 16 + (lane & 15)][koff];
      accR[t] = __builtin_amdgcn_mfma_f32_16x16x32_bf16(ac, bv, accR[t], 0, 0, 0);
      accI[t] = __builtin_amdgcn_mfma_f32_16x16x32_bf16(as, bv, accI[t], 0, 0, 0);
    }
    __syncthreads();
  }
#pragma unroll
  for (int t = 0; t < 4; ++t) {
    int gn = n0 + t * 16 + (lane & 15);
#pragma unroll
    for (int r = 0; r < 4; ++r) {
      int gm = m0 + wv * 16 + (lane >> 4) * 4 + r;
      if (gm < NFREQ) {
        size_t o = ((size_t)(b * NFREQ + gm)) * NDIN + gn;
        RFb[o] = f2bf(accR[t][r]);
        IFb[o] = f2bf(accI[t][r]);
      }
    }
  }
}

// complex mix, transposed output into packed irfft B-matrix (bf16).
__global__ __launch_bounds__(256) void mix_mfma_kernel(
    const unsigned short* __restrict__ RFb, const unsigned short* __restrict__ IFb,
    const unsigned short* __restrict__ Wrt, const unsigned short* __restrict__ Wit,
    const float* __restrict__ rb, const float* __restrict__ ib,
    unsigned short* __restrict__ PK) {
  __shared__ unsigned short AsR[64][40], AsI[64][40], BsR[64][40], BsI[64][40];
  int tid = threadIdx.x;
  int lane = tid & 63, wv = tid >> 6;
  int n0 = blockIdx.x * 64, m0 = blockIdx.y * 64;
  int sm = tid >> 2, part = tid & 3;
  f32x4 accR[4] = {}, accI[4] = {};
  for (int k0 = 0; k0 < NDIN; k0 += 32) {
    *(bf16x8*)&AsR[sm][part * 8] = *(const bf16x8*)(Wrt + (size_t)(m0 + sm) * NDIN + k0 + part * 8);
    *(bf16x8*)&AsI[sm][part * 8] = *(const bf16x8*)(Wit + (size_t)(m0 + sm) * NDIN + k0 + part * 8);
    bf16x8 brf = {}, bif = {};
    if (n0 + sm < NMROW) {
      brf = *(const bf16x8*)(RFb + (size_t)(n0 + sm) * NDIN + k0 + part * 8);
      bif = *(const bf16x8*)(IFb + (size_t)(n0 + sm) * NDIN + k0 + part * 8);
    }
    *(bf16x8*)&BsR[sm][part * 8] = brf;
    *(bf16x8*)&BsI[sm][part * 8] = bif;
    __syncthreads();
    int am = wv * 16 + (lane & 15);
    int koff = (lane >> 4) * 8;
    bf16x8 a_wr = *(bf16x8*)&AsR[am][koff];
    bf16x8 a_wi = *(bf16x8*)&AsI[am][koff];
    union { bf16x8 h; i32x4 i; } un;
    un.h = a_wi;
    un.i = un.i ^ (int)0x80008000;
    bf16x8 a_win = un.h;
#pragma unroll
    for (int t = 0; t < 4; ++t) {
      bf16x8 b_rf = *(bf16x8*)&BsR[t * 16 + (lane & 15)][koff];
      bf16x8 b_if = *(bf16x8*)&BsI[t * 16 + (lane & 15)][koff];
      accR[t] = __builtin_amdgcn_mfma_f32_16x16x32_bf16(a_wr, b_rf, accR[t], 0, 0, 0);
      accR[t] = __builtin_amdgcn_mfma_f32_16x16x32_bf16(a_win, b_if, accR[t], 0, 0, 0);
      accI[t] = __builtin_amdgcn_mfma_f32_16x16x32_bf16(a_wr, b_if, accI[t], 0, 0, 0);
      accI[t] = __builtin_amdgcn_mfma_f32_16x16x32_bf16(a_wi, b_rf, accI[t], 0, 0, 0);
    }
    __syncthreads();
  }
#pragma unroll
  for (int t = 0; t < 4; ++t) {
    int gn = n0 + t * 16 + (lane & 15);   // freq global
    int bb = (gn >= 3 * NFREQ) ? 3 : (gn >= 2 * NFREQ) ? 2 : (gn >= NFREQ) ? 1 : 0;
    int kf = gn - bb * NFREQ;
    bool ok = gn < NMROW;
#pragma unroll
    for (int r = 0; r < 4; ++r) {
      int gm = m0 + wv * 16 + (lane >> 4) * 4 + r;   // c_out
      if (ok) {
        float vr = fmaxf(accR[t][r] + rb[gm], 0.f);
        float vi = fmaxf(accI[t][r] + ib[gm], 0.f);
        size_t base = ((size_t)gm * NB + bb) * NKPK;
        PK[base + kf] = f2bf(vr);
        PK[base + NFREQ + kf] = f2bf(vi);
      }
    }
  }
}

// irfft on matrix cores: ff[b,l,d] = sum_k Ci[l][k] * PK[d][b][k]  (f32 out)
__global__ __launch_bounds__(256) void idft_mfma_kernel(
    const unsigned short* __restrict__ Ci, const unsigned short* __restrict__ PK,
    float* __restrict__ ff) {
  __shared__ unsigned short As[64][40], Bs[64][40];
  int tid = threadIdx.x;
  int lane = tid & 63, wv = tid >> 6;
  int n0 = blockIdx.x * 64, m0 = blockIdx.y * 64, b = blockIdx.z;
  int sm = tid >> 2, part = tid & 3;
  f32x4 acc[4] = {};
  for (int k0 = 0; k0 < NKPK; k0 += 32) {
    *(bf16x8*)&As[sm][part * 8] = *(const bf16x8*)(Ci + (size_t)(m0 + sm) * NKPK + k0 + part * 8);
    *(bf16x8*)&Bs[sm][part * 8] = *(const bf16x8*)(PK + ((size_t)(n0 + sm) * NB + b) * NKPK + k0 + part * 8);
    __syncthreads();
    int am = wv * 16 + (lane & 15);
    int koff = (lane >> 4) * 8;
    bf16x8 av = *(bf16x8*)&As[am][koff];
#pragma unroll
    for (int t = 0; t < 4; ++t) {
      bf16x8 bv = *(bf16x8*)&Bs[t * 16 + (lane & 15)][koff];
      acc[t] = __builtin_amdgcn_mfma_f32_16x16x32_bf16(av, bv, acc[t], 0, 0, 0);
    }
    __syncthreads();
  }
#pragma unroll
  for (int t = 0; t < 4; ++t) {
    int gn = n0 + t * 16 + (lane & 15);     // d
#pragma unroll
    for (int r = 0; r < 4; ++r) {
      int gm = m0 + wv * 16 + (lane >> 4) * 4 + r;   // l
      ff[((size_t)(b * NL + gm)) * NDIN + gn] = acc[t][r];
    }
  }
}

extern "C" void kernel_launch(void* const* d_in, const int* in_sizes, int n_in,
                              void* d_out, int out_size, void* d_ws, size_t ws_size,
                              hipStream_t stream) {
  const float* x      = (const float*)d_in[0];
  const float* ln1_g  = (const float*)d_in[1];
  const float* ln1_b  = (const float*)d_in[2];
  const float* mln_g  = (const float*)d_in[3];
  const float* mln_b  = (const float*)d_in[4];
  const float* w_in   = (const float*)d_in[5];
  const float* conv_w = (const float*)d_in[6];
  const float* conv_b = (const float*)d_in[7];
  const float* w_xprj = (const float*)d_in[8];
  const float* w_dt   = (const float*)d_in[9];
  const float* b_dt   = (const float*)d_in[10];
  const float* A_log  = (const float*)d_in[11];
  const float* Dp     = (const float*)d_in[12];
  const float* w_out  = (const float*)d_in[13];
  const float* ln2_g  = (const float*)d_in[14];
  const float* ln2_b  = (const float*)d_in[15];
  const float* fc1_w  = (const float*)d_in[16];
  const float* bn1_s  = (const float*)d_in[17];
  const float* bn1_b  = (const float*)d_in[18];
  const float* Wr     = (const float*)d_in[19];
  const float* Wi     = (const float*)d_in[20];
  const float* rb     = (const float*)d_in[21];
  const float* ib     = (const float*)d_in[22];
  const float* fc2_w  = (const float*)d_in[23];
  const float* bn2_s  = (const float*)d_in[24];
  const float* bn2_b  = (const float*)d_in[25];

  float* ws     = (float*)d_ws;
  float* h      = ws + OFF_H;
  float* xr     = ws + OFF_XR;
  float* xc_t   = ws + OFF_XCT;
  float* res_t  = ws + OFF_REST;
  float* xdbl_t = ws + OFF_XDBL;
  float* delta_t= ws + OFF_DELT;
  float* yf_t   = ws + OFF_YFT;
  float* x2     = ws + OFF_X2;
  float* ct     = ws + OFF_CT;
  float* st     = ws + OFF_ST;
  float* h2     = ws + OFF_H;
  float* ff     = ws + OFF_DELT;
  unsigned short* Cfb = (unsigned short*)(ws + OFF_XR);             // 320x576
  unsigned short* Sfb = (unsigned short*)(ws + OFF_XR + 92160u);    // 320x576
  unsigned short* Cib = (unsigned short*)(ws + OFF_XR + 184320u);   // 576x608
  unsigned short* PK  = (unsigned short*)(ws + OFF_YFT);            // 512x4x608
  unsigned short* ftb = (unsigned short*)(ws + OFF_F);              // 512x2304
  unsigned short* Wrt = (unsigned short*)(ws + OFF_F + 589824u);
  unsigned short* Wit = (unsigned short*)(ws + OFF_F + 720896u);
  unsigned short* RFb = (unsigned short*)(ws + OFF_RF);
  unsigned short* IFb = (unsigned short*)(ws + OFF_IF);
  float* out  = (float*)d_out;

  trig_kernel<<<1, NL, 0, stream>>>(ct, st);
  // h = LN(LN(x))
  ln_kernel<<<NTOK, 64, 0, stream>>>(x, h, ln1_g, ln1_b, mln_g, mln_b, 1);
  // xr = h @ w_in  (2304x1024)
  gemm_f32<<<dim3(16, 36), 256, 0, stream>>>(h, NC, w_in, NWIN, xr, NWIN,
                                             NTOK, NWIN, NC, 0, 0, nullptr, nullptr, nullptr, 0);
  // xc_t = silu(conv(xm))^T ; res_t = res^T
  convT_kernel<<<dim3(8, 36, 2), 256, 0, stream>>>(xr, conv_w, conv_b, xc_t, res_t);
  // xdbl_t = (xc @ w_xproj)^T
  gemm_f32<<<dim3(2, 36), 256, 0, stream>>>(xc_t, NTOK, w_xprj, NXD, xdbl_t, NTOK,
                                            NTOK, NXD, NDIN, 0, 3, nullptr, nullptr, nullptr, 0);
  // delta_t = softplus(dt @ w_dt + b_dt)^T
  gemm_f32<<<dim3(8, 36), 256, 0, stream>>>(xdbl_t, NTOK, w_dt, NDIN, delta_t, NTOK,
                                            NTOK, NDIN, NDTR, 1, 3, nullptr, b_dt, nullptr, 0);
  // yf_t = ((selective_scan + u*D) * silu(res))^T  -- thread-coarsened scan
  scan5_kernel<<<NB * NDIN, 256, 0, stream>>>(delta_t, xc_t, xdbl_t, A_log, Dp, res_t, yf_t);
  // x2 = x + yf @ w_out   (last reader of yf_t; PK overlays it)
  gemm_f32<<<dim3(4, 36), 256, 0, stream>>>(yf_t, NTOK, w_out, NC, x2, NC,
                                            NTOK, NC, NDIN, 2, 1, nullptr, nullptr, x, NC);
  // build bf16 trig matrices (xr region is dead now)
  build_cfsf_kernel<<<320, NL, 0, stream>>>(ct, st, Cfb, Sfb);
  build_ci_kernel<<<NL, 640, 0, stream>>>(ct, st, Cib);
  // zero PK pad columns (yf_t is dead now)
  zero_pkpad_kernel<<<256, 256, 0, stream>>>(PK);
  // h2 = LN(x2)
  ln_kernel<<<NTOK, 64, 0, stream>>>(x2, h2, ln2_g, ln2_b, nullptr, nullptr, 0);
  // f_t = relu(h2 @ fc1_w * bn1_s + bn1_b)^T as bf16  [512][2304]
  gemm_f32<<<dim3(8, 36), 256, 0, stream>>>(h2, NC, fc1_w, NDIN, (float*)ftb, NTOK,
                                            NTOK, NDIN, NC, 3, 6, bn1_s, bn1_b, nullptr, 0);
  // pack Wr/Wi transposed to bf16
  packw_kernel<<<dim3(8, 8, 2), 256, 0, stream>>>(Wr, Wi, Wrt, Wit);
  // rfft on MFMA -> RFb/IFb bf16
  dftf_mfma_kernel<<<dim3(8, 5, NB), 256, 0, stream>>>(Cfb, Sfb, ftb, RFb, IFb);
  // complex mix + relu on MFMA -> packed PK bf16
  mix_mfma_kernel<<<dim3(19, 8), 256, 0, stream>>>(RFb, IFb, Wrt, Wit, rb, ib, PK);
  // irfft on MFMA -> ff f32
  idft_mfma_kernel<<<dim3(8, 9, NB), 256, 0, stream>>>(Cib, PK, ff);
  // out = x2 + ff @ fc2_w * bn2_s + bn2_b
  gemm_f32<<<dim3(4, 36), 256, 0, stream>>>(ff, NDIN, fc2_w, NC, out, NC,
                                            NTOK, NC, NDIN, 4, 0, bn2_s, bn2_b, x2, NC);
}

// Round 9
// 247.728 us; speedup vs baseline: 3.9764x; 1.2831x over previous
//
#include <hip/hip_runtime.h>
#include <math.h>

#define NB 4
#define NL 576
#define NC 256
#define NTOK (NB*NL)      // 2304
#define NDIN 512
#define NXD 112
#define NDTR 16
#define NDST 48
#define NFREQ 289
#define NWIN 1024
#define NMROW (NB*NFREQ)  // 1156
#define NKPK 608          // packed K for irfft (2*289 -> 608)

// ---- workspace layout (f32-equivalent offsets), lifetime-reused ----
#define OFF_HB    0u         // hb bf16 [2304][256] -> h2b later
#define OFF_XR    294912u    // xr f32 [2304][1024]; dead after convT -> subdivided:
#define OFF_CF    (OFF_XR + 0u)        // Cfb bf16 320x576   (92160)
#define OFF_SF    (OFF_XR + 92160u)    // Sfb bf16 320x576   (92160)
#define OFF_CI    (OFF_XR + 184320u)   // Cib bf16 576x608   (175104)
#define OFF_YFB   (OFF_XR + 359424u)   // yfb bf16 [2304][512] (589824)
#define OFF_FFB   (OFF_XR + 949248u)   // ffb bf16 [2304][512] (589824)
#define OFF_WXPT  (OFF_XR + 1539072u)  // w_xprojT bf16 [112][512]
#define OFF_WOT   (OFF_XR + 1567744u)  // w_outT bf16 [256][512]
#define OFF_FC1T  (OFF_XR + 1633280u)  // fc1T bf16 [512][256]
#define OFF_FC2T  (OFF_XR + 1698816u)  // fc2T bf16 [256][512]
#define OFF_XCT   2654208u   // xc_t f32 [512][2304]
#define OFF_REST  3833856u   // res_t f32 [512][2304]
#define OFF_XCB   5013504u   // xcb bf16 [2304][512]
#define OFF_XDBL  5603328u   // xdbl_t f32 [112][2304]
#define OFF_YFT   5861376u   // yf_t f32 [512][2304] -> PK bf16 [512*4][608]
#define OFF_X2    7041024u   // x2 f32 [2304][256]
#define OFF_FTB   7630848u   // ftb bf16 [512][2304]
#define OFF_RF    8220672u   // RFb bf16 [1156][512]
#define OFF_IF    8516608u   // IFb bf16
#define OFF_WRT   8812544u   // Wrt bf16 [512][512]
#define OFF_WIT   8943616u   // Wit bf16
#define OFF_WINT  9074688u   // w_inT bf16 [1024][256]
#define OFF_CT    9205760u
#define OFF_ST    9206336u

typedef __attribute__((ext_vector_type(8))) short bf16x8;
typedef __attribute__((ext_vector_type(4))) float f32x4;
typedef __attribute__((ext_vector_type(4))) int   i32x4;

__device__ __forceinline__ float wave_sum(float v) {
#pragma unroll
  for (int o = 32; o > 0; o >>= 1) v += __shfl_xor(v, o);
  return v;
}

__device__ __forceinline__ unsigned short f2bf(float f) {
  unsigned int u = __float_as_uint(f);
  unsigned int r = (u + 0x7fffu + ((u >> 16) & 1u)) >> 16;  // RNE
  return (unsigned short)r;
}

// 64-lane inclusive prefix sum via DPP + readlane broadcasts.
__device__ __forceinline__ float wave_iscan(float x, int lane) {
  x += __int_as_float(__builtin_amdgcn_update_dpp(0, __float_as_int(x), 0x111, 0xf, 0xf, true));
  x += __int_as_float(__builtin_amdgcn_update_dpp(0, __float_as_int(x), 0x112, 0xf, 0xf, true));
  x += __int_as_float(__builtin_amdgcn_update_dpp(0, __float_as_int(x), 0x114, 0xf, 0xf, true));
  x += __int_as_float(__builtin_amdgcn_update_dpp(0, __float_as_int(x), 0x118, 0xf, 0xf, true));
  int xi = __float_as_int(x);
  float s15 = __int_as_float(__builtin_amdgcn_readlane(xi, 15));
  float s31 = __int_as_float(__builtin_amdgcn_readlane(xi, 31));
  float s47 = __int_as_float(__builtin_amdgcn_readlane(xi, 47));
  float off = 0.f;
  if (lane >= 16) off += s15;
  if (lane >= 32) off += s31;
  if (lane >= 48) off += s47;
  return x + off;
}

__global__ void trig_kernel(float* ct, float* st) {
  int i = threadIdx.x;
  if (i < NL) {
    double a = (6.283185307179586476925286766559 * (double)i) / (double)NL;
    ct[i] = (float)cos(a);
    st[i] = (float)sin(a);
  }
}

__global__ void build_cfsf_kernel(const float* __restrict__ ct, const float* __restrict__ st,
                                  unsigned short* __restrict__ Cf, unsigned short* __restrict__ Sf) {
  int m = blockIdx.x, l = threadIdx.x;   // 320 x 576
  float c = 0.f, s = 0.f;
  if (m < NFREQ) {
    int idx = (m * l) % NL;
    c = ct[idx] * (1.f / 24.f);
    s = -st[idx] * (1.f / 24.f);
  }
  Cf[(size_t)m * NL + l] = f2bf(c);
  Sf[(size_t)m * NL + l] = f2bf(s);
}

__global__ void build_ci_kernel(const float* __restrict__ ct, const float* __restrict__ st,
                                unsigned short* __restrict__ Ci) {
  int l = blockIdx.x, k = threadIdx.x;   // 576 x 640 (guard 608)
  if (k >= NKPK) return;
  float v = 0.f;
  if (k < NFREQ) {
    float w = (k == 0 || k == NFREQ - 1) ? 1.f : 2.f;
    v = w * ct[(k * l) % NL] * (1.f / 24.f);
  } else if (k < 2 * NFREQ) {
    int kk = k - NFREQ;
    float w = (kk == 0 || kk == NFREQ - 1) ? 1.f : 2.f;
    v = -w * st[(kk * l) % NL] * (1.f / 24.f);
  }
  Ci[(size_t)l * NKPK + k] = f2bf(v);
}

__global__ void zero_pkpad_kernel(unsigned short* __restrict__ PK) {
  int i = blockIdx.x * blockDim.x + threadIdx.x;
  int row = i >> 5, c = i & 31;
  if (row < NDIN * NB && c < NKPK - 2 * NFREQ)
    PK[(size_t)row * NKPK + 2 * NFREQ + c] = 0;
}

// one wave per token row; bf16 output. dbl=1: two chained LNs.
__global__ void ln_kernel(const float* __restrict__ in, unsigned short* __restrict__ out,
                          const float* __restrict__ g1, const float* __restrict__ b1,
                          const float* __restrict__ g2, const float* __restrict__ b2,
                          int dbl) {
  int row = blockIdx.x, lane = threadIdx.x;
  const float* p = in + (size_t)row * NC;
  float v[4];
#pragma unroll
  for (int j = 0; j < 4; ++j) v[j] = p[lane + j * 64];
  float s = wave_sum(v[0] + v[1] + v[2] + v[3]);
  float m = s * (1.f / NC);
  float q = 0.f;
#pragma unroll
  for (int j = 0; j < 4; ++j) { float d = v[j] - m; q += d * d; }
  q = wave_sum(q);
  float rs = 1.f / sqrtf(q * (1.f / NC) + 1e-3f);
#pragma unroll
  for (int j = 0; j < 4; ++j) {
    int c = lane + j * 64;
    v[j] = (v[j] - m) * rs * g1[c] + b1[c];
  }
  if (dbl) {
    s = wave_sum(v[0] + v[1] + v[2] + v[3]);
    m = s * (1.f / NC);
    q = 0.f;
#pragma unroll
    for (int j = 0; j < 4; ++j) { float d = v[j] - m; q += d * d; }
    q = wave_sum(q);
    rs = 1.f / sqrtf(q * (1.f / NC) + 1e-3f);
#pragma unroll
    for (int j = 0; j < 4; ++j) {
      int c = lane + j * 64;
      v[j] = (v[j] - m) * rs * g2[c] + b2[c];
    }
  }
  unsigned short* o = out + (size_t)row * NC;
#pragma unroll
  for (int j = 0; j < 4; ++j) o[lane + j * 64] = f2bf(v[j]);
}

// transpose + bf16 pack: dst[c][r] = bf16(src[r][c]); guards for any R,C.
__global__ __launch_bounds__(256) void packT_kernel(
    const float* __restrict__ src, unsigned short* __restrict__ dst, int R, int C) {
  __shared__ float tile[64][65];
  int c0 = blockIdx.x * 64, r0 = blockIdx.y * 64;
  int tid = threadIdx.x;
  for (int u = tid; u < 4096; u += 256) {
    int r = u >> 6, c = u & 63;
    float v = 0.f;
    if (r0 + r < R && c0 + c < C) v = src[(size_t)(r0 + r) * C + c0 + c];
    tile[r][c] = v;
  }
  __syncthreads();
  for (int u = tid; u < 4096; u += 256) {
    int nr = u >> 6, nc = u & 63;
    if (c0 + nr < C && r0 + nc < R)
      dst[(size_t)(c0 + nr) * R + r0 + nc] = f2bf(tile[nc][nr]);
  }
}

// generic MFMA GEMM: C = A[M][K]bf16 @ B[N][K]bf16^T (f32 accum), fused epilogues.
// mode 0: store; 2: v+add; 3: relu(v*scl+bias); 4: v*scl+bias+add
// flags bit1: transposed store C[n][m]; bit2: bf16 store. M must be mult of 64.
__global__ __launch_bounds__(256) void gemm_mfma(
    const unsigned short* __restrict__ A, const unsigned short* __restrict__ B,
    void* __restrict__ C, int ldc, int M, int N, int K, int mode, int flags,
    const float* __restrict__ scl, const float* __restrict__ bias,
    const float* __restrict__ add, int ldadd) {
  __shared__ unsigned short As[64][40], Bs[64][40];
  int tid = threadIdx.x, lane = tid & 63, wv = tid >> 6;
  int n0 = blockIdx.x * 64, m0 = blockIdx.y * 64;
  int sm = tid >> 2, part = tid & 3;
  f32x4 acc[4] = {};
  for (int k0 = 0; k0 < K; k0 += 32) {
    *(bf16x8*)&As[sm][part * 8] = *(const bf16x8*)(A + (size_t)(m0 + sm) * K + k0 + part * 8);
    bf16x8 bv = {};
    if (n0 + sm < N) bv = *(const bf16x8*)(B + (size_t)(n0 + sm) * K + k0 + part * 8);
    *(bf16x8*)&Bs[sm][part * 8] = bv;
    __syncthreads();
    int am = wv * 16 + (lane & 15), koff = (lane >> 4) * 8;
    bf16x8 a = *(bf16x8*)&As[am][koff];
#pragma unroll
    for (int t = 0; t < 4; ++t) {
      bf16x8 b = *(bf16x8*)&Bs[t * 16 + (lane & 15)][koff];
      acc[t] = __builtin_amdgcn_mfma_f32_16x16x32_bf16(a, b, acc[t], 0, 0, 0);
    }
    __syncthreads();
  }
#pragma unroll
  for (int t = 0; t < 4; ++t) {
    int gn = n0 + t * 16 + (lane & 15);
    if (gn >= N) continue;
    float sv = scl ? scl[gn] : 0.f, bvv = bias ? bias[gn] : 0.f;
#pragma unroll
    for (int r = 0; r < 4; ++r) {
      int gm = m0 + wv * 16 + (lane >> 4) * 4 + r;
      float v = acc[t][r];
      if (mode == 2) v += add[(size_t)gm * ldadd + gn];
      else if (mode == 3) v = fmaxf(v * sv + bvv, 0.f);
      else if (mode == 4) v = v * sv + bvv + add[(size_t)gm * ldadd + gn];
      size_t o = (flags & 2) ? (size_t)gn * ldc + gm : (size_t)gm * ldc + gn;
      if (flags & 4) ((unsigned short*)C)[o] = f2bf(v);
      else ((float*)C)[o] = v;
    }
  }
}

// Fused causal depthwise conv(4)+silu: xc_t f32 (d-major) + xcb bf16 (tok-major);
// z=1: res transpose -> res_t.
__global__ __launch_bounds__(256) void convT_kernel(
    const float* __restrict__ xr, const float* __restrict__ cw,
    const float* __restrict__ cb, float* __restrict__ xc_t,
    float* __restrict__ res_t, unsigned short* __restrict__ xcb) {
  __shared__ float tile[67][65];
  int d0 = blockIdx.x * 64;
  int rt = blockIdx.y;
  int b = rt / 9, l0 = (rt % 9) * 64;
  int tid = threadIdx.x;
  int li = tid & 63, dj0 = tid >> 6;
  if (blockIdx.z == 0) {
    for (int u = tid; u < 67 * 16; u += 256) {
      int r = u >> 4, c4 = (u & 15) * 4;
      int l = l0 - 3 + r;
      float4 v = make_float4(0.f, 0.f, 0.f, 0.f);
      if (l >= 0) v = *reinterpret_cast<const float4*>(xr + (size_t)(b * NL + l) * NWIN + d0 + c4);
      tile[r][c4 + 0] = v.x; tile[r][c4 + 1] = v.y;
      tile[r][c4 + 2] = v.z; tile[r][c4 + 3] = v.w;
    }
    __syncthreads();
    float outv[16];
#pragma unroll
    for (int k2 = 0; k2 < 16; ++k2) {
      int dj = dj0 + k2 * 4;
      int d = d0 + dj;
      float acc = cb[d];
#pragma unroll
      for (int k = 0; k < 4; ++k) acc += cw[k * NDIN + d] * tile[li + k][dj];
      acc = acc / (1.f + __expf(-acc));
      outv[k2] = acc;
      xc_t[(size_t)d * NTOK + b * NL + l0 + li] = acc;
    }
    __syncthreads();
#pragma unroll
    for (int k2 = 0; k2 < 16; ++k2) tile[li][dj0 + k2 * 4] = outv[k2];
    __syncthreads();
    for (int u = tid; u < 1024; u += 256) {
      int r = u >> 4, c4 = (u & 15) * 4;
      unsigned long long pk =
          (unsigned long long)f2bf(tile[r][c4 + 0]) |
          ((unsigned long long)f2bf(tile[r][c4 + 1]) << 16) |
          ((unsigned long long)f2bf(tile[r][c4 + 2]) << 32) |
          ((unsigned long long)f2bf(tile[r][c4 + 3]) << 48);
      *(unsigned long long*)(xcb + (size_t)(b * NL + l0 + r) * NDIN + d0 + c4) = pk;
    }
  } else {
    for (int u = tid; u < 64 * 16; u += 256) {
      int r = u >> 4, c4 = (u & 15) * 4;
      float4 v = *reinterpret_cast<const float4*>(xr + (size_t)(b * NL + l0 + r) * NWIN + NDIN + d0 + c4);
      tile[r][c4 + 0] = v.x; tile[r][c4 + 1] = v.y;
      tile[r][c4 + 2] = v.z; tile[r][c4 + 3] = v.w;
    }
    __syncthreads();
    for (int dj = dj0; dj < 64; dj += 4)
      res_t[(size_t)(d0 + dj) * NTOK + b * NL + l0 + li] = tile[li][dj];
  }
}

// selective scan with fused delta: one block = one (b,d); 4 waves x 12 states;
// each lane owns 9 consecutive l (serial prefix + one wave scan).
__global__ __launch_bounds__(256) void scan6_kernel(
    const float* __restrict__ xc_t, const float* __restrict__ xdbl_t,
    const float* __restrict__ w_dt, const float* __restrict__ b_dt,
    const float* __restrict__ A_log, const float* __restrict__ Dp,
    const float* __restrict__ res_t, float* __restrict__ yf_t) {
  __shared__ float yl[4][NL];
  int b = blockIdx.x >> 9, d = blockIdx.x & 511;
  int tid = threadIdx.x, lane = tid & 63, wv = tid >> 6;
  int bbase = b * NL;
  int col0 = bbase + lane * 9;
  const float* urow = xc_t + (size_t)d * NTOK;

  // fused delta = softplus(dt @ w_dt[:,d] + b_dt[d]) for this thread's 9 tokens
  float wdt[16];
#pragma unroll
  for (int r = 0; r < 16; ++r) wdt[r] = w_dt[r * NDIN + d];
  float bd = b_dt[d];
  float dl[9];
#pragma unroll
  for (int j = 0; j < 9; ++j) dl[j] = bd;
#pragma unroll
  for (int r = 0; r < 16; ++r) {
    const float* dtp = xdbl_t + (size_t)r * NTOK + col0;
#pragma unroll
    for (int j = 0; j < 9; ++j) dl[j] += dtp[j] * wdt[r];
  }
#pragma unroll
  for (int j = 0; j < 9; ++j) {
    float v = dl[j];
    dl[j] = fmaxf(v, 0.f) + log1pf(__expf(-fabsf(v)));
  }

  float ul[9];
#pragma unroll
  for (int j = 0; j < 9; ++j) ul[j] = urow[col0 + j];
  float pre[9];
  float s = 0.f;
#pragma unroll
  for (int j = 0; j < 9; ++j) { s += dl[j]; pre[j] = s; }
  float isc = wave_iscan(s, lane);
  float total = __int_as_float(__builtin_amdgcn_readlane(__float_as_int(isc), 63));
  float excl = isc - s;
  float Ts[9], dlul[9];
#pragma unroll
  for (int j = 0; j < 9; ++j) {
    Ts[j] = total - excl - pre[j];
    dlul[j] = dl[j] * ul[j];
  }

  const float* Arow = A_log + (size_t)d * NDST + wv * 12;
  float y[9] = {};
  for (int jj = 0; jj < 12; ++jj) {
    float An = -__expf(Arow[jj]);
    const float* bbp = xdbl_t + (size_t)(NDTR + wv * 12 + jj) * NTOK + col0;
    const float* ccp = xdbl_t + (size_t)(NDTR + NDST + wv * 12 + jj) * NTOK + col0;
    float e[9], w[9];
    float ps = 0.f;
#pragma unroll
    for (int j = 0; j < 9; ++j) {
      e[j] = __expf(An * Ts[j]);
      ps += dlul[j] * bbp[j] * e[j];
      w[j] = ps;
    }
    float wi = wave_iscan(ps, lane);
    float wexcl = wi - ps;
#pragma unroll
    for (int j = 0; j < 9; ++j)
      y[j] += __fdividef(w[j] + wexcl, e[j] + 1e-12f) * ccp[j];
  }
#pragma unroll
  for (int j = 0; j < 9; ++j) yl[wv][lane * 9 + j] = y[j];
  __syncthreads();

  const float* rrow = res_t + (size_t)d * NTOK;
  float* orow = yf_t + (size_t)d * NTOK;
  float Dd = Dp[d];
  for (int e0 = tid; e0 < NL; e0 += 256) {
    float yy = yl[0][e0] + yl[1][e0] + yl[2][e0] + yl[3][e0];
    float uu = urow[bbase + e0];
    float rr = rrow[bbase + e0];
    float yv = yy + uu * Dd;
    float sr = rr / (1.f + __expf(-rr));
    orow[bbase + e0] = yv * sr;
  }
}

// forward rfft on matrix cores: RF = Cf@f, IF = Sf@f.
__global__ __launch_bounds__(256) void dftf_mfma_kernel(
    const unsigned short* __restrict__ Cf, const unsigned short* __restrict__ Sf,
    const unsigned short* __restrict__ ft,
    unsigned short* __restrict__ RFb, unsigned short* __restrict__ IFb) {
  __shared__ unsigned short AsC[64][40], AsS[64][40], Bs[64][40];
  int tid = threadIdx.x;
  int lane = tid & 63, wv = tid >> 6;
  int n0 = blockIdx.x * 64, m0 = blockIdx.y * 64, b = blockIdx.z;
  int sm = tid >> 2, part = tid & 3;
  f32x4 accR[4] = {}, accI[4] = {};
  for (int k0 = 0; k0 < NL; k0 += 32) {
    *(bf16x8*)&AsC[sm][part * 8] = *(const bf16x8*)(Cf + (size_t)(m0 + sm) * NL + k0 + part * 8);
    *(bf16x8*)&AsS[sm][part * 8] = *(const bf16x8*)(Sf + (size_t)(m0 + sm) * NL + k0 + part * 8);
    *(bf16x8*)&Bs[sm][part * 8]  = *(const bf16x8*)(ft + (size_t)(n0 + sm) * NTOK + b * NL + k0 + part * 8);
    __syncthreads();
    int am = wv * 16 + (lane & 15);
    int koff = (lane >> 4) * 8;
    bf16x8 ac = *(bf16x8*)&AsC[am][koff];
    bf16x8 as = *(bf16x8*)&AsS[am][koff];
#pragma unroll
    for (int t = 0; t < 4; ++t) {
      bf16x8 bv = *(bf16x8*)&Bs[t * 16 + (lane & 15)][koff];
      accR[t] = __builtin_amdgcn_mfma_f32_16x16x32_bf16(ac, bv, accR[t], 0, 0, 0);
      accI[t] = __builtin_amdgcn_mfma_f32_16x16x32_bf16(as, bv, accI[t], 0, 0, 0);
    }
    __syncthreads();
  }
#pragma unroll
  for (int t = 0; t < 4; ++t) {
    int gn = n0 + t * 16 + (lane & 15);
#pragma unroll
    for (int r = 0; r < 4; ++r) {
      int gm = m0 + wv * 16 + (lane >> 4) * 4 + r;
      if (gm < NFREQ) {
        size_t o = ((size_t)(b * NFREQ + gm)) * NDIN + gn;
        RFb[o] = f2bf(accR[t][r]);
        IFb[o] = f2bf(accI[t][r]);
      }
    }
  }
}

// complex mix -> packed irfft B-matrix PK (bf16).
__global__ __launch_bounds__(256) void mix_mfma_kernel(
    const unsigned short* __restrict__ RFb, const unsigned short* __restrict__ IFb,
    const unsigned short* __restrict__ Wrt, const unsigned short* __restrict__ Wit,
    const float* __restrict__ rb, const float* __restrict__ ib,
    unsigned short* __restrict__ PK) {
  __shared__ unsigned short AsR[64][40], AsI[64][40], BsR[64][40], BsI[64][40];
  int tid = threadIdx.x;
  int lane = tid & 63, wv = tid >> 6;
  int n0 = blockIdx.x * 64, m0 = blockIdx.y * 64;
  int sm = tid >> 2, part = tid & 3;
  f32x4 accR[4] = {}, accI[4] = {};
  for (int k0 = 0; k0 < NDIN; k0 += 32) {
    *(bf16x8*)&AsR[sm][part * 8] = *(const bf16x8*)(Wrt + (size_t)(m0 + sm) * NDIN + k0 + part * 8);
    *(bf16x8*)&AsI[sm][part * 8] = *(const bf16x8*)(Wit + (size_t)(m0 + sm) * NDIN + k0 + part * 8);
    bf16x8 brf = {}, bif = {};
    if (n0 + sm < NMROW) {
      brf = *(const bf16x8*)(RFb + (size_t)(n0 + sm) * NDIN + k0 + part * 8);
      bif = *(const bf16x8*)(IFb + (size_t)(n0 + sm) * NDIN + k0 + part * 8);
    }
    *(bf16x8*)&BsR[sm][part * 8] = brf;
    *(bf16x8*)&BsI[sm][part * 8] = bif;
    __syncthreads();
    int am = wv * 16 + (lane & 15);
    int koff = (lane >> 4) * 8;
    bf16x8 a_wr = *(bf16x8*)&AsR[am][koff];
    bf16x8 a_wi = *(bf16x8*)&AsI[am][koff];
    union { bf16x8 h; i32x4 i; } un;
    un.h = a_wi;
    un.i = un.i ^ (int)0x80008000;
    bf16x8 a_win = un.h;
#pragma unroll
    for (int t = 0; t < 4; ++t) {
      bf16x8 b_rf = *(bf16x8*)&BsR[t * 16 + (lane & 15)][koff];
      bf16x8 b_if = *(bf16x8*)&BsI[t * 16 + (lane & 15)][koff];
      accR[t] = __builtin_amdgcn_mfma_f32_16x16x32_bf16(a_wr, b_rf, accR[t], 0, 0, 0);
      accR[t] = __builtin_amdgcn_mfma_f32_16x16x32_bf16(a_win, b_if, accR[t], 0, 0, 0);
      accI[t] = __builtin_amdgcn_mfma_f32_16x16x32_bf16(a_wr, b_if, accI[t], 0, 0, 0);
      accI[t] = __builtin_amdgcn_mfma_f32_16x16x32_bf16(a_wi, b_rf, accI[t], 0, 0, 0);
    }
    __syncthreads();
  }
#pragma unroll
  for (int t = 0; t < 4; ++t) {
    int gn = n0 + t * 16 + (lane & 15);   // freq global
    int bb = (gn >= 3 * NFREQ) ? 3 : (gn >= 2 * NFREQ) ? 2 : (gn >= NFREQ) ? 1 : 0;
    int kf = gn - bb * NFREQ;
    bool ok = gn < NMROW;
#pragma unroll
    for (int r = 0; r < 4; ++r) {
      int gm = m0 + wv * 16 + (lane >> 4) * 4 + r;   // c_out
      if (ok) {
        float vr = fmaxf(accR[t][r] + rb[gm], 0.f);
        float vi = fmaxf(accI[t][r] + ib[gm], 0.f);
        size_t base = ((size_t)gm * NB + bb) * NKPK;
        PK[base + kf] = f2bf(vr);
        PK[base + NFREQ + kf] = f2bf(vi);
      }
    }
  }
}

// irfft on matrix cores -> ffb bf16 [2304][512]
__global__ __launch_bounds__(256) void idft_mfma_kernel(
    const unsigned short* __restrict__ Ci, const unsigned short* __restrict__ PK,
    unsigned short* __restrict__ ffb) {
  __shared__ unsigned short As[64][40], Bs[64][40];
  int tid = threadIdx.x;
  int lane = tid & 63, wv = tid >> 6;
  int n0 = blockIdx.x * 64, m0 = blockIdx.y * 64, b = blockIdx.z;
  int sm = tid >> 2, part = tid & 3;
  f32x4 acc[4] = {};
  for (int k0 = 0; k0 < NKPK; k0 += 32) {
    *(bf16x8*)&As[sm][part * 8] = *(const bf16x8*)(Ci + (size_t)(m0 + sm) * NKPK + k0 + part * 8);
    *(bf16x8*)&Bs[sm][part * 8] = *(const bf16x8*)(PK + ((size_t)(n0 + sm) * NB + b) * NKPK + k0 + part * 8);
    __syncthreads();
    int am = wv * 16 + (lane & 15);
    int koff = (lane >> 4) * 8;
    bf16x8 av = *(bf16x8*)&As[am][koff];
#pragma unroll
    for (int t = 0; t < 4; ++t) {
      bf16x8 bv = *(bf16x8*)&Bs[t * 16 + (lane & 15)][koff];
      acc[t] = __builtin_amdgcn_mfma_f32_16x16x32_bf16(av, bv, acc[t], 0, 0, 0);
    }
    __syncthreads();
  }
#pragma unroll
  for (int t = 0; t < 4; ++t) {
    int gn = n0 + t * 16 + (lane & 15);     // d
#pragma unroll
    for (int r = 0; r < 4; ++r) {
      int gm = m0 + wv * 16 + (lane >> 4) * 4 + r;   // l
      ffb[((size_t)(b * NL + gm)) * NDIN + gn] = f2bf(acc[t][r]);
    }
  }
}

extern "C" void kernel_launch(void* const* d_in, const int* in_sizes, int n_in,
                              void* d_out, int out_size, void* d_ws, size_t ws_size,
                              hipStream_t stream) {
  const float* x      = (const float*)d_in[0];
  const float* ln1_g  = (const float*)d_in[1];
  const float* ln1_b  = (const float*)d_in[2];
  const float* mln_g  = (const float*)d_in[3];
  const float* mln_b  = (const float*)d_in[4];
  const float* w_in   = (const float*)d_in[5];
  const float* conv_w = (const float*)d_in[6];
  const float* conv_b = (const float*)d_in[7];
  const float* w_xprj = (const float*)d_in[8];
  const float* w_dt   = (const float*)d_in[9];
  const float* b_dt   = (const float*)d_in[10];
  const float* A_log  = (const float*)d_in[11];
  const float* Dp     = (const float*)d_in[12];
  const float* w_out  = (const float*)d_in[13];
  const float* ln2_g  = (const float*)d_in[14];
  const float* ln2_b  = (const float*)d_in[15];
  const float* fc1_w  = (const float*)d_in[16];
  const float* bn1_s  = (const float*)d_in[17];
  const float* bn1_b  = (const float*)d_in[18];
  const float* Wr     = (const float*)d_in[19];
  const float* Wi     = (const float*)d_in[20];
  const float* rb     = (const float*)d_in[21];
  const float* ib     = (const float*)d_in[22];
  const float* fc2_w  = (const float*)d_in[23];
  const float* bn2_s  = (const float*)d_in[24];
  const float* bn2_b  = (const float*)d_in[25];

  float* ws = (float*)d_ws;
  unsigned short* hb   = (unsigned short*)(ws + OFF_HB);   // then h2b
  float* xr     = ws + OFF_XR;
  float* xc_t   = ws + OFF_XCT;
  float* res_t  = ws + OFF_REST;
  float* xdbl_t = ws + OFF_XDBL;
  float* yf_t   = ws + OFF_YFT;
  float* x2     = ws + OFF_X2;
  float* ct     = ws + OFF_CT;
  float* st     = ws + OFF_ST;
  unsigned short* xcb  = (unsigned short*)(ws + OFF_XCB);
  unsigned short* Cfb  = (unsigned short*)(ws + OFF_CF);
  unsigned short* Sfb  = (unsigned short*)(ws + OFF_SF);
  unsigned short* Cib  = (unsigned short*)(ws + OFF_CI);
  unsigned short* yfb  = (unsigned short*)(ws + OFF_YFB);
  unsigned short* ffb  = (unsigned short*)(ws + OFF_FFB);
  unsigned short* wxpT = (unsigned short*)(ws + OFF_WXPT);
  unsigned short* woT  = (unsigned short*)(ws + OFF_WOT);
  unsigned short* fc1T = (unsigned short*)(ws + OFF_FC1T);
  unsigned short* fc2T = (unsigned short*)(ws + OFF_FC2T);
  unsigned short* winT = (unsigned short*)(ws + OFF_WINT);
  unsigned short* PK   = (unsigned short*)(ws + OFF_YFT);
  unsigned short* ftb  = (unsigned short*)(ws + OFF_FTB);
  unsigned short* Wrt  = (unsigned short*)(ws + OFF_WRT);
  unsigned short* Wit  = (unsigned short*)(ws + OFF_WIT);
  unsigned short* RFb  = (unsigned short*)(ws + OFF_RF);
  unsigned short* IFb  = (unsigned short*)(ws + OFF_IF);
  unsigned short* h2b  = hb;
  float* out = (float*)d_out;

  trig_kernel<<<1, NL, 0, stream>>>(ct, st);
  // hb = bf16(LN(LN(x)))
  ln_kernel<<<NTOK, 64, 0, stream>>>(x, hb, ln1_g, ln1_b, mln_g, mln_b, 1);
  // weight packs independent of xr lifetime
  packT_kernel<<<dim3(16, 4), 256, 0, stream>>>(w_in, winT, NC, NWIN);
  packT_kernel<<<dim3(8, 8), 256, 0, stream>>>(Wr, Wrt, NDIN, NDIN);
  packT_kernel<<<dim3(8, 8), 256, 0, stream>>>(Wi, Wit, NDIN, NDIN);
  // xr = hb @ w_in (f32 out)
  gemm_mfma<<<dim3(16, 36), 256, 0, stream>>>(hb, winT, xr, NWIN, NTOK, NWIN, NC,
                                              0, 0, nullptr, nullptr, nullptr, 0);
  // xc_t f32 + xcb bf16 + res_t
  convT_kernel<<<dim3(8, 36, 2), 256, 0, stream>>>(xr, conv_w, conv_b, xc_t, res_t, xcb);
  // xr dead: packs + trig matrices into its region
  packT_kernel<<<dim3(2, 8), 256, 0, stream>>>(w_xprj, wxpT, NDIN, NXD);
  packT_kernel<<<dim3(4, 8), 256, 0, stream>>>(w_out, woT, NDIN, NC);
  packT_kernel<<<dim3(8, 4), 256, 0, stream>>>(fc1_w, fc1T, NC, NDIN);
  packT_kernel<<<dim3(4, 8), 256, 0, stream>>>(fc2_w, fc2T, NDIN, NC);
  build_cfsf_kernel<<<320, NL, 0, stream>>>(ct, st, Cfb, Sfb);
  build_ci_kernel<<<NL, 640, 0, stream>>>(ct, st, Cib);
  // xdbl_t = (xcb @ w_xproj)^T f32 [112][2304]
  gemm_mfma<<<dim3(2, 36), 256, 0, stream>>>(xcb, wxpT, xdbl_t, NTOK, NTOK, NXD, NDIN,
                                             0, 2, nullptr, nullptr, nullptr, 0);
  // scan with fused delta
  scan6_kernel<<<NB * NDIN, 256, 0, stream>>>(xc_t, xdbl_t, w_dt, b_dt, A_log, Dp, res_t, yf_t);
  // yfb = bf16(yf^T)  [2304][512]
  packT_kernel<<<dim3(36, 8), 256, 0, stream>>>(yf_t, yfb, NDIN, NTOK);
  // x2 = x + yfb @ w_out
  gemm_mfma<<<dim3(4, 36), 256, 0, stream>>>(yfb, woT, x2, NC, NTOK, NC, NDIN,
                                             2, 0, nullptr, nullptr, x, NC);
  // PK pad zero (yf_t dead)
  zero_pkpad_kernel<<<256, 256, 0, stream>>>(PK);
  // h2b = bf16(LN(x2))
  ln_kernel<<<NTOK, 64, 0, stream>>>(x2, h2b, ln2_g, ln2_b, nullptr, nullptr, 0);
  // ftb = bf16(relu(h2b@fc1 * s + b))^T [512][2304]
  gemm_mfma<<<dim3(8, 36), 256, 0, stream>>>(h2b, fc1T, ftb, NTOK, NTOK, NDIN, NC,
                                             3, 6, bn1_s, bn1_b, nullptr, 0);
  // rfft / mix / irfft on MFMA
  dftf_mfma_kernel<<<dim3(8, 5, NB), 256, 0, stream>>>(Cfb, Sfb, ftb, RFb, IFb);
  mix_mfma_kernel<<<dim3(19, 8), 256, 0, stream>>>(RFb, IFb, Wrt, Wit, rb, ib, PK);
  idft_mfma_kernel<<<dim3(8, 9, NB), 256, 0, stream>>>(Cib, PK, ffb);
  // out = x2 + ffb @ fc2 * s + b
  gemm_mfma<<<dim3(4, 36), 256, 0, stream>>>(ffb, fc2T, out, NC, NTOK, NC, NDIN,
                                             4, 0, bn2_s, bn2_b, x2, NC);
}

// Round 10
// 239.417 us; speedup vs baseline: 4.1144x; 1.0347x over previous
//
#include <hip/hip_runtime.h>
#include <math.h>

#define NB 4
#define NL 576
#define NC 256
#define NTOK (NB*NL)      // 2304
#define NDIN 512
#define NXD 112
#define NDTR 16
#define NDST 48
#define NFREQ 289
#define NWIN 1024
#define NMROW (NB*NFREQ)  // 1156
#define NKPK 608          // packed K for irfft (2*289 -> 608)

// ---- workspace layout (f32-equivalent offsets), lifetime-reused ----
#define OFF_HB    0u         // hb bf16 [2304][256] -> h2b later
#define OFF_XR    294912u    // xr f32 [2304][1024]; dead after convT -> subdivided:
#define OFF_CF    (OFF_XR + 0u)        // Cfb bf16 320x576   (92160)
#define OFF_SF    (OFF_XR + 92160u)    // Sfb bf16 320x576   (92160)
#define OFF_CI    (OFF_XR + 184320u)   // Cib bf16 576x608   (175104)
#define OFF_YFB   (OFF_XR + 359424u)   // yfb bf16 [2304][512] (589824)
#define OFF_FFB   (OFF_XR + 949248u)   // ffb bf16 [2304][512] (589824)
#define OFF_WXPT  (OFF_XR + 1539072u)  // w_xprojT bf16 [112][512]
#define OFF_WOT   (OFF_XR + 1567744u)  // w_outT bf16 [256][512]
#define OFF_FC1T  (OFF_XR + 1633280u)  // fc1T bf16 [512][256]
#define OFF_FC2T  (OFF_XR + 1698816u)  // fc2T bf16 [256][512]
#define OFF_XCT   2654208u   // xc_t f32 [512][2304]
#define OFF_REST  3833856u   // res_t f32 [512][2304]
#define OFF_XCB   5013504u   // xcb bf16 [2304][512]
#define OFF_XDBL  5603328u   // xdbl_t f32 [112][2304] (token-PERMUTED within batch)
#define OFF_YFT   5861376u   // yf_t f32 [512][2304] -> PK bf16 [512*4][608]
#define OFF_X2    7041024u   // x2 f32 [2304][256]
#define OFF_FTB   7630848u   // ftb bf16 [512][2304]
#define OFF_RF    8220672u   // RFb bf16 [1156][512]
#define OFF_IF    8516608u   // IFb bf16
#define OFF_WRT   8812544u   // Wrt bf16 [512][512]
#define OFF_WIT   8943616u   // Wit bf16
#define OFF_WINT  9074688u   // w_inT bf16 [1024][256]
#define OFF_CT    9205760u
#define OFF_ST    9206336u

typedef __attribute__((ext_vector_type(8))) short bf16x8;
typedef __attribute__((ext_vector_type(4))) float f32x4;
typedef __attribute__((ext_vector_type(4))) int   i32x4;

__device__ __forceinline__ float wave_sum(float v) {
#pragma unroll
  for (int o = 32; o > 0; o >>= 1) v += __shfl_xor(v, o);
  return v;
}

__device__ __forceinline__ unsigned short f2bf(float f) {
  unsigned int u = __float_as_uint(f);
  unsigned int r = (u + 0x7fffu + ((u >> 16) & 1u)) >> 16;  // RNE
  return (unsigned short)r;
}

// 64-lane inclusive prefix sum via DPP + readlane broadcasts.
__device__ __forceinline__ float wave_iscan(float x, int lane) {
  x += __int_as_float(__builtin_amdgcn_update_dpp(0, __float_as_int(x), 0x111, 0xf, 0xf, true));
  x += __int_as_float(__builtin_amdgcn_update_dpp(0, __float_as_int(x), 0x112, 0xf, 0xf, true));
  x += __int_as_float(__builtin_amdgcn_update_dpp(0, __float_as_int(x), 0x114, 0xf, 0xf, true));
  x += __int_as_float(__builtin_amdgcn_update_dpp(0, __float_as_int(x), 0x118, 0xf, 0xf, true));
  int xi = __float_as_int(x);
  float s15 = __int_as_float(__builtin_amdgcn_readlane(xi, 15));
  float s31 = __int_as_float(__builtin_amdgcn_readlane(xi, 31));
  float s47 = __int_as_float(__builtin_amdgcn_readlane(xi, 47));
  float off = 0.f;
  if (lane >= 16) off += s15;
  if (lane >= 32) off += s31;
  if (lane >= 48) off += s47;
  return x + off;
}

__global__ void trig_kernel(float* ct, float* st) {
  int i = threadIdx.x;
  if (i < NL) {
    double a = (6.283185307179586476925286766559 * (double)i) / (double)NL;
    ct[i] = (float)cos(a);
    st[i] = (float)sin(a);
  }
}

__global__ void build_cfsf_kernel(const float* __restrict__ ct, const float* __restrict__ st,
                                  unsigned short* __restrict__ Cf, unsigned short* __restrict__ Sf) {
  int m = blockIdx.x, l = threadIdx.x;   // 320 x 576
  float c = 0.f, s = 0.f;
  if (m < NFREQ) {
    int idx = (m * l) % NL;
    c = ct[idx] * (1.f / 24.f);
    s = -st[idx] * (1.f / 24.f);
  }
  Cf[(size_t)m * NL + l] = f2bf(c);
  Sf[(size_t)m * NL + l] = f2bf(s);
}

__global__ void build_ci_kernel(const float* __restrict__ ct, const float* __restrict__ st,
                                unsigned short* __restrict__ Ci) {
  int l = blockIdx.x, k = threadIdx.x;   // 576 x 640 (guard 608)
  if (k >= NKPK) return;
  float v = 0.f;
  if (k < NFREQ) {
    float w = (k == 0 || k == NFREQ - 1) ? 1.f : 2.f;
    v = w * ct[(k * l) % NL] * (1.f / 24.f);
  } else if (k < 2 * NFREQ) {
    int kk = k - NFREQ;
    float w = (kk == 0 || kk == NFREQ - 1) ? 1.f : 2.f;
    v = -w * st[(kk * l) % NL] * (1.f / 24.f);
  }
  Ci[(size_t)l * NKPK + k] = f2bf(v);
}

__global__ void zero_pkpad_kernel(unsigned short* __restrict__ PK) {
  int i = blockIdx.x * blockDim.x + threadIdx.x;
  int row = i >> 5, c = i & 31;
  if (row < NDIN * NB && c < NKPK - 2 * NFREQ)
    PK[(size_t)row * NKPK + 2 * NFREQ + c] = 0;
}

// one wave per token row; bf16 output. dbl=1: two chained LNs.
__global__ void ln_kernel(const float* __restrict__ in, unsigned short* __restrict__ out,
                          const float* __restrict__ g1, const float* __restrict__ b1,
                          const float* __restrict__ g2, const float* __restrict__ b2,
                          int dbl) {
  int row = blockIdx.x, lane = threadIdx.x;
  const float* p = in + (size_t)row * NC;
  float v[4];
#pragma unroll
  for (int j = 0; j < 4; ++j) v[j] = p[lane + j * 64];
  float s = wave_sum(v[0] + v[1] + v[2] + v[3]);
  float m = s * (1.f / NC);
  float q = 0.f;
#pragma unroll
  for (int j = 0; j < 4; ++j) { float d = v[j] - m; q += d * d; }
  q = wave_sum(q);
  float rs = 1.f / sqrtf(q * (1.f / NC) + 1e-3f);
#pragma unroll
  for (int j = 0; j < 4; ++j) {
    int c = lane + j * 64;
    v[j] = (v[j] - m) * rs * g1[c] + b1[c];
  }
  if (dbl) {
    s = wave_sum(v[0] + v[1] + v[2] + v[3]);
    m = s * (1.f / NC);
    q = 0.f;
#pragma unroll
    for (int j = 0; j < 4; ++j) { float d = v[j] - m; q += d * d; }
    q = wave_sum(q);
    rs = 1.f / sqrtf(q * (1.f / NC) + 1e-3f);
#pragma unroll
    for (int j = 0; j < 4; ++j) {
      int c = lane + j * 64;
      v[j] = (v[j] - m) * rs * g2[c] + b2[c];
    }
  }
  unsigned short* o = out + (size_t)row * NC;
#pragma unroll
  for (int j = 0; j < 4; ++j) o[lane + j * 64] = f2bf(v[j]);
}

// transpose + bf16 pack: dst[c][r] = bf16(src[r][c]); guards for any R,C.
__global__ __launch_bounds__(256) void packT_kernel(
    const float* __restrict__ src, unsigned short* __restrict__ dst, int R, int C) {
  __shared__ float tile[64][65];
  int c0 = blockIdx.x * 64, r0 = blockIdx.y * 64;
  int tid = threadIdx.x;
  for (int u = tid; u < 4096; u += 256) {
    int r = u >> 6, c = u & 63;
    float v = 0.f;
    if (r0 + r < R && c0 + c < C) v = src[(size_t)(r0 + r) * C + c0 + c];
    tile[r][c] = v;
  }
  __syncthreads();
  for (int u = tid; u < 4096; u += 256) {
    int nr = u >> 6, nc = u & 63;
    if (c0 + nr < C && r0 + nc < R)
      dst[(size_t)(c0 + nr) * R + r0 + nc] = f2bf(tile[nc][nr]);
  }
}

// generic MFMA GEMM: C = A[M][K]bf16 @ B[N][K]bf16^T (f32 accum), fused epilogues.
// mode 0: store; 2: v+add; 3: relu(v*scl+bias); 4: v*scl+bias+add
// flags bit1: transposed store C[n][m]; bit2: bf16 store;
// flags bit3: scan-permute token index within 576-batch on transposed store.
__global__ __launch_bounds__(256) void gemm_mfma(
    const unsigned short* __restrict__ A, const unsigned short* __restrict__ B,
    void* __restrict__ C, int ldc, int M, int N, int K, int mode, int flags,
    const float* __restrict__ scl, const float* __restrict__ bias,
    const float* __restrict__ add, int ldadd) {
  __shared__ unsigned short As[64][40], Bs[64][40];
  int tid = threadIdx.x, lane = tid & 63, wv = tid >> 6;
  int n0 = blockIdx.x * 64, m0 = blockIdx.y * 64;
  int sm = tid >> 2, part = tid & 3;
  f32x4 acc[4] = {};
  for (int k0 = 0; k0 < K; k0 += 32) {
    *(bf16x8*)&As[sm][part * 8] = *(const bf16x8*)(A + (size_t)(m0 + sm) * K + k0 + part * 8);
    bf16x8 bv = {};
    if (n0 + sm < N) bv = *(const bf16x8*)(B + (size_t)(n0 + sm) * K + k0 + part * 8);
    *(bf16x8*)&Bs[sm][part * 8] = bv;
    __syncthreads();
    int am = wv * 16 + (lane & 15), koff = (lane >> 4) * 8;
    bf16x8 a = *(bf16x8*)&As[am][koff];
#pragma unroll
    for (int t = 0; t < 4; ++t) {
      bf16x8 b = *(bf16x8*)&Bs[t * 16 + (lane & 15)][koff];
      acc[t] = __builtin_amdgcn_mfma_f32_16x16x32_bf16(a, b, acc[t], 0, 0, 0);
    }
    __syncthreads();
  }
#pragma unroll
  for (int t = 0; t < 4; ++t) {
    int gn = n0 + t * 16 + (lane & 15);
    if (gn >= N) continue;
    float sv = scl ? scl[gn] : 0.f, bvv = bias ? bias[gn] : 0.f;
#pragma unroll
    for (int r = 0; r < 4; ++r) {
      int gm = m0 + wv * 16 + (lane >> 4) * 4 + r;
      float v = acc[t][r];
      if (mode == 2) v += add[(size_t)gm * ldadd + gn];
      else if (mode == 3) v = fmaxf(v * sv + bvv, 0.f);
      else if (mode == 4) v = v * sv + bvv + add[(size_t)gm * ldadd + gn];
      int gms = gm;
      if (flags & 8) {
        int bq = gm / NL, tt = gm - bq * NL;
        int t9 = tt / 9;
        gms = bq * NL + (tt - t9 * 9) * 64 + t9;
      }
      size_t o = (flags & 2) ? (size_t)gn * ldc + gms : (size_t)gm * ldc + gn;
      if (flags & 4) ((unsigned short*)C)[o] = f2bf(v);
      else ((float*)C)[o] = v;
    }
  }
}

// Fused causal depthwise conv(4)+silu: xc_t f32 (d-major) + xcb bf16 (tok-major);
// z=1: res transpose -> res_t.
__global__ __launch_bounds__(256) void convT_kernel(
    const float* __restrict__ xr, const float* __restrict__ cw,
    const float* __restrict__ cb, float* __restrict__ xc_t,
    float* __restrict__ res_t, unsigned short* __restrict__ xcb) {
  __shared__ float tile[67][65];
  int d0 = blockIdx.x * 64;
  int rt = blockIdx.y;
  int b = rt / 9, l0 = (rt % 9) * 64;
  int tid = threadIdx.x;
  int li = tid & 63, dj0 = tid >> 6;
  if (blockIdx.z == 0) {
    for (int u = tid; u < 67 * 16; u += 256) {
      int r = u >> 4, c4 = (u & 15) * 4;
      int l = l0 - 3 + r;
      float4 v = make_float4(0.f, 0.f, 0.f, 0.f);
      if (l >= 0) v = *reinterpret_cast<const float4*>(xr + (size_t)(b * NL + l) * NWIN + d0 + c4);
      tile[r][c4 + 0] = v.x; tile[r][c4 + 1] = v.y;
      tile[r][c4 + 2] = v.z; tile[r][c4 + 3] = v.w;
    }
    __syncthreads();
    float outv[16];
#pragma unroll
    for (int k2 = 0; k2 < 16; ++k2) {
      int dj = dj0 + k2 * 4;
      int d = d0 + dj;
      float acc = cb[d];
#pragma unroll
      for (int k = 0; k < 4; ++k) acc += cw[k * NDIN + d] * tile[li + k][dj];
      acc = acc / (1.f + __expf(-acc));
      outv[k2] = acc;
      xc_t[(size_t)d * NTOK + b * NL + l0 + li] = acc;
    }
    __syncthreads();
#pragma unroll
    for (int k2 = 0; k2 < 16; ++k2) tile[li][dj0 + k2 * 4] = outv[k2];
    __syncthreads();
    for (int u = tid; u < 1024; u += 256) {
      int r = u >> 4, c4 = (u & 15) * 4;
      unsigned long long pk =
          (unsigned long long)f2bf(tile[r][c4 + 0]) |
          ((unsigned long long)f2bf(tile[r][c4 + 1]) << 16) |
          ((unsigned long long)f2bf(tile[r][c4 + 2]) << 32) |
          ((unsigned long long)f2bf(tile[r][c4 + 3]) << 48);
      *(unsigned long long*)(xcb + (size_t)(b * NL + l0 + r) * NDIN + d0 + c4) = pk;
    }
  } else {
    for (int u = tid; u < 64 * 16; u += 256) {
      int r = u >> 4, c4 = (u & 15) * 4;
      float4 v = *reinterpret_cast<const float4*>(xr + (size_t)(b * NL + l0 + r) * NWIN + NDIN + d0 + c4);
      tile[r][c4 + 0] = v.x; tile[r][c4 + 1] = v.y;
      tile[r][c4 + 2] = v.z; tile[r][c4 + 3] = v.w;
    }
    __syncthreads();
    for (int dj = dj0; dj < 64; dj += 4)
      res_t[(size_t)(d0 + dj) * NTOK + b * NL + l0 + li] = tile[li][dj];
  }
}

// selective scan with fused delta; xdbl_t is token-PERMUTED so that the j-th
// element of lane's 9-consecutive block sits at [j*64+lane] -> coalesced loads.
__global__ __launch_bounds__(256) void scan6_kernel(
    const float* __restrict__ xc_t, const float* __restrict__ xdbl_t,
    const float* __restrict__ w_dt, const float* __restrict__ b_dt,
    const float* __restrict__ A_log, const float* __restrict__ Dp,
    const float* __restrict__ res_t, float* __restrict__ yf_t) {
  __shared__ float yl[4][NL];
  __shared__ float u_lds[NL];
  int b = blockIdx.x >> 9, d = blockIdx.x & 511;
  int tid = threadIdx.x, lane = tid & 63, wv = tid >> 6;
  int bbase = b * NL;
  const float* urow = xc_t + (size_t)d * NTOK;

  // stage u row coalesced into LDS
  for (int e = tid; e < NL; e += 256) u_lds[e] = urow[bbase + e];

  // fused delta = softplus(dt @ w_dt[:,d] + b_dt[d]) ; permuted coalesced loads
  float wdt[16];
#pragma unroll
  for (int r = 0; r < 16; ++r) wdt[r] = w_dt[r * NDIN + d];
  float bd = b_dt[d];
  float dl[9];
#pragma unroll
  for (int j = 0; j < 9; ++j) dl[j] = bd;
#pragma unroll
  for (int r = 0; r < 16; ++r) {
    const float* dtp = xdbl_t + (size_t)r * NTOK + bbase;
#pragma unroll
    for (int j = 0; j < 9; ++j) dl[j] += dtp[j * 64 + lane] * wdt[r];
  }
#pragma unroll
  for (int j = 0; j < 9; ++j) {
    float v = dl[j];
    dl[j] = fmaxf(v, 0.f) + __logf(1.f + __expf(-fabsf(v)));
  }
  __syncthreads();

  float ul[9];
#pragma unroll
  for (int j = 0; j < 9; ++j) ul[j] = u_lds[lane * 9 + j];
  float pre[9];
  float s = 0.f;
#pragma unroll
  for (int j = 0; j < 9; ++j) { s += dl[j]; pre[j] = s; }
  float isc = wave_iscan(s, lane);
  float total = __int_as_float(__builtin_amdgcn_readlane(__float_as_int(isc), 63));
  float excl = isc - s;
  float Ts[9], dlul[9];
#pragma unroll
  for (int j = 0; j < 9; ++j) {
    Ts[j] = total - excl - pre[j];
    dlul[j] = dl[j] * ul[j];
  }

  const float* Arow = A_log + (size_t)d * NDST + wv * 12;
  float y[9] = {};
  for (int jj = 0; jj < 12; ++jj) {
    float An = -__expf(Arow[jj]);
    const float* bbp = xdbl_t + (size_t)(NDTR + wv * 12 + jj) * NTOK + bbase;
    const float* ccp = xdbl_t + (size_t)(NDTR + NDST + wv * 12 + jj) * NTOK + bbase;
    float e[9], w[9];
    float ps = 0.f;
#pragma unroll
    for (int j = 0; j < 9; ++j) {
      e[j] = __expf(An * Ts[j]);
      ps += dlul[j] * bbp[j * 64 + lane] * e[j];
      w[j] = ps;
    }
    float wi = wave_iscan(ps, lane);
    float wexcl = wi - ps;
#pragma unroll
    for (int j = 0; j < 9; ++j)
      y[j] += __fdividef(w[j] + wexcl, e[j] + 1e-12f) * ccp[j * 64 + lane];
  }
#pragma unroll
  for (int j = 0; j < 9; ++j) yl[wv][lane * 9 + j] = y[j];
  __syncthreads();

  const float* rrow = res_t + (size_t)d * NTOK;
  float* orow = yf_t + (size_t)d * NTOK;
  float Dd = Dp[d];
  for (int e0 = tid; e0 < NL; e0 += 256) {
    float yy = yl[0][e0] + yl[1][e0] + yl[2][e0] + yl[3][e0];
    float uu = u_lds[e0];
    float rr = rrow[bbase + e0];
    float yv = yy + uu * Dd;
    float sr = rr / (1.f + __expf(-rr));
    orow[bbase + e0] = yv * sr;
  }
}

// forward rfft on matrix cores: RF = Cf@f, IF = Sf@f.
__global__ __launch_bounds__(256) void dftf_mfma_kernel(
    const unsigned short* __restrict__ Cf, const unsigned short* __restrict__ Sf,
    const unsigned short* __restrict__ ft,
    unsigned short* __restrict__ RFb, unsigned short* __restrict__ IFb) {
  __shared__ unsigned short AsC[64][40], AsS[64][40], Bs[64][40];
  int tid = threadIdx.x;
  int lane = tid & 63, wv = tid >> 6;
  int n0 = blockIdx.x * 64, m0 = blockIdx.y * 64, b = blockIdx.z;
  int sm = tid >> 2, part = tid & 3;
  f32x4 accR[4] = {}, accI[4] = {};
  for (int k0 = 0; k0 < NL; k0 += 32) {
    *(bf16x8*)&AsC[sm][part * 8] = *(const bf16x8*)(Cf + (size_t)(m0 + sm) * NL + k0 + part * 8);
    *(bf16x8*)&AsS[sm][part * 8] = *(const bf16x8*)(Sf + (size_t)(m0 + sm) * NL + k0 + part * 8);
    *(bf16x8*)&Bs[sm][part * 8]  = *(const bf16x8*)(ft + (size_t)(n0 + sm) * NTOK + b * NL + k0 + part * 8);
    __syncthreads();
    int am = wv * 16 + (lane & 15);
    int koff = (lane >> 4) * 8;
    bf16x8 ac = *(bf16x8*)&AsC[am][koff];
    bf16x8 as = *(bf16x8*)&AsS[am][koff];
#pragma unroll
    for (int t = 0; t < 4; ++t) {
      bf16x8 bv = *(bf16x8*)&Bs[t * 16 + (lane & 15)][koff];
      accR[t] = __builtin_amdgcn_mfma_f32_16x16x32_bf16(ac, bv, accR[t], 0, 0, 0);
      accI[t] = __builtin_amdgcn_mfma_f32_16x16x32_bf16(as, bv, accI[t], 0, 0, 0);
    }
    __syncthreads();
  }
#pragma unroll
  for (int t = 0; t < 4; ++t) {
    int gn = n0 + t * 16 + (lane & 15);
#pragma unroll
    for (int r = 0; r < 4; ++r) {
      int gm = m0 + wv * 16 + (lane >> 4) * 4 + r;
      if (gm < NFREQ) {
        size_t o = ((size_t)(b * NFREQ + gm)) * NDIN + gn;
        RFb[o] = f2bf(accR[t][r]);
        IFb[o] = f2bf(accI[t][r]);
      }
    }
  }
}

// complex mix -> packed irfft B-matrix PK (bf16).
__global__ __launch_bounds__(256) void mix_mfma_kernel(
    const unsigned short* __restrict__ RFb, const unsigned short* __restrict__ IFb,
    const unsigned short* __restrict__ Wrt, const unsigned short* __restrict__ Wit,
    const float* __restrict__ rb, const float* __restrict__ ib,
    unsigned short* __restrict__ PK) {
  __shared__ unsigned short AsR[64][40], AsI[64][40], BsR[64][40], BsI[64][40];
  int tid = threadIdx.x;
  int lane = tid & 63, wv = tid >> 6;
  int n0 = blockIdx.x * 64, m0 = blockIdx.y * 64;
  int sm = tid >> 2, part = tid & 3;
  f32x4 accR[4] = {}, accI[4] = {};
  for (int k0 = 0; k0 < NDIN; k0 += 32) {
    *(bf16x8*)&AsR[sm][part * 8] = *(const bf16x8*)(Wrt + (size_t)(m0 + sm) * NDIN + k0 + part * 8);
    *(bf16x8*)&AsI[sm][part * 8] = *(const bf16x8*)(Wit + (size_t)(m0 + sm) * NDIN + k0 + part * 8);
    bf16x8 brf = {}, bif = {};
    if (n0 + sm < NMROW) {
      brf = *(const bf16x8*)(RFb + (size_t)(n0 + sm) * NDIN + k0 + part * 8);
      bif = *(const bf16x8*)(IFb + (size_t)(n0 + sm) * NDIN + k0 + part * 8);
    }
    *(bf16x8*)&BsR[sm][part * 8] = brf;
    *(bf16x8*)&BsI[sm][part * 8] = bif;
    __syncthreads();
    int am = wv * 16 + (lane & 15);
    int koff = (lane >> 4) * 8;
    bf16x8 a_wr = *(bf16x8*)&AsR[am][koff];
    bf16x8 a_wi = *(bf16x8*)&AsI[am][koff];
    union { bf16x8 h; i32x4 i; } un;
    un.h = a_wi;
    un.i = un.i ^ (int)0x80008000;
    bf16x8 a_win = un.h;
#pragma unroll
    for (int t = 0; t < 4; ++t) {
      bf16x8 b_rf = *(bf16x8*)&BsR[t * 16 + (lane & 15)][koff];
      bf16x8 b_if = *(bf16x8*)&BsI[t * 16 + (lane & 15)][koff];
      accR[t] = __builtin_amdgcn_mfma_f32_16x16x32_bf16(a_wr, b_rf, accR[t], 0, 0, 0);
      accR[t] = __builtin_amdgcn_mfma_f32_16x16x32_bf16(a_win, b_if, accR[t], 0, 0, 0);
      accI[t] = __builtin_amdgcn_mfma_f32_16x16x32_bf16(a_wr, b_if, accI[t], 0, 0, 0);
      accI[t] = __builtin_amdgcn_mfma_f32_16x16x32_bf16(a_wi, b_rf, accI[t], 0, 0, 0);
    }
    __syncthreads();
  }
#pragma unroll
  for (int t = 0; t < 4; ++t) {
    int gn = n0 + t * 16 + (lane & 15);   // freq global
    int bb = (gn >= 3 * NFREQ) ? 3 : (gn >= 2 * NFREQ) ? 2 : (gn >= NFREQ) ? 1 : 0;
    int kf = gn - bb * NFREQ;
    bool ok = gn < NMROW;
#pragma unroll
    for (int r = 0; r < 4; ++r) {
      int gm = m0 + wv * 16 + (lane >> 4) * 4 + r;   // c_out
      if (ok) {
        float vr = fmaxf(accR[t][r] + rb[gm], 0.f);
        float vi = fmaxf(accI[t][r] + ib[gm], 0.f);
        size_t base = ((size_t)gm * NB + bb) * NKPK;
        PK[base + kf] = f2bf(vr);
        PK[base + NFREQ + kf] = f2bf(vi);
      }
    }
  }
}

// irfft on matrix cores -> ffb bf16 [2304][512]
__global__ __launch_bounds__(256) void idft_mfma_kernel(
    const unsigned short* __restrict__ Ci, const unsigned short* __restrict__ PK,
    unsigned short* __restrict__ ffb) {
  __shared__ unsigned short As[64][40], Bs[64][40];
  int tid = threadIdx.x;
  int lane = tid & 63, wv = tid >> 6;
  int n0 = blockIdx.x * 64, m0 = blockIdx.y * 64, b = blockIdx.z;
  int sm = tid >> 2, part = tid & 3;
  f32x4 acc[4] = {};
  for (int k0 = 0; k0 < NKPK; k0 += 32) {
    *(bf16x8*)&As[sm][part * 8] = *(const bf16x8*)(Ci + (size_t)(m0 + sm) * NKPK + k0 + part * 8);
    *(bf16x8*)&Bs[sm][part * 8] = *(const bf16x8*)(PK + ((size_t)(n0 + sm) * NB + b) * NKPK + k0 + part * 8);
    __syncthreads();
    int am = wv * 16 + (lane & 15);
    int koff = (lane >> 4) * 8;
    bf16x8 av = *(bf16x8*)&As[am][koff];
#pragma unroll
    for (int t = 0; t < 4; ++t) {
      bf16x8 bv = *(bf16x8*)&Bs[t * 16 + (lane & 15)][koff];
      acc[t] = __builtin_amdgcn_mfma_f32_16x16x32_bf16(av, bv, acc[t], 0, 0, 0);
    }
    __syncthreads();
  }
#pragma unroll
  for (int t = 0; t < 4; ++t) {
    int gn = n0 + t * 16 + (lane & 15);     // d
#pragma unroll
    for (int r = 0; r < 4; ++r) {
      int gm = m0 + wv * 16 + (lane >> 4) * 4 + r;   // l
      ffb[((size_t)(b * NL + gm)) * NDIN + gn] = f2bf(acc[t][r]);
    }
  }
}

extern "C" void kernel_launch(void* const* d_in, const int* in_sizes, int n_in,
                              void* d_out, int out_size, void* d_ws, size_t ws_size,
                              hipStream_t stream) {
  const float* x      = (const float*)d_in[0];
  const float* ln1_g  = (const float*)d_in[1];
  const float* ln1_b  = (const float*)d_in[2];
  const float* mln_g  = (const float*)d_in[3];
  const float* mln_b  = (const float*)d_in[4];
  const float* w_in   = (const float*)d_in[5];
  const float* conv_w = (const float*)d_in[6];
  const float* conv_b = (const float*)d_in[7];
  const float* w_xprj = (const float*)d_in[8];
  const float* w_dt   = (const float*)d_in[9];
  const float* b_dt   = (const float*)d_in[10];
  const float* A_log  = (const float*)d_in[11];
  const float* Dp     = (const float*)d_in[12];
  const float* w_out  = (const float*)d_in[13];
  const float* ln2_g  = (const float*)d_in[14];
  const float* ln2_b  = (const float*)d_in[15];
  const float* fc1_w  = (const float*)d_in[16];
  const float* bn1_s  = (const float*)d_in[17];
  const float* bn1_b  = (const float*)d_in[18];
  const float* Wr     = (const float*)d_in[19];
  const float* Wi     = (const float*)d_in[20];
  const float* rb     = (const float*)d_in[21];
  const float* ib     = (const float*)d_in[22];
  const float* fc2_w  = (const float*)d_in[23];
  const float* bn2_s  = (const float*)d_in[24];
  const float* bn2_b  = (const float*)d_in[25];

  float* ws = (float*)d_ws;
  unsigned short* hb   = (unsigned short*)(ws + OFF_HB);   // then h2b
  float* xr     = ws + OFF_XR;
  float* xc_t   = ws + OFF_XCT;
  float* res_t  = ws + OFF_REST;
  float* xdbl_t = ws + OFF_XDBL;
  float* yf_t   = ws + OFF_YFT;
  float* x2     = ws + OFF_X2;
  float* ct     = ws + OFF_CT;
  float* st     = ws + OFF_ST;
  unsigned short* xcb  = (unsigned short*)(ws + OFF_XCB);
  unsigned short* Cfb  = (unsigned short*)(ws + OFF_CF);
  unsigned short* Sfb  = (unsigned short*)(ws + OFF_SF);
  unsigned short* Cib  = (unsigned short*)(ws + OFF_CI);
  unsigned short* yfb  = (unsigned short*)(ws + OFF_YFB);
  unsigned short* ffb  = (unsigned short*)(ws + OFF_FFB);
  unsigned short* wxpT = (unsigned short*)(ws + OFF_WXPT);
  unsigned short* woT  = (unsigned short*)(ws + OFF_WOT);
  unsigned short* fc1T = (unsigned short*)(ws + OFF_FC1T);
  unsigned short* fc2T = (unsigned short*)(ws + OFF_FC2T);
  unsigned short* winT = (unsigned short*)(ws + OFF_WINT);
  unsigned short* PK   = (unsigned short*)(ws + OFF_YFT);
  unsigned short* ftb  = (unsigned short*)(ws + OFF_FTB);
  unsigned short* Wrt  = (unsigned short*)(ws + OFF_WRT);
  unsigned short* Wit  = (unsigned short*)(ws + OFF_WIT);
  unsigned short* RFb  = (unsigned short*)(ws + OFF_RF);
  unsigned short* IFb  = (unsigned short*)(ws + OFF_IF);
  unsigned short* h2b  = hb;
  float* out = (float*)d_out;

  trig_kernel<<<1, NL, 0, stream>>>(ct, st);
  // hb = bf16(LN(LN(x)))
  ln_kernel<<<NTOK, 64, 0, stream>>>(x, hb, ln1_g, ln1_b, mln_g, mln_b, 1);
  // weight packs independent of xr lifetime
  packT_kernel<<<dim3(16, 4), 256, 0, stream>>>(w_in, winT, NC, NWIN);
  packT_kernel<<<dim3(8, 8), 256, 0, stream>>>(Wr, Wrt, NDIN, NDIN);
  packT_kernel<<<dim3(8, 8), 256, 0, stream>>>(Wi, Wit, NDIN, NDIN);
  // xr = hb @ w_in (f32 out)
  gemm_mfma<<<dim3(16, 36), 256, 0, stream>>>(hb, winT, xr, NWIN, NTOK, NWIN, NC,
                                              0, 0, nullptr, nullptr, nullptr, 0);
  // xc_t f32 + xcb bf16 + res_t
  convT_kernel<<<dim3(8, 36, 2), 256, 0, stream>>>(xr, conv_w, conv_b, xc_t, res_t, xcb);
  // xr dead: packs + trig matrices into its region
  packT_kernel<<<dim3(2, 8), 256, 0, stream>>>(w_xprj, wxpT, NDIN, NXD);
  packT_kernel<<<dim3(4, 8), 256, 0, stream>>>(w_out, woT, NDIN, NC);
  packT_kernel<<<dim3(8, 4), 256, 0, stream>>>(fc1_w, fc1T, NC, NDIN);
  packT_kernel<<<dim3(4, 8), 256, 0, stream>>>(fc2_w, fc2T, NDIN, NC);
  build_cfsf_kernel<<<320, NL, 0, stream>>>(ct, st, Cfb, Sfb);
  build_ci_kernel<<<NL, 640, 0, stream>>>(ct, st, Cib);
  // xdbl_t = (xcb @ w_xproj)^T f32 [112][2304], token-permuted for scan coalescing
  gemm_mfma<<<dim3(2, 36), 256, 0, stream>>>(xcb, wxpT, xdbl_t, NTOK, NTOK, NXD, NDIN,
                                             0, 10, nullptr, nullptr, nullptr, 0);
  // scan with fused delta (coalesced permuted reads)
  scan6_kernel<<<NB * NDIN, 256, 0, stream>>>(xc_t, xdbl_t, w_dt, b_dt, A_log, Dp, res_t, yf_t);
  // yfb = bf16(yf^T)  [2304][512]
  packT_kernel<<<dim3(36, 8), 256, 0, stream>>>(yf_t, yfb, NDIN, NTOK);
  // x2 = x + yfb @ w_out
  gemm_mfma<<<dim3(4, 36), 256, 0, stream>>>(yfb, woT, x2, NC, NTOK, NC, NDIN,
                                             2, 0, nullptr, nullptr, x, NC);
  // PK pad zero (yf_t dead)
  zero_pkpad_kernel<<<256, 256, 0, stream>>>(PK);
  // h2b = bf16(LN(x2))
  ln_kernel<<<NTOK, 64, 0, stream>>>(x2, h2b, ln2_g, ln2_b, nullptr, nullptr, 0);
  // ftb = bf16(relu(h2b@fc1 * s + b))^T [512][2304]
  gemm_mfma<<<dim3(8, 36), 256, 0, stream>>>(h2b, fc1T, ftb, NTOK, NTOK, NDIN, NC,
                                             3, 6, bn1_s, bn1_b, nullptr, 0);
  // rfft / mix / irfft on MFMA
  dftf_mfma_kernel<<<dim3(8, 5, NB), 256, 0, stream>>>(Cfb, Sfb, ftb, RFb, IFb);
  mix_mfma_kernel<<<dim3(19, 8), 256, 0, stream>>>(RFb, IFb, Wrt, Wit, rb, ib, PK);
  idft_mfma_kernel<<<dim3(8, 9, NB), 256, 0, stream>>>(Cib, PK, ffb);
  // out = x2 + ffb @ fc2 * s + b
  gemm_mfma<<<dim3(4, 36), 256, 0, stream>>>(ffb, fc2T, out, NC, NTOK, NC, NDIN,
                                             4, 0, bn2_s, bn2_b, x2, NC);
}

// Round 11
// 185.845 us; speedup vs baseline: 5.3004x; 1.2883x over previous
//
#include <hip/hip_runtime.h>
#include <math.h>

#define NB 4
#define NL 576
#define NC 256
#define NTOK (NB*NL)      // 2304
#define NDIN 512
#define NXD 112
#define NDTR 16
#define NDST 48
#define NFREQ 289
#define NWIN 1024
#define NMROW (NB*NFREQ)  // 1156
#define NKPK 608          // packed K for irfft (2*289 -> 608)

// ---- workspace layout (f32-equivalent offsets), no-alias except noted ----
#define OFF_HB    0u          // hb bf16 [2304][256] (reused as h2b)
#define OFF_XRF   147456u     // xr f32 [2304][1024]
#define OFF_XCT   2506752u    // xc_t f32 [512][2304]
#define OFF_REST  3686400u    // res_t f32 [512][2304]
#define OFF_XCB   4866048u    // xcb bf16 [2304][512]
#define OFF_XDBL  5455872u    // xdbl bf16 [112][2304] (token-permuted)
#define OFF_YFT   5584896u    // yf_t f32 [512][2304] -> PK bf16 [2048][608] later
#define OFF_X2    6764544u    // x2 f32 [2304][256]
#define OFF_FTB   7354368u    // ftb bf16 [512][2304]
#define OFF_RF    7944192u    // RFb bf16 [1156][512]
#define OFF_IF    8240128u    // IFb bf16
#define OFF_YFB   8536064u    // yfb bf16 [2304][512]
#define OFF_FFB   9125888u    // ffb bf16 [2304][512]
#define OFF_WINT  9715712u    // winT bf16 [1024][256]
#define OFF_WRT   9846784u    // Wrt bf16 [512][512]
#define OFF_WIT   9977856u    // Wit bf16 [512][512]
#define OFF_WXPT  10108928u   // wxpT bf16 [112][512]
#define OFF_WOT   10137600u   // woT bf16 [256][512]
#define OFF_FC1T  10203136u   // fc1T bf16 [512][256]
#define OFF_FC2T  10268672u   // fc2T bf16 [256][512]
#define OFF_CF    10334208u   // Cfb bf16 [320][576]
#define OFF_SF    10426368u   // Sfb bf16 [320][576]
#define OFF_CI    10518528u   // Cib bf16 [576][608]   end 10693632

typedef __attribute__((ext_vector_type(8))) short bf16x8;
typedef __attribute__((ext_vector_type(4))) float f32x4;
typedef __attribute__((ext_vector_type(4))) int   i32x4;

__device__ __forceinline__ float wave_sum(float v) {
#pragma unroll
  for (int o = 32; o > 0; o >>= 1) v += __shfl_xor(v, o);
  return v;
}

__device__ __forceinline__ unsigned short f2bf(float f) {
  unsigned int u = __float_as_uint(f);
  unsigned int r = (u + 0x7fffu + ((u >> 16) & 1u)) >> 16;  // RNE
  return (unsigned short)r;
}
__device__ __forceinline__ float b2f(unsigned short u) {
  return __uint_as_float(((unsigned int)u) << 16);
}

// 64-lane inclusive prefix sum via DPP + readlane broadcasts.
__device__ __forceinline__ float wave_iscan(float x, int lane) {
  x += __int_as_float(__builtin_amdgcn_update_dpp(0, __float_as_int(x), 0x111, 0xf, 0xf, true));
  x += __int_as_float(__builtin_amdgcn_update_dpp(0, __float_as_int(x), 0x112, 0xf, 0xf, true));
  x += __int_as_float(__builtin_amdgcn_update_dpp(0, __float_as_int(x), 0x114, 0xf, 0xf, true));
  x += __int_as_float(__builtin_amdgcn_update_dpp(0, __float_as_int(x), 0x118, 0xf, 0xf, true));
  int xi = __float_as_int(x);
  float s15 = __int_as_float(__builtin_amdgcn_readlane(xi, 15));
  float s31 = __int_as_float(__builtin_amdgcn_readlane(xi, 31));
  float s47 = __int_as_float(__builtin_amdgcn_readlane(xi, 47));
  float off = 0.f;
  if (lane >= 16) off += s15;
  if (lane >= 32) off += s31;
  if (lane >= 48) off += s47;
  return x + off;
}

// device-side 64x64 transpose+bf16 pack tile
__device__ void packT_dev(const float* __restrict__ src, unsigned short* __restrict__ dst,
                          int R, int C, int tile, int cblks) {
  __shared__ float t[64][65];
  int cb = tile % cblks, rb = tile / cblks;
  int c0 = cb * 64, r0 = rb * 64;
  int tid = threadIdx.x;
  for (int u = tid; u < 4096; u += 256) {
    int r = u >> 6, c = u & 63;
    float v = 0.f;
    if (r0 + r < R && c0 + c < C) v = src[(size_t)(r0 + r) * C + c0 + c];
    t[r][c] = v;
  }
  __syncthreads();
  for (int u = tid; u < 4096; u += 256) {
    int nr = u >> 6, nc = u & 63;
    if (c0 + nr < C && r0 + nc < R)
      dst[(size_t)(c0 + nr) * R + r0 + nc] = f2bf(t[nc][nr]);
  }
}

// ONE setup kernel: all weight packs + trig matrices (inline sincos).
__global__ __launch_bounds__(256) void setup_kernel(
    const float* __restrict__ w_in, const float* __restrict__ Wr,
    const float* __restrict__ Wi, const float* __restrict__ wxp,
    const float* __restrict__ wo, const float* __restrict__ fc1,
    const float* __restrict__ fc2,
    unsigned short* __restrict__ winT, unsigned short* __restrict__ Wrt,
    unsigned short* __restrict__ Wit, unsigned short* __restrict__ wxpT,
    unsigned short* __restrict__ woT, unsigned short* __restrict__ fc1T,
    unsigned short* __restrict__ fc2T, unsigned short* __restrict__ Cf,
    unsigned short* __restrict__ Sf, unsigned short* __restrict__ Ci) {
  int bid = blockIdx.x;
  const float TWO_PI_N = 6.28318530717958647692f / (float)NL;
  if (bid < 64)       packT_dev(w_in, winT, NC, NWIN, bid, 16);
  else if (bid < 128) packT_dev(Wr, Wrt, NDIN, NDIN, bid - 64, 8);
  else if (bid < 192) packT_dev(Wi, Wit, NDIN, NDIN, bid - 128, 8);
  else if (bid < 208) packT_dev(wxp, wxpT, NDIN, NXD, bid - 192, 2);
  else if (bid < 240) packT_dev(wo, woT, NDIN, NC, bid - 208, 4);
  else if (bid < 272) packT_dev(fc1, fc1T, NC, NDIN, bid - 240, 8);
  else if (bid < 304) packT_dev(fc2, fc2T, NDIN, NC, bid - 272, 4);
  else if (bid < 384) {            // Cf/Sf: 80 blocks x 4 m-rows
    int m0 = (bid - 304) * 4;
    for (int u = threadIdx.x; u < 4 * NL; u += 256) {
      int m = m0 + u / NL, l = u % NL;
      float c = 0.f, s = 0.f;
      if (m < NFREQ) {
        int idx = (m * l) % NL;
        float sv, cv;
        __sincosf(TWO_PI_N * idx, &sv, &cv);
        c = cv * (1.f / 24.f);
        s = -sv * (1.f / 24.f);
      }
      Cf[(size_t)m * NL + l] = f2bf(c);
      Sf[(size_t)m * NL + l] = f2bf(s);
    }
  } else {                         // Ci: 72 blocks x 8 l-rows
    int l0 = (bid - 384) * 8;
    for (int u = threadIdx.x; u < 8 * NKPK; u += 256) {
      int l = l0 + u / NKPK, k = u % NKPK;
      float v = 0.f;
      if (k < NFREQ) {
        float w = (k == 0 || k == NFREQ - 1) ? 1.f : 2.f;
        int idx = (k * l) % NL;
        float sv, cv;
        __sincosf(TWO_PI_N * idx, &sv, &cv);
        v = w * cv * (1.f / 24.f);
      } else if (k < 2 * NFREQ) {
        int kk = k - NFREQ;
        float w = (kk == 0 || kk == NFREQ - 1) ? 1.f : 2.f;
        int idx = (kk * l) % NL;
        float sv, cv;
        __sincosf(TWO_PI_N * idx, &sv, &cv);
        v = -w * sv * (1.f / 24.f);
      }
      Ci[(size_t)l * NKPK + k] = f2bf(v);
    }
  }
}

// one wave per token row; bf16 output. dbl=1: two chained LNs.
__global__ void ln_kernel(const float* __restrict__ in, unsigned short* __restrict__ out,
                          const float* __restrict__ g1, const float* __restrict__ b1,
                          const float* __restrict__ g2, const float* __restrict__ b2,
                          int dbl) {
  int row = blockIdx.x, lane = threadIdx.x;
  const float* p = in + (size_t)row * NC;
  float v[4];
#pragma unroll
  for (int j = 0; j < 4; ++j) v[j] = p[lane + j * 64];
  float s = wave_sum(v[0] + v[1] + v[2] + v[3]);
  float m = s * (1.f / NC);
  float q = 0.f;
#pragma unroll
  for (int j = 0; j < 4; ++j) { float d = v[j] - m; q += d * d; }
  q = wave_sum(q);
  float rs = 1.f / sqrtf(q * (1.f / NC) + 1e-3f);
#pragma unroll
  for (int j = 0; j < 4; ++j) {
    int c = lane + j * 64;
    v[j] = (v[j] - m) * rs * g1[c] + b1[c];
  }
  if (dbl) {
    s = wave_sum(v[0] + v[1] + v[2] + v[3]);
    m = s * (1.f / NC);
    q = 0.f;
#pragma unroll
    for (int j = 0; j < 4; ++j) { float d = v[j] - m; q += d * d; }
    q = wave_sum(q);
    rs = 1.f / sqrtf(q * (1.f / NC) + 1e-3f);
#pragma unroll
    for (int j = 0; j < 4; ++j) {
      int c = lane + j * 64;
      v[j] = (v[j] - m) * rs * g2[c] + b2[c];
    }
  }
  unsigned short* o = out + (size_t)row * NC;
#pragma unroll
  for (int j = 0; j < 4; ++j) o[lane + j * 64] = f2bf(v[j]);
}

// standalone transpose+bf16 pack (for yf_t -> yfb)
__global__ __launch_bounds__(256) void packT_kernel(
    const float* __restrict__ src, unsigned short* __restrict__ dst, int R, int C) {
  packT_dev(src, dst, R, C, blockIdx.y * gridDim.x + blockIdx.x, gridDim.x);
}

// generic MFMA GEMM: C = A[M][K]bf16 @ B[N][K]bf16^T (f32 accum), fused epilogues.
// mode 0: store; 2: v+add; 3: relu(v*scl+bias); 4: v*scl+bias+add
// flags bit1: transposed store C[n][m]; bit2: bf16 store;
// flags bit3: scan-permute token index within 576-batch on transposed store.
__global__ __launch_bounds__(256) void gemm_mfma(
    const unsigned short* __restrict__ A, const unsigned short* __restrict__ B,
    void* __restrict__ C, int ldc, int M, int N, int K, int mode, int flags,
    const float* __restrict__ scl, const float* __restrict__ bias,
    const float* __restrict__ add, int ldadd) {
  __shared__ unsigned short As[64][40], Bs[64][40];
  int tid = threadIdx.x, lane = tid & 63, wv = tid >> 6;
  int n0 = blockIdx.x * 64, m0 = blockIdx.y * 64;
  int sm = tid >> 2, part = tid & 3;
  f32x4 acc[4] = {};
  for (int k0 = 0; k0 < K; k0 += 32) {
    *(bf16x8*)&As[sm][part * 8] = *(const bf16x8*)(A + (size_t)(m0 + sm) * K + k0 + part * 8);
    bf16x8 bv = {};
    if (n0 + sm < N) bv = *(const bf16x8*)(B + (size_t)(n0 + sm) * K + k0 + part * 8);
    *(bf16x8*)&Bs[sm][part * 8] = bv;
    __syncthreads();
    int am = wv * 16 + (lane & 15), koff = (lane >> 4) * 8;
    bf16x8 a = *(bf16x8*)&As[am][koff];
#pragma unroll
    for (int t = 0; t < 4; ++t) {
      bf16x8 b = *(bf16x8*)&Bs[t * 16 + (lane & 15)][koff];
      acc[t] = __builtin_amdgcn_mfma_f32_16x16x32_bf16(a, b, acc[t], 0, 0, 0);
    }
    __syncthreads();
  }
#pragma unroll
  for (int t = 0; t < 4; ++t) {
    int gn = n0 + t * 16 + (lane & 15);
    if (gn >= N) continue;
    float sv = scl ? scl[gn] : 0.f, bvv = bias ? bias[gn] : 0.f;
#pragma unroll
    for (int r = 0; r < 4; ++r) {
      int gm = m0 + wv * 16 + (lane >> 4) * 4 + r;
      float v = acc[t][r];
      if (mode == 2) v += add[(size_t)gm * ldadd + gn];
      else if (mode == 3) v = fmaxf(v * sv + bvv, 0.f);
      else if (mode == 4) v = v * sv + bvv + add[(size_t)gm * ldadd + gn];
      int gms = gm;
      if (flags & 8) {
        int bq = gm / NL, tt = gm - bq * NL;
        int t9 = tt / 9;
        gms = bq * NL + (tt - t9 * 9) * 64 + t9;
      }
      size_t o = (flags & 2) ? (size_t)gn * ldc + gms : (size_t)gm * ldc + gn;
      if (flags & 4) ((unsigned short*)C)[o] = f2bf(v);
      else ((float*)C)[o] = v;
    }
  }
}

// Fused causal depthwise conv(4)+silu: xc_t f32 (d-major) + xcb bf16 (tok-major);
// z=1: res transpose -> res_t.
__global__ __launch_bounds__(256) void convT_kernel(
    const float* __restrict__ xr, const float* __restrict__ cw,
    const float* __restrict__ cb, float* __restrict__ xc_t,
    float* __restrict__ res_t, unsigned short* __restrict__ xcb) {
  __shared__ float tile[67][65];
  int d0 = blockIdx.x * 64;
  int rt = blockIdx.y;
  int b = rt / 9, l0 = (rt % 9) * 64;
  int tid = threadIdx.x;
  int li = tid & 63, dj0 = tid >> 6;
  if (blockIdx.z == 0) {
    for (int u = tid; u < 67 * 16; u += 256) {
      int r = u >> 4, c4 = (u & 15) * 4;
      int l = l0 - 3 + r;
      float4 v = make_float4(0.f, 0.f, 0.f, 0.f);
      if (l >= 0) v = *reinterpret_cast<const float4*>(xr + (size_t)(b * NL + l) * NWIN + d0 + c4);
      tile[r][c4 + 0] = v.x; tile[r][c4 + 1] = v.y;
      tile[r][c4 + 2] = v.z; tile[r][c4 + 3] = v.w;
    }
    __syncthreads();
    float outv[16];
#pragma unroll
    for (int k2 = 0; k2 < 16; ++k2) {
      int dj = dj0 + k2 * 4;
      int d = d0 + dj;
      float acc = cb[d];
#pragma unroll
      for (int k = 0; k < 4; ++k) acc += cw[k * NDIN + d] * tile[li + k][dj];
      acc = acc / (1.f + __expf(-acc));
      outv[k2] = acc;
      xc_t[(size_t)d * NTOK + b * NL + l0 + li] = acc;
    }
    __syncthreads();
#pragma unroll
    for (int k2 = 0; k2 < 16; ++k2) tile[li][dj0 + k2 * 4] = outv[k2];
    __syncthreads();
    for (int u = tid; u < 1024; u += 256) {
      int r = u >> 4, c4 = (u & 15) * 4;
      unsigned long long pk =
          (unsigned long long)f2bf(tile[r][c4 + 0]) |
          ((unsigned long long)f2bf(tile[r][c4 + 1]) << 16) |
          ((unsigned long long)f2bf(tile[r][c4 + 2]) << 32) |
          ((unsigned long long)f2bf(tile[r][c4 + 3]) << 48);
      *(unsigned long long*)(xcb + (size_t)(b * NL + l0 + r) * NDIN + d0 + c4) = pk;
    }
  } else {
    for (int u = tid; u < 64 * 16; u += 256) {
      int r = u >> 4, c4 = (u & 15) * 4;
      float4 v = *reinterpret_cast<const float4*>(xr + (size_t)(b * NL + l0 + r) * NWIN + NDIN + d0 + c4);
      tile[r][c4 + 0] = v.x; tile[r][c4 + 1] = v.y;
      tile[r][c4 + 2] = v.z; tile[r][c4 + 3] = v.w;
    }
    __syncthreads();
    for (int dj = dj0; dj < 64; dj += 4)
      res_t[(size_t)(d0 + dj) * NTOK + b * NL + l0 + li] = tile[li][dj];
  }
}

// selective scan with fused delta; xdbl bf16, token-permuted for coalescing.
__global__ __launch_bounds__(256) void scan7_kernel(
    const float* __restrict__ xc_t, const unsigned short* __restrict__ xdbl,
    const float* __restrict__ w_dt, const float* __restrict__ b_dt,
    const float* __restrict__ A_log, const float* __restrict__ Dp,
    const float* __restrict__ res_t, float* __restrict__ yf_t) {
  __shared__ float yl[4][NL];
  __shared__ float u_lds[NL];
  int b = blockIdx.x >> 9, d = blockIdx.x & 511;
  int tid = threadIdx.x, lane = tid & 63, wv = tid >> 6;
  int bbase = b * NL;
  const float* urow = xc_t + (size_t)d * NTOK;

  for (int e = tid; e < NL; e += 256) u_lds[e] = urow[bbase + e];

  float wdt[16];
#pragma unroll
  for (int r = 0; r < 16; ++r) wdt[r] = w_dt[r * NDIN + d];
  float bd = b_dt[d];
  float dl[9];
#pragma unroll
  for (int j = 0; j < 9; ++j) dl[j] = bd;
#pragma unroll
  for (int r = 0; r < 16; ++r) {
    const unsigned short* dtp = xdbl + (size_t)r * NTOK + bbase;
#pragma unroll
    for (int j = 0; j < 9; ++j) dl[j] += b2f(dtp[j * 64 + lane]) * wdt[r];
  }
#pragma unroll
  for (int j = 0; j < 9; ++j) {
    float v = dl[j];
    dl[j] = fmaxf(v, 0.f) + __logf(1.f + __expf(-fabsf(v)));
  }
  __syncthreads();

  float ul[9];
#pragma unroll
  for (int j = 0; j < 9; ++j) ul[j] = u_lds[lane * 9 + j];
  float pre[9];
  float s = 0.f;
#pragma unroll
  for (int j = 0; j < 9; ++j) { s += dl[j]; pre[j] = s; }
  float isc = wave_iscan(s, lane);
  float total = __int_as_float(__builtin_amdgcn_readlane(__float_as_int(isc), 63));
  float excl = isc - s;
  float Ts[9], dlul[9];
#pragma unroll
  for (int j = 0; j < 9; ++j) {
    Ts[j] = total - excl - pre[j];
    dlul[j] = dl[j] * ul[j];
  }

  const float* Arow = A_log + (size_t)d * NDST + wv * 12;
  float y[9] = {};
  for (int jj = 0; jj < 12; ++jj) {
    float An = -__expf(Arow[jj]);
    const unsigned short* bbp = xdbl + (size_t)(NDTR + wv * 12 + jj) * NTOK + bbase;
    const unsigned short* ccp = xdbl + (size_t)(NDTR + NDST + wv * 12 + jj) * NTOK + bbase;
    float e[9], w[9];
    float ps = 0.f;
#pragma unroll
    for (int j = 0; j < 9; ++j) {
      e[j] = __expf(An * Ts[j]);
      ps += dlul[j] * b2f(bbp[j * 64 + lane]) * e[j];
      w[j] = ps;
    }
    float wi = wave_iscan(ps, lane);
    float wexcl = wi - ps;
#pragma unroll
    for (int j = 0; j < 9; ++j)
      y[j] += __fdividef(w[j] + wexcl, e[j] + 1e-12f) * b2f(ccp[j * 64 + lane]);
  }
#pragma unroll
  for (int j = 0; j < 9; ++j) yl[wv][lane * 9 + j] = y[j];
  __syncthreads();

  const float* rrow = res_t + (size_t)d * NTOK;
  float* orow = yf_t + (size_t)d * NTOK;
  float Dd = Dp[d];
  for (int e0 = tid; e0 < NL; e0 += 256) {
    float yy = yl[0][e0] + yl[1][e0] + yl[2][e0] + yl[3][e0];
    float uu = u_lds[e0];
    float rr = rrow[bbase + e0];
    float yv = yy + uu * Dd;
    float sr = rr / (1.f + __expf(-rr));
    orow[bbase + e0] = yv * sr;
  }
}

// forward rfft on matrix cores: RF = Cf@f, IF = Sf@f.
__global__ __launch_bounds__(256) void dftf_mfma_kernel(
    const unsigned short* __restrict__ Cf, const unsigned short* __restrict__ Sf,
    const unsigned short* __restrict__ ft,
    unsigned short* __restrict__ RFb, unsigned short* __restrict__ IFb) {
  __shared__ unsigned short AsC[64][40], AsS[64][40], Bs[64][40];
  int tid = threadIdx.x;
  int lane = tid & 63, wv = tid >> 6;
  int n0 = blockIdx.x * 64, m0 = blockIdx.y * 64, b = blockIdx.z;
  int sm = tid >> 2, part = tid & 3;
  f32x4 accR[4] = {}, accI[4] = {};
  for (int k0 = 0; k0 < NL; k0 += 32) {
    *(bf16x8*)&AsC[sm][part * 8] = *(const bf16x8*)(Cf + (size_t)(m0 + sm) * NL + k0 + part * 8);
    *(bf16x8*)&AsS[sm][part * 8] = *(const bf16x8*)(Sf + (size_t)(m0 + sm) * NL + k0 + part * 8);
    *(bf16x8*)&Bs[sm][part * 8]  = *(const bf16x8*)(ft + (size_t)(n0 + sm) * NTOK + b * NL + k0 + part * 8);
    __syncthreads();
    int am = wv * 16 + (lane & 15);
    int koff = (lane >> 4) * 8;
    bf16x8 ac = *(bf16x8*)&AsC[am][koff];
    bf16x8 as = *(bf16x8*)&AsS[am][koff];
#pragma unroll
    for (int t = 0; t < 4; ++t) {
      bf16x8 bv = *(bf16x8*)&Bs[t * 16 + (lane & 15)][koff];
      accR[t] = __builtin_amdgcn_mfma_f32_16x16x32_bf16(ac, bv, accR[t], 0, 0, 0);
      accI[t] = __builtin_amdgcn_mfma_f32_16x16x32_bf16(as, bv, accI[t], 0, 0, 0);
    }
    __syncthreads();
  }
#pragma unroll
  for (int t = 0; t < 4; ++t) {
    int gn = n0 + t * 16 + (lane & 15);
#pragma unroll
    for (int r = 0; r < 4; ++r) {
      int gm = m0 + wv * 16 + (lane >> 4) * 4 + r;
      if (gm < NFREQ) {
        size_t o = ((size_t)(b * NFREQ + gm)) * NDIN + gn;
        RFb[o] = f2bf(accR[t][r]);
        IFb[o] = f2bf(accI[t][r]);
      }
    }
  }
}

// complex mix -> packed irfft B-matrix PK (bf16).
__global__ __launch_bounds__(256) void mix_mfma_kernel(
    const unsigned short* __restrict__ RFb, const unsigned short* __restrict__ IFb,
    const unsigned short* __restrict__ Wrt, const unsigned short* __restrict__ Wit,
    const float* __restrict__ rb, const float* __restrict__ ib,
    unsigned short* __restrict__ PK) {
  __shared__ unsigned short AsR[64][40], AsI[64][40], BsR[64][40], BsI[64][40];
  int tid = threadIdx.x;
  int lane = tid & 63, wv = tid >> 6;
  int n0 = blockIdx.x * 64, m0 = blockIdx.y * 64;
  int sm = tid >> 2, part = tid & 3;
  f32x4 accR[4] = {}, accI[4] = {};
  for (int k0 = 0; k0 < NDIN; k0 += 32) {
    *(bf16x8*)&AsR[sm][part * 8] = *(const bf16x8*)(Wrt + (size_t)(m0 + sm) * NDIN + k0 + part * 8);
    *(bf16x8*)&AsI[sm][part * 8] = *(const bf16x8*)(Wit + (size_t)(m0 + sm) * NDIN + k0 + part * 8);
    bf16x8 brf = {}, bif = {};
    if (n0 + sm < NMROW) {
      brf = *(const bf16x8*)(RFb + (size_t)(n0 + sm) * NDIN + k0 + part * 8);
      bif = *(const bf16x8*)(IFb + (size_t)(n0 + sm) * NDIN + k0 + part * 8);
    }
    *(bf16x8*)&BsR[sm][part * 8] = brf;
    *(bf16x8*)&BsI[sm][part * 8] = bif;
    __syncthreads();
    int am = wv * 16 + (lane & 15);
    int koff = (lane >> 4) * 8;
    bf16x8 a_wr = *(bf16x8*)&AsR[am][koff];
    bf16x8 a_wi = *(bf16x8*)&AsI[am][koff];
    union { bf16x8 h; i32x4 i; } un;
    un.h = a_wi;
    un.i = un.i ^ (int)0x80008000;
    bf16x8 a_win = un.h;
#pragma unroll
    for (int t = 0; t < 4; ++t) {
      bf16x8 b_rf = *(bf16x8*)&BsR[t * 16 + (lane & 15)][koff];
      bf16x8 b_if = *(bf16x8*)&BsI[t * 16 + (lane & 15)][koff];
      accR[t] = __builtin_amdgcn_mfma_f32_16x16x32_bf16(a_wr, b_rf, accR[t], 0, 0, 0);
      accR[t] = __builtin_amdgcn_mfma_f32_16x16x32_bf16(a_win, b_if, accR[t], 0, 0, 0);
      accI[t] = __builtin_amdgcn_mfma_f32_16x16x32_bf16(a_wr, b_if, accI[t], 0, 0, 0);
      accI[t] = __builtin_amdgcn_mfma_f32_16x16x32_bf16(a_wi, b_rf, accI[t], 0, 0, 0);
    }
    __syncthreads();
  }
#pragma unroll
  for (int t = 0; t < 4; ++t) {
    int gn = n0 + t * 16 + (lane & 15);   // freq global
    int bb = (gn >= 3 * NFREQ) ? 3 : (gn >= 2 * NFREQ) ? 2 : (gn >= NFREQ) ? 1 : 0;
    int kf = gn - bb * NFREQ;
    bool ok = gn < NMROW;
#pragma unroll
    for (int r = 0; r < 4; ++r) {
      int gm = m0 + wv * 16 + (lane >> 4) * 4 + r;   // c_out
      if (ok) {
        float vr = fmaxf(accR[t][r] + rb[gm], 0.f);
        float vi = fmaxf(accI[t][r] + ib[gm], 0.f);
        size_t base = ((size_t)gm * NB + bb) * NKPK;
        PK[base + kf] = f2bf(vr);
        PK[base + NFREQ + kf] = f2bf(vi);
      }
    }
  }
}

// irfft on matrix cores -> ffb bf16 [2304][512]; pad lanes (578..607) masked in-register.
__global__ __launch_bounds__(256) void idft_mfma_kernel(
    const unsigned short* __restrict__ Ci, const unsigned short* __restrict__ PK,
    unsigned short* __restrict__ ffb) {
  __shared__ unsigned short As[64][40], Bs[64][40];
  int tid = threadIdx.x;
  int lane = tid & 63, wv = tid >> 6;
  int n0 = blockIdx.x * 64, m0 = blockIdx.y * 64, b = blockIdx.z;
  int sm = tid >> 2, part = tid & 3;
  f32x4 acc[4] = {};
  for (int k0 = 0; k0 < NKPK; k0 += 32) {
    *(bf16x8*)&As[sm][part * 8] = *(const bf16x8*)(Ci + (size_t)(m0 + sm) * NKPK + k0 + part * 8);
    bf16x8 bv = *(const bf16x8*)(PK + ((size_t)(n0 + sm) * NB + b) * NKPK + k0 + part * 8);
    if (k0 + part * 8 >= 2 * NFREQ - 2) {  // chunk contains pad cols (>=576 area)
      union { bf16x8 h; i32x4 i; } u;
      u.h = bv;
      if (k0 + part * 8 == 576) { u.i[1] = 0; u.i[2] = 0; u.i[3] = 0; }  // keep 576,577
      else { u.i[0] = 0; u.i[1] = 0; u.i[2] = 0; u.i[3] = 0; }
      bv = u.h;
    }
    *(bf16x8*)&Bs[sm][part * 8] = bv;
    __syncthreads();
    int am = wv * 16 + (lane & 15);
    int koff = (lane >> 4) * 8;
    bf16x8 av = *(bf16x8*)&As[am][koff];
#pragma unroll
    for (int t = 0; t < 4; ++t) {
      bf16x8 b2 = *(bf16x8*)&Bs[t * 16 + (lane & 15)][koff];
      acc[t] = __builtin_amdgcn_mfma_f32_16x16x32_bf16(av, b2, acc[t], 0, 0, 0);
    }
    __syncthreads();
  }
#pragma unroll
  for (int t = 0; t < 4; ++t) {
    int gn = n0 + t * 16 + (lane & 15);     // d
#pragma unroll
    for (int r = 0; r < 4; ++r) {
      int gm = m0 + wv * 16 + (lane >> 4) * 4 + r;   // l
      ffb[((size_t)(b * NL + gm)) * NDIN + gn] = f2bf(acc[t][r]);
    }
  }
}

extern "C" void kernel_launch(void* const* d_in, const int* in_sizes, int n_in,
                              void* d_out, int out_size, void* d_ws, size_t ws_size,
                              hipStream_t stream) {
  const float* x      = (const float*)d_in[0];
  const float* ln1_g  = (const float*)d_in[1];
  const float* ln1_b  = (const float*)d_in[2];
  const float* mln_g  = (const float*)d_in[3];
  const float* mln_b  = (const float*)d_in[4];
  const float* w_in   = (const float*)d_in[5];
  const float* conv_w = (const float*)d_in[6];
  const float* conv_b = (const float*)d_in[7];
  const float* w_xprj = (const float*)d_in[8];
  const float* w_dt   = (const float*)d_in[9];
  const float* b_dt   = (const float*)d_in[10];
  const float* A_log  = (const float*)d_in[11];
  const float* Dp     = (const float*)d_in[12];
  const float* w_out  = (const float*)d_in[13];
  const float* ln2_g  = (const float*)d_in[14];
  const float* ln2_b  = (const float*)d_in[15];
  const float* fc1_w  = (const float*)d_in[16];
  const float* bn1_s  = (const float*)d_in[17];
  const float* bn1_b  = (const float*)d_in[18];
  const float* Wr     = (const float*)d_in[19];
  const float* Wi     = (const float*)d_in[20];
  const float* rb     = (const float*)d_in[21];
  const float* ib     = (const float*)d_in[22];
  const float* fc2_w  = (const float*)d_in[23];
  const float* bn2_s  = (const float*)d_in[24];
  const float* bn2_b  = (const float*)d_in[25];

  float* ws = (float*)d_ws;
  unsigned short* hb   = (unsigned short*)(ws + OFF_HB);   // reused as h2b
  float* xr     = ws + OFF_XRF;
  float* xc_t   = ws + OFF_XCT;
  float* res_t  = ws + OFF_REST;
  float* yf_t   = ws + OFF_YFT;
  float* x2     = ws + OFF_X2;
  unsigned short* xcb  = (unsigned short*)(ws + OFF_XCB);
  unsigned short* xdbl = (unsigned short*)(ws + OFF_XDBL);
  unsigned short* PK   = (unsigned short*)(ws + OFF_YFT);
  unsigned short* ftb  = (unsigned short*)(ws + OFF_FTB);
  unsigned short* RFb  = (unsigned short*)(ws + OFF_RF);
  unsigned short* IFb  = (unsigned short*)(ws + OFF_IF);
  unsigned short* yfb  = (unsigned short*)(ws + OFF_YFB);
  unsigned short* ffb  = (unsigned short*)(ws + OFF_FFB);
  unsigned short* winT = (unsigned short*)(ws + OFF_WINT);
  unsigned short* Wrt  = (unsigned short*)(ws + OFF_WRT);
  unsigned short* Wit  = (unsigned short*)(ws + OFF_WIT);
  unsigned short* wxpT = (unsigned short*)(ws + OFF_WXPT);
  unsigned short* woT  = (unsigned short*)(ws + OFF_WOT);
  unsigned short* fc1T = (unsigned short*)(ws + OFF_FC1T);
  unsigned short* fc2T = (unsigned short*)(ws + OFF_FC2T);
  unsigned short* Cfb  = (unsigned short*)(ws + OFF_CF);
  unsigned short* Sfb  = (unsigned short*)(ws + OFF_SF);
  unsigned short* Cib  = (unsigned short*)(ws + OFF_CI);
  unsigned short* h2b  = hb;
  float* out = (float*)d_out;

  // 1: all weight packs + trig matrices in one launch
  setup_kernel<<<456, 256, 0, stream>>>(w_in, Wr, Wi, w_xprj, w_out, fc1_w, fc2_w,
                                        winT, Wrt, Wit, wxpT, woT, fc1T, fc2T,
                                        Cfb, Sfb, Cib);
  // 2: hb = bf16(LN(LN(x)))
  ln_kernel<<<NTOK, 64, 0, stream>>>(x, hb, ln1_g, ln1_b, mln_g, mln_b, 1);
  // 3: xr = hb @ w_in (f32)
  gemm_mfma<<<dim3(16, 36), 256, 0, stream>>>(hb, winT, xr, NWIN, NTOK, NWIN, NC,
                                              0, 0, nullptr, nullptr, nullptr, 0);
  // 4: xc_t f32 + xcb bf16 + res_t
  convT_kernel<<<dim3(8, 36, 2), 256, 0, stream>>>(xr, conv_w, conv_b, xc_t, res_t, xcb);
  // 5: xdbl = bf16((xcb @ w_xproj)^T), token-permuted [112][2304]
  gemm_mfma<<<dim3(2, 36), 256, 0, stream>>>(xcb, wxpT, xdbl, NTOK, NTOK, NXD, NDIN,
                                             0, 14, nullptr, nullptr, nullptr, 0);
  // 6: scan (fused delta, bf16 B/C)
  scan7_kernel<<<NB * NDIN, 256, 0, stream>>>(xc_t, xdbl, w_dt, b_dt, A_log, Dp, res_t, yf_t);
  // 7: yfb = bf16(yf^T)
  packT_kernel<<<dim3(36, 8), 256, 0, stream>>>(yf_t, yfb, NDIN, NTOK);
  // 8: x2 = x + yfb @ w_out
  gemm_mfma<<<dim3(4, 36), 256, 0, stream>>>(yfb, woT, x2, NC, NTOK, NC, NDIN,
                                             2, 0, nullptr, nullptr, x, NC);
  // 9: h2b = bf16(LN(x2))
  ln_kernel<<<NTOK, 64, 0, stream>>>(x2, h2b, ln2_g, ln2_b, nullptr, nullptr, 0);
  // 10: ftb = bf16(relu(h2b@fc1 * s + b))^T [512][2304]
  gemm_mfma<<<dim3(8, 36), 256, 0, stream>>>(h2b, fc1T, ftb, NTOK, NTOK, NDIN, NC,
                                             3, 6, bn1_s, bn1_b, nullptr, 0);
  // 11-13: rfft / mix / irfft on MFMA (idft masks PK pad lanes in-register)
  dftf_mfma_kernel<<<dim3(8, 5, NB), 256, 0, stream>>>(Cfb, Sfb, ftb, RFb, IFb);
  mix_mfma_kernel<<<dim3(19, 8), 256, 0, stream>>>(RFb, IFb, Wrt, Wit, rb, ib, PK);
  idft_mfma_kernel<<<dim3(8, 9, NB), 256, 0, stream>>>(Cib, PK, ffb);
  // 14: out = x2 + ffb @ fc2 * s + b
  gemm_mfma<<<dim3(4, 36), 256, 0, stream>>>(ffb, fc2T, out, NC, NTOK, NC, NDIN,
                                             4, 0, bn2_s, bn2_b, x2, NC);
}